// Round 2
// baseline (372.566 us; speedup 1.0000x reference)
//
#include <hip/hip_runtime.h>
#include <math.h>

#define BB 2
#define NN 2048
#define KK 30
#define DD 128
#define HH 4
#define PQ_ 8
#define PV_ 4
#define NPB 8

#define INV3C    0.05103103630798288f   // sqrt(1/(3*128))
#define INV3     0.5773502691896258f    // sqrt(1/3)
#define PT_SCALE 0.09622504486493764f   // sqrt(1/108)

__global__ __launch_bounds__(256) void proj_kernel(
    const float* __restrict__ hV, const float* __restrict__ R, const float* __restrict__ tvec,
    const float* __restrict__ Wq, const float* __restrict__ bq,
    const float* __restrict__ Wkv, const float* __restrict__ bkv,
    const float* __restrict__ Wqp, const float* __restrict__ bqp,
    const float* __restrict__ Wkvp, const float* __restrict__ bkvp,
    float* __restrict__ q, float* __restrict__ kk, float* __restrict__ vv,
    float* __restrict__ qpts, float* __restrict__ kpts, float* __restrict__ vpts)
{
    const int node0 = blockIdx.x * NPB;
    const int tid = threadIdx.x;
    __shared__ float sx[NPB][DD];
    __shared__ float sqp[NPB][96];
    __shared__ float skvp[NPB][144];

    for (int i = tid; i < NPB * DD; i += 256)
        sx[i >> 7][i & 127] = hV[(size_t)node0 * DD + i];
    __syncthreads();

    // q: 512 cols
    for (int c = tid; c < 512; c += 256) {
        float acc[NPB];
        #pragma unroll
        for (int r = 0; r < NPB; ++r) acc[r] = bq[c];
        for (int i = 0; i < DD; ++i) {
            float w = Wq[i * 512 + c];
            #pragma unroll
            for (int r = 0; r < NPB; ++r) acc[r] = fmaf(sx[r][i], w, acc[r]);
        }
        #pragma unroll
        for (int r = 0; r < NPB; ++r) q[(size_t)(node0 + r) * 512 + c] = acc[r];
    }
    // kv: 1024 cols -> split into k_, v_
    for (int c = tid; c < 1024; c += 256) {
        float acc[NPB];
        #pragma unroll
        for (int r = 0; r < NPB; ++r) acc[r] = bkv[c];
        for (int i = 0; i < DD; ++i) {
            float w = Wkv[i * 1024 + c];
            #pragma unroll
            for (int r = 0; r < NPB; ++r) acc[r] = fmaf(sx[r][i], w, acc[r]);
        }
        int h = c >> 8, wcol = c & 255;
        #pragma unroll
        for (int r = 0; r < NPB; ++r) {
            if (wcol < DD) kk[(size_t)(node0 + r) * 512 + h * DD + wcol] = acc[r];
            else           vv[(size_t)(node0 + r) * 512 + h * DD + wcol - DD] = acc[r];
        }
    }
    // qp: 96 cols (threads 0..95)
    if (tid < 96) {
        float acc[NPB];
        #pragma unroll
        for (int r = 0; r < NPB; ++r) acc[r] = bqp[tid];
        for (int i = 0; i < DD; ++i) {
            float w = Wqp[i * 96 + tid];
            #pragma unroll
            for (int r = 0; r < NPB; ++r) acc[r] = fmaf(sx[r][i], w, acc[r]);
        }
        #pragma unroll
        for (int r = 0; r < NPB; ++r) sqp[r][tid] = acc[r];
    }
    // kvp: 144 cols (threads 112..255)
    if (tid >= 112) {
        int c = tid - 112;
        float acc[NPB];
        #pragma unroll
        for (int r = 0; r < NPB; ++r) acc[r] = bkvp[c];
        for (int i = 0; i < DD; ++i) {
            float w = Wkvp[i * 144 + c];
            #pragma unroll
            for (int r = 0; r < NPB; ++r) acc[r] = fmaf(sx[r][i], w, acc[r]);
        }
        #pragma unroll
        for (int r = 0; r < NPB; ++r) skvp[r][c] = acc[r];
    }
    __syncthreads();

    // rigid transform q_pts: out[x] = sum_y R[x,y]*p[y] + t[x]
    for (int idx = tid; idx < NPB * 96; idx += 256) {
        int r = idx / 96, u = idx % 96;
        int j = u / 3, d = u % 3;
        int node = node0 + r;
        float acc = tvec[node * 3 + d];
        #pragma unroll
        for (int y = 0; y < 3; ++y)
            acc = fmaf(R[node * 9 + d * 3 + y], sqp[r][y * 32 + j], acc);
        qpts[(size_t)node * 96 + j * 3 + d] = acc;
    }
    // rigid transform kv_pts, split into k_pts / v_pts
    for (int idx = tid; idx < NPB * 144; idx += 256) {
        int r = idx / 144, u = idx % 144;
        int jj = u / 3, d = u % 3;
        int node = node0 + r;
        float acc = tvec[node * 3 + d];
        #pragma unroll
        for (int y = 0; y < 3; ++y)
            acc = fmaf(R[node * 9 + d * 3 + y], skvp[r][y * 48 + jj], acc);
        int hh = jj / 12, pp = jj % 12;
        if (pp < PQ_) kpts[(size_t)node * 96 + (hh * PQ_ + pp) * 3 + d] = acc;
        else          vpts[(size_t)node * 48 + (hh * PV_ + (pp - PQ_)) * 3 + d] = acc;
    }
}

__global__ __launch_bounds__(256) void attn_kernel(
    const float* __restrict__ hV, const float* __restrict__ hE, const int* __restrict__ Eidx,
    const float* __restrict__ R, const float* __restrict__ tvec,
    const float* __restrict__ mask_att, const float* __restrict__ maskV,
    const float* __restrict__ Wb, const float* __restrict__ bb,
    const float* __restrict__ head_w,
    const float* __restrict__ Wout, const float* __restrict__ bout,
    const float* __restrict__ ln0w, const float* __restrict__ ln0b,
    const float* __restrict__ ln1w, const float* __restrict__ ln1b,
    const float* __restrict__ Wm1, const float* __restrict__ bm1,
    const float* __restrict__ Wm2, const float* __restrict__ bm2,
    const float* __restrict__ q, const float* __restrict__ kk, const float* __restrict__ vv,
    const float* __restrict__ qpts, const float* __restrict__ kpts, const float* __restrict__ vpts,
    float* __restrict__ out)
{
    const int node = blockIdx.x;
    const int b = node / NN;
    const int tid = threadIdx.x;
    const int lane = tid & 63;
    const int wv = tid >> 6;

    __shared__ float s_q[512];
    __shared__ float s_qp[96];
    __shared__ float s_p[HH][32];
    __shared__ int   s_j[KK];
    __shared__ float s_mask[KK];
    __shared__ float s_hw[HH];
    __shared__ float s_cat[1088];
    __shared__ float s_opt[48];
    __shared__ float s_hv[DD];
    __shared__ float s_x[DD];
    __shared__ float s_m1[512];
    __shared__ float s_red[256];
    __shared__ float s_stat[2];

    for (int i = tid; i < 512; i += 256) s_q[i] = q[(size_t)node * 512 + i];
    if (tid < 96) s_qp[tid] = qpts[(size_t)node * 96 + tid];
    if (tid < KK) {
        s_j[tid] = Eidx[(size_t)node * KK + tid];
        s_mask[tid] = 100000.0f * (mask_att[(size_t)node * KK + tid] - 1.0f);
    }
    if (tid < HH) s_hw[tid] = log1pf(expf(head_w[tid]));
    __syncthreads();

    // ---- logits: wave wv handles head h=wv, loop over k ----
    const int h = wv;
    for (int kx = 0; kx < KK; ++kx) {
        int j = s_j[kx];
        size_t jb = (size_t)(b * NN + j);
        const float* kr = kk + jb * 512 + h * DD;
        const float* her = hE + ((size_t)node * KK + kx) * DD;
        float p1 = s_q[h * DD + lane] * kr[lane] + s_q[h * DD + lane + 64] * kr[lane + 64];
        float p2 = her[lane] * Wb[lane * HH + h] + her[lane + 64] * Wb[(lane + 64) * HH + h];
        float p3 = 0.f;
        if (lane < 24) {
            float dd = s_qp[h * 24 + lane] - kpts[jb * 96 + h * 24 + lane];
            p3 = dd * dd;
        }
        #pragma unroll
        for (int off = 32; off; off >>= 1) {
            p1 += __shfl_down(p1, off);
            p2 += __shfl_down(p2, off);
            p3 += __shfl_down(p3, off);
        }
        if (lane == 0) {
            s_p[h][kx] = INV3C * p1 + INV3 * (p2 + bb[h])
                       - 0.5f * PT_SCALE * s_hw[h] * p3 + s_mask[kx];
        }
    }
    __syncthreads();

    // ---- softmax over k, wave per head ----
    {
        float val = (lane < KK) ? s_p[h][lane] : -INFINITY;
        float m = val;
        #pragma unroll
        for (int off = 32; off; off >>= 1) m = fmaxf(m, __shfl_down(m, off));
        m = __shfl(m, 0);
        float e = (lane < KK) ? expf(val - m) : 0.f;
        float ssum = e;
        #pragma unroll
        for (int off = 32; off; off >>= 1) ssum += __shfl_down(ssum, off);
        ssum = __shfl(ssum, 0);
        if (lane < KK) s_p[h][lane] = e / ssum;
    }
    __syncthreads();

    // ---- o = sum_k p * v_nb ----
    for (int oidx = tid; oidx < 512; oidx += 256) {
        int oh = oidx >> 7, oc = oidx & 127;
        float acc = 0.f;
        for (int kx = 0; kx < KK; ++kx) {
            size_t jb = (size_t)(b * NN + s_j[kx]);
            acc = fmaf(s_p[oh][kx], vv[jb * 512 + oh * DD + oc], acc);
        }
        s_cat[oh * DD + oc] = acc;
    }
    // ---- o_pair = sum_k p * h_E ----
    for (int oidx = tid; oidx < 512; oidx += 256) {
        int oh = oidx >> 7, oc = oidx & 127;
        float acc = 0.f;
        const float* her = hE + (size_t)node * KK * DD + oc;
        for (int kx = 0; kx < KK; ++kx)
            acc = fmaf(s_p[oh][kx], her[kx * DD], acc);
        s_cat[576 + oh * DD + oc] = acc;
    }
    // ---- o_pt (global frame): 16 points x 3 coords = 48 values ----
    if (tid < 48) {
        int jj = tid / 3, d = tid % 3;   // jj in [0,16): point index h*PV+p
        int oh = jj >> 2;                // head
        float acc = 0.f;
        for (int kx = 0; kx < KK; ++kx) {
            size_t jb = (size_t)(b * NN + s_j[kx]);
            acc = fmaf(s_p[oh][kx], vpts[jb * 48 + jj * 3 + d], acc);
        }
        s_opt[tid] = acc;
    }
    __syncthreads();
    // ---- inverse rigid + norm (16 points) ----
    if (tid < 16) {
        int jj = tid;
        float g0 = s_opt[jj * 3 + 0] - tvec[node * 3 + 0];
        float g1 = s_opt[jj * 3 + 1] - tvec[node * 3 + 1];
        float g2 = s_opt[jj * 3 + 2] - tvec[node * 3 + 2];
        // out[x] = sum_y R[y,x] * g[y]
        float l0 = R[node * 9 + 0] * g0 + R[node * 9 + 3] * g1 + R[node * 9 + 6] * g2;
        float l1 = R[node * 9 + 1] * g0 + R[node * 9 + 4] * g1 + R[node * 9 + 7] * g2;
        float l2 = R[node * 9 + 2] * g0 + R[node * 9 + 5] * g1 + R[node * 9 + 8] * g2;
        s_cat[512 + 0 * 16 + jj] = l0;
        s_cat[512 + 1 * 16 + jj] = l1;
        s_cat[512 + 2 * 16 + jj] = l2;
        s_cat[560 + jj] = sqrtf(l0 * l0 + l1 * l1 + l2 * l2 + 1e-8f);
    }
    __syncthreads();

    // ---- s = cat @ Wout + bout; residual; LN0 ----
    const int c = tid & 127;
    const int halfsel = tid >> 7;
    {
        float acc = 0.f;
        for (int i = halfsel * 544; i < halfsel * 544 + 544; ++i)
            acc = fmaf(s_cat[i], Wout[(size_t)i * DD + c], acc);
        s_red[tid] = acc;
    }
    __syncthreads();
    if (tid < DD)
        s_x[tid] = s_red[tid] + s_red[DD + tid] + bout[tid] + hV[(size_t)node * DD + tid];
    __syncthreads();
    if (wv == 0) {
        float x0 = s_x[lane], x1 = s_x[lane + 64];
        float ssum = x0 + x1, ssq = x0 * x0 + x1 * x1;
        #pragma unroll
        for (int off = 32; off; off >>= 1) { ssum += __shfl_down(ssum, off); ssq += __shfl_down(ssq, off); }
        if (lane == 0) {
            float mu = ssum / 128.f;
            s_stat[0] = mu;
            s_stat[1] = rsqrtf(ssq / 128.f - mu * mu + 1e-5f);
        }
    }
    __syncthreads();
    if (tid < DD)
        s_hv[tid] = (s_x[tid] - s_stat[0]) * s_stat[1] * ln0w[tid] + ln0b[tid];
    __syncthreads();

    // ---- MLP ----
    for (int col = tid; col < 512; col += 256) {
        float acc = bm1[col];
        for (int i = 0; i < DD; ++i) acc = fmaf(s_hv[i], Wm1[i * 512 + col], acc);
        s_m1[col] = fmaxf(acc, 0.f);
    }
    __syncthreads();
    {
        float acc = 0.f;
        for (int i = halfsel * 256; i < halfsel * 256 + 256; ++i)
            acc = fmaf(s_m1[i], Wm2[(size_t)i * DD + c], acc);
        s_red[tid] = acc;
    }
    __syncthreads();
    if (tid < DD)
        s_x[tid] = s_red[tid] + s_red[DD + tid] + bm2[tid] + s_hv[tid];
    __syncthreads();
    if (wv == 0) {
        float x0 = s_x[lane], x1 = s_x[lane + 64];
        float ssum = x0 + x1, ssq = x0 * x0 + x1 * x1;
        #pragma unroll
        for (int off = 32; off; off >>= 1) { ssum += __shfl_down(ssum, off); ssq += __shfl_down(ssq, off); }
        if (lane == 0) {
            float mu = ssum / 128.f;
            s_stat[0] = mu;
            s_stat[1] = rsqrtf(ssq / 128.f - mu * mu + 1e-5f);
        }
    }
    __syncthreads();
    if (tid < DD) {
        float o = (s_x[tid] - s_stat[0]) * s_stat[1] * ln1w[tid] + ln1b[tid];
        out[(size_t)node * DD + tid] = o * maskV[node];
    }
}

extern "C" void kernel_launch(void* const* d_in, const int* in_sizes, int n_in,
                              void* d_out, int out_size, void* d_ws, size_t ws_size,
                              hipStream_t stream)
{
    const float* hV      = (const float*)d_in[0];
    const float* hE      = (const float*)d_in[1];
    const int*   Eidx    = (const int*)  d_in[2];
    const float* R       = (const float*)d_in[3];
    const float* tvec    = (const float*)d_in[4];
    const float* mask_at = (const float*)d_in[5];
    const float* maskV   = (const float*)d_in[6];
    const float* Wq      = (const float*)d_in[7];
    const float* bq      = (const float*)d_in[8];
    const float* Wkv     = (const float*)d_in[9];
    const float* bkv     = (const float*)d_in[10];
    const float* Wqp     = (const float*)d_in[11];
    const float* bqp     = (const float*)d_in[12];
    const float* Wkvp    = (const float*)d_in[13];
    const float* bkvp    = (const float*)d_in[14];
    const float* Wb      = (const float*)d_in[15];
    const float* bb      = (const float*)d_in[16];
    const float* hw      = (const float*)d_in[17];
    const float* Wout    = (const float*)d_in[18];
    const float* bout    = (const float*)d_in[19];
    const float* ln0w    = (const float*)d_in[20];
    const float* ln0b    = (const float*)d_in[21];
    const float* ln1w    = (const float*)d_in[22];
    const float* ln1b    = (const float*)d_in[23];
    const float* Wm1     = (const float*)d_in[24];
    const float* bm1     = (const float*)d_in[25];
    const float* Wm2     = (const float*)d_in[26];
    const float* bm2     = (const float*)d_in[27];

    const size_t nodes = (size_t)BB * NN;
    float* ws  = (float*)d_ws;
    float* q   = ws;
    float* kk  = q  + nodes * 512;
    float* vv  = kk + nodes * 512;
    float* qp  = vv + nodes * 512;
    float* kp  = qp + nodes * 96;
    float* vp  = kp + nodes * 96;

    proj_kernel<<<(int)(nodes / NPB), 256, 0, stream>>>(
        hV, R, tvec, Wq, bq, Wkv, bkv, Wqp, bqp, Wkvp, bkvp,
        q, kk, vv, qp, kp, vp);

    attn_kernel<<<(int)nodes, 256, 0, stream>>>(
        hV, hE, Eidx, R, tvec, mask_at, maskV,
        Wb, bb, hw, Wout, bout, ln0w, ln0b, ln1w, ln1b,
        Wm1, bm1, Wm2, bm2,
        q, kk, vv, qp, kp, vp, (float*)d_out);
}

// Round 3
// 316.321 us; speedup vs baseline: 1.1778x; 1.1778x over previous
//
#include <hip/hip_runtime.h>
#include <math.h>

#define BB 2
#define NN 2048
#define KK 30
#define DD 128
#define HH 4
#define PQ_ 8
#define PV_ 4
#define NPB 8

#define INV3C    0.05103103630798288f   // sqrt(1/(3*128))
#define INV3     0.5773502691896258f    // sqrt(1/3)
#define PT_SCALE 0.09622504486493764f   // sqrt(1/108)

__global__ __launch_bounds__(256) void proj_kernel(
    const float* __restrict__ hV, const float* __restrict__ R, const float* __restrict__ tvec,
    const float* __restrict__ Wq, const float* __restrict__ bq,
    const float* __restrict__ Wkv, const float* __restrict__ bkv,
    const float* __restrict__ Wqp, const float* __restrict__ bqp,
    const float* __restrict__ Wkvp, const float* __restrict__ bkvp,
    float* __restrict__ q, float* __restrict__ kk, float* __restrict__ vv,
    float* __restrict__ qpts, float* __restrict__ kpts, float* __restrict__ vpts)
{
    const int node0 = blockIdx.x * NPB;
    const int tid = threadIdx.x;
    __shared__ float sx[NPB][DD];
    __shared__ float sqp[NPB][96];
    __shared__ float skvp[NPB][144];

    for (int i = tid; i < NPB * DD; i += 256)
        sx[i >> 7][i & 127] = hV[(size_t)node0 * DD + i];
    __syncthreads();

    // q: 512 cols
    for (int c = tid; c < 512; c += 256) {
        float acc[NPB];
        #pragma unroll
        for (int r = 0; r < NPB; ++r) acc[r] = bq[c];
        for (int i = 0; i < DD; ++i) {
            float w = Wq[i * 512 + c];
            #pragma unroll
            for (int r = 0; r < NPB; ++r) acc[r] = fmaf(sx[r][i], w, acc[r]);
        }
        #pragma unroll
        for (int r = 0; r < NPB; ++r) q[(size_t)(node0 + r) * 512 + c] = acc[r];
    }
    // kv: 1024 cols -> split into k_, v_
    for (int c = tid; c < 1024; c += 256) {
        float acc[NPB];
        #pragma unroll
        for (int r = 0; r < NPB; ++r) acc[r] = bkv[c];
        for (int i = 0; i < DD; ++i) {
            float w = Wkv[i * 1024 + c];
            #pragma unroll
            for (int r = 0; r < NPB; ++r) acc[r] = fmaf(sx[r][i], w, acc[r]);
        }
        int h = c >> 8, wcol = c & 255;
        #pragma unroll
        for (int r = 0; r < NPB; ++r) {
            if (wcol < DD) kk[(size_t)(node0 + r) * 512 + h * DD + wcol] = acc[r];
            else           vv[(size_t)(node0 + r) * 512 + h * DD + wcol - DD] = acc[r];
        }
    }
    // qp: 96 cols (threads 0..95)
    if (tid < 96) {
        float acc[NPB];
        #pragma unroll
        for (int r = 0; r < NPB; ++r) acc[r] = bqp[tid];
        for (int i = 0; i < DD; ++i) {
            float w = Wqp[i * 96 + tid];
            #pragma unroll
            for (int r = 0; r < NPB; ++r) acc[r] = fmaf(sx[r][i], w, acc[r]);
        }
        #pragma unroll
        for (int r = 0; r < NPB; ++r) sqp[r][tid] = acc[r];
    }
    // kvp: 144 cols (threads 112..255)
    if (tid >= 112) {
        int c = tid - 112;
        float acc[NPB];
        #pragma unroll
        for (int r = 0; r < NPB; ++r) acc[r] = bkvp[c];
        for (int i = 0; i < DD; ++i) {
            float w = Wkvp[i * 144 + c];
            #pragma unroll
            for (int r = 0; r < NPB; ++r) acc[r] = fmaf(sx[r][i], w, acc[r]);
        }
        #pragma unroll
        for (int r = 0; r < NPB; ++r) skvp[r][c] = acc[r];
    }
    __syncthreads();

    // rigid transform q_pts
    for (int idx = tid; idx < NPB * 96; idx += 256) {
        int r = idx / 96, u = idx % 96;
        int j = u / 3, d = u % 3;
        int node = node0 + r;
        float acc = tvec[node * 3 + d];
        #pragma unroll
        for (int y = 0; y < 3; ++y)
            acc = fmaf(R[node * 9 + d * 3 + y], sqp[r][y * 32 + j], acc);
        qpts[(size_t)node * 96 + j * 3 + d] = acc;
    }
    // rigid transform kv_pts, split into k_pts / v_pts
    for (int idx = tid; idx < NPB * 144; idx += 256) {
        int r = idx / 144, u = idx % 144;
        int jj = u / 3, d = u % 3;
        int node = node0 + r;
        float acc = tvec[node * 3 + d];
        #pragma unroll
        for (int y = 0; y < 3; ++y)
            acc = fmaf(R[node * 9 + d * 3 + y], skvp[r][y * 48 + jj], acc);
        int hh = jj / 12, pp = jj % 12;
        if (pp < PQ_) kpts[(size_t)node * 96 + (hh * PQ_ + pp) * 3 + d] = acc;
        else          vpts[(size_t)node * 48 + (hh * PV_ + (pp - PQ_)) * 3 + d] = acc;
    }
}

__global__ __launch_bounds__(256) void attn_kernel(
    const float* __restrict__ hV, const float* __restrict__ hE, const int* __restrict__ Eidx,
    const float* __restrict__ R, const float* __restrict__ tvec,
    const float* __restrict__ mask_att, const float* __restrict__ maskV,
    const float* __restrict__ Wb, const float* __restrict__ bb,
    const float* __restrict__ head_w,
    const float* __restrict__ Wout, const float* __restrict__ bout,
    const float* __restrict__ ln0w, const float* __restrict__ ln0b,
    const float* __restrict__ ln1w, const float* __restrict__ ln1b,
    const float* __restrict__ Wm1, const float* __restrict__ bm1,
    const float* __restrict__ Wm2, const float* __restrict__ bm2,
    const float* __restrict__ q, const float* __restrict__ kk, const float* __restrict__ vv,
    const float* __restrict__ qpts, const float* __restrict__ kpts, const float* __restrict__ vpts,
    float* __restrict__ out)
{
    const int node = blockIdx.x;
    const int b = node >> 11;           // node / NN
    const int tid = threadIdx.x;
    const int lane = tid & 63;
    const int wv = tid >> 6;

    __shared__ float s_hE[KK * DD];     // 15360 B
    __shared__ float s_cat[1088];
    __shared__ float s_red[1024];
    __shared__ float s_m1[512];
    __shared__ float s_qp[96];
    __shared__ float s_p[HH][32];
    __shared__ int   s_j[32];
    __shared__ float s_mask[32];
    __shared__ float s_opt[48];
    __shared__ float s_hv[DD];
    __shared__ float s_x[DD];
    __shared__ float s_stat[2];

    // ---- stage hE tile once, coalesced float4 ----
    {
        const float4* src = (const float4*)(hE + (size_t)node * (KK * DD));
        float4* dst = (float4*)s_hE;
        for (int i = tid; i < (KK * DD) / 4; i += 256) dst[i] = src[i];
    }
    if (tid < 96) s_qp[tid] = qpts[(size_t)node * 96 + tid];
    if (tid < KK) {
        s_j[tid] = Eidx[(size_t)node * KK + tid];
        s_mask[tid] = 100000.0f * (mask_att[(size_t)node * KK + tid] - 1.0f);
    }
    __syncthreads();

    const int h = wv;
    // per-lane hoisted values
    const float q0  = q[(size_t)node * 512 + h * DD + lane];
    const float q1  = q[(size_t)node * 512 + h * DD + 64 + lane];
    const float wb0 = Wb[lane * HH + h];
    const float wb1 = Wb[(lane + 64) * HH + h];
    const float cpt = -0.5f * PT_SCALE * log1pf(expf(head_w[h]));
    const float bbh = INV3 * bb[h];
    const float qpl = (lane < 24) ? s_qp[h * 24 + lane] : 0.f;

    // ---- logits: wave per head, fused single reduction ----
    for (int kx = 0; kx < KK; ++kx) {
        size_t jb = (size_t)(b * NN + s_j[kx]);
        const float* kr = kk + jb * 512 + h * DD;
        float k0 = kr[lane], k1 = kr[lane + 64];
        float he0 = s_hE[kx * DD + lane], he1 = s_hE[kx * DD + 64 + lane];
        float ptc = 0.f;
        if (lane < 24) {
            float d = qpl - kpts[jb * 96 + h * 24 + lane];
            ptc = d * d;
        }
        float val = INV3C * (q0 * k0 + q1 * k1)
                  + INV3  * (he0 * wb0 + he1 * wb1)
                  + cpt * ptc;
        #pragma unroll
        for (int off = 32; off; off >>= 1) val += __shfl_down(val, off);
        if (lane == 0) s_p[h][kx] = val + bbh + s_mask[kx];
    }
    __syncthreads();

    // ---- softmax over k (values live in lanes 0..29 -> 5 levels) ----
    {
        float v = (lane < KK) ? s_p[h][lane] : -INFINITY;
        float m = v;
        #pragma unroll
        for (int off = 16; off; off >>= 1) m = fmaxf(m, __shfl_down(m, off));
        m = __shfl(m, 0);
        float e = (lane < KK) ? expf(v - m) : 0.f;
        float s = e;
        #pragma unroll
        for (int off = 16; off; off >>= 1) s += __shfl_down(s, off);
        s = __shfl(s, 0);
        if (lane < KK) s_p[h][lane] = e / s;
    }
    __syncthreads();

    // ---- o (gathered v) and o_pair (hE from LDS), float2 per thread ----
    {
        const int oh = tid >> 6;           // == wv
        const int oc0 = (tid & 63) * 2;
        float a0 = 0.f, a1 = 0.f;
        for (int kx = 0; kx < KK; ++kx) {
            size_t jb = (size_t)(b * NN + s_j[kx]);
            const float2 v2 = *(const float2*)(vv + jb * 512 + oh * DD + oc0);
            float p = s_p[oh][kx];
            a0 = fmaf(p, v2.x, a0);
            a1 = fmaf(p, v2.y, a1);
        }
        s_cat[oh * DD + oc0]     = a0;
        s_cat[oh * DD + oc0 + 1] = a1;
        float b0 = 0.f, b1 = 0.f;
        for (int kx = 0; kx < KK; ++kx) {
            const float2 e2 = *(const float2*)(s_hE + kx * DD + oc0);
            float p = s_p[oh][kx];
            b0 = fmaf(p, e2.x, b0);
            b1 = fmaf(p, e2.y, b1);
        }
        s_cat[576 + oh * DD + oc0]     = b0;
        s_cat[576 + oh * DD + oc0 + 1] = b1;
    }
    // ---- o_pt (global frame): 16 points x 3 ----
    if (tid < 48) {
        int jj = tid / 3, d = tid % 3;
        int oh = jj >> 2;
        float acc = 0.f;
        for (int kx = 0; kx < KK; ++kx) {
            size_t jb = (size_t)(b * NN + s_j[kx]);
            acc = fmaf(s_p[oh][kx], vpts[jb * 48 + jj * 3 + d], acc);
        }
        s_opt[tid] = acc;
    }
    __syncthreads();
    // ---- inverse rigid + norm (16 points) ----
    if (tid < 16) {
        int jj = tid;
        float g0 = s_opt[jj * 3 + 0] - tvec[node * 3 + 0];
        float g1 = s_opt[jj * 3 + 1] - tvec[node * 3 + 1];
        float g2 = s_opt[jj * 3 + 2] - tvec[node * 3 + 2];
        float l0 = R[node * 9 + 0] * g0 + R[node * 9 + 3] * g1 + R[node * 9 + 6] * g2;
        float l1 = R[node * 9 + 1] * g0 + R[node * 9 + 4] * g1 + R[node * 9 + 7] * g2;
        float l2 = R[node * 9 + 2] * g0 + R[node * 9 + 5] * g1 + R[node * 9 + 8] * g2;
        s_cat[512 + 0 * 16 + jj] = l0;
        s_cat[512 + 1 * 16 + jj] = l1;
        s_cat[512 + 2 * 16 + jj] = l2;
        s_cat[560 + jj] = sqrtf(l0 * l0 + l1 * l1 + l2 * l2 + 1e-8f);
    }
    __syncthreads();

    // ---- s = cat @ Wout : 8 i-groups x 32 col-quads, float4 weight loads ----
    {
        const int quad = tid & 31, grp = tid >> 5;
        const float4* W4 = (const float4*)Wout;   // row i at W4[i*32 + quad]
        float a0 = 0.f, a1 = 0.f, a2 = 0.f, a3 = 0.f;
        const int i0 = grp * 136;
        for (int i = i0; i < i0 + 136; ++i) {
            float x = s_cat[i];
            float4 w = W4[(size_t)i * 32 + quad];
            a0 = fmaf(x, w.x, a0); a1 = fmaf(x, w.y, a1);
            a2 = fmaf(x, w.z, a2); a3 = fmaf(x, w.w, a3);
        }
        ((float4*)s_red)[grp * 32 + quad] = make_float4(a0, a1, a2, a3);
    }
    __syncthreads();
    if (tid < DD) {
        float acc = bout[tid] + hV[(size_t)node * DD + tid];
        #pragma unroll
        for (int g = 0; g < 8; ++g) acc += s_red[g * DD + tid];
        s_x[tid] = acc;
    }
    __syncthreads();
    // ---- LN0 ----
    if (wv == 0) {
        float x0 = s_x[lane], x1 = s_x[lane + 64];
        float ssum = x0 + x1, ssq = x0 * x0 + x1 * x1;
        #pragma unroll
        for (int off = 32; off; off >>= 1) { ssum += __shfl_down(ssum, off); ssq += __shfl_down(ssq, off); }
        if (lane == 0) {
            float mu = ssum / 128.f;
            s_stat[0] = mu;
            s_stat[1] = rsqrtf(ssq / 128.f - mu * mu + 1e-5f);
        }
    }
    __syncthreads();
    if (tid < DD)
        s_hv[tid] = (s_x[tid] - s_stat[0]) * s_stat[1] * ln0w[tid] + ln0b[tid];
    __syncthreads();

    // ---- MLP layer 1: Wm1[128][512], 2 i-groups x 128 col-quads ----
    {
        const int quad = tid & 127, grp = tid >> 7;
        const float4* W4 = (const float4*)Wm1;    // row i at W4[i*128 + quad]
        float a0 = 0.f, a1 = 0.f, a2 = 0.f, a3 = 0.f;
        const int i0 = grp * 64;
        for (int i = i0; i < i0 + 64; ++i) {
            float x = s_hv[i];
            float4 w = W4[i * 128 + quad];
            a0 = fmaf(x, w.x, a0); a1 = fmaf(x, w.y, a1);
            a2 = fmaf(x, w.z, a2); a3 = fmaf(x, w.w, a3);
        }
        ((float4*)s_red)[grp * 128 + quad] = make_float4(a0, a1, a2, a3);
    }
    __syncthreads();
    for (int c = tid; c < 512; c += 256)
        s_m1[c] = fmaxf(s_red[c] + s_red[512 + c] + bm1[c], 0.f);
    __syncthreads();
    // ---- MLP layer 2: Wm2[512][128], 8 i-groups x 32 col-quads ----
    {
        const int quad = tid & 31, grp = tid >> 5;
        const float4* W4 = (const float4*)Wm2;    // row i at W4[i*32 + quad]
        float a0 = 0.f, a1 = 0.f, a2 = 0.f, a3 = 0.f;
        const int i0 = grp * 64;
        for (int i = i0; i < i0 + 64; ++i) {
            float x = s_m1[i];
            float4 w = W4[i * 32 + quad];
            a0 = fmaf(x, w.x, a0); a1 = fmaf(x, w.y, a1);
            a2 = fmaf(x, w.z, a2); a3 = fmaf(x, w.w, a3);
        }
        ((float4*)s_red)[grp * 32 + quad] = make_float4(a0, a1, a2, a3);
    }
    __syncthreads();
    if (tid < DD) {
        float acc = bm2[tid] + s_hv[tid];
        #pragma unroll
        for (int g = 0; g < 8; ++g) acc += s_red[g * DD + tid];
        s_x[tid] = acc;
    }
    __syncthreads();
    // ---- LN1 + mask + store ----
    if (wv == 0) {
        float x0 = s_x[lane], x1 = s_x[lane + 64];
        float ssum = x0 + x1, ssq = x0 * x0 + x1 * x1;
        #pragma unroll
        for (int off = 32; off; off >>= 1) { ssum += __shfl_down(ssum, off); ssq += __shfl_down(ssq, off); }
        if (lane == 0) {
            float mu = ssum / 128.f;
            s_stat[0] = mu;
            s_stat[1] = rsqrtf(ssq / 128.f - mu * mu + 1e-5f);
        }
    }
    __syncthreads();
    if (tid < DD) {
        float o = (s_x[tid] - s_stat[0]) * s_stat[1] * ln1w[tid] + ln1b[tid];
        out[(size_t)node * DD + tid] = o * maskV[node];
    }
}

extern "C" void kernel_launch(void* const* d_in, const int* in_sizes, int n_in,
                              void* d_out, int out_size, void* d_ws, size_t ws_size,
                              hipStream_t stream)
{
    const float* hV      = (const float*)d_in[0];
    const float* hE      = (const float*)d_in[1];
    const int*   Eidx    = (const int*)  d_in[2];
    const float* R       = (const float*)d_in[3];
    const float* tvec    = (const float*)d_in[4];
    const float* mask_at = (const float*)d_in[5];
    const float* maskV   = (const float*)d_in[6];
    const float* Wq      = (const float*)d_in[7];
    const float* bq      = (const float*)d_in[8];
    const float* Wkv     = (const float*)d_in[9];
    const float* bkv     = (const float*)d_in[10];
    const float* Wqp     = (const float*)d_in[11];
    const float* bqp     = (const float*)d_in[12];
    const float* Wkvp    = (const float*)d_in[13];
    const float* bkvp    = (const float*)d_in[14];
    const float* Wb      = (const float*)d_in[15];
    const float* bb      = (const float*)d_in[16];
    const float* hw      = (const float*)d_in[17];
    const float* Wout    = (const float*)d_in[18];
    const float* bout    = (const float*)d_in[19];
    const float* ln0w    = (const float*)d_in[20];
    const float* ln0b    = (const float*)d_in[21];
    const float* ln1w    = (const float*)d_in[22];
    const float* ln1b    = (const float*)d_in[23];
    const float* Wm1     = (const float*)d_in[24];
    const float* bm1     = (const float*)d_in[25];
    const float* Wm2     = (const float*)d_in[26];
    const float* bm2     = (const float*)d_in[27];

    const size_t nodes = (size_t)BB * NN;
    float* ws  = (float*)d_ws;
    float* q   = ws;
    float* kk  = q  + nodes * 512;
    float* vv  = kk + nodes * 512;
    float* qp  = vv + nodes * 512;
    float* kp  = qp + nodes * 96;
    float* vp  = kp + nodes * 96;

    proj_kernel<<<(int)(nodes / NPB), 256, 0, stream>>>(
        hV, R, tvec, Wq, bq, Wkv, bkv, Wqp, bqp, Wkvp, bkvp,
        q, kk, vv, qp, kp, vp);

    attn_kernel<<<(int)nodes, 256, 0, stream>>>(
        hV, hE, Eidx, R, tvec, mask_at, maskV,
        Wb, bb, hw, Wout, bout, ln0w, ln0b, ln1w, ln1b,
        Wm1, bm1, Wm2, bm2,
        q, kk, vv, qp, kp, vp, (float*)d_out);
}

// Round 4
// 246.677 us; speedup vs baseline: 1.5103x; 1.2823x over previous
//
#include <hip/hip_runtime.h>
#include <math.h>

#define BB 2
#define NN 2048
#define KK 30
#define DD 128
#define HH 4
#define PQ_ 8
#define PV_ 4
#define NPB 8
#define NPC 8

#define INV3C    0.05103103630798288f   // sqrt(1/(3*128))
#define INV3     0.5773502691896258f    // sqrt(1/3)
#define PT_SCALE 0.09622504486493764f   // sqrt(1/108)

__global__ __launch_bounds__(256) void proj_kernel(
    const float* __restrict__ hV, const float* __restrict__ R, const float* __restrict__ tvec,
    const float* __restrict__ Wq, const float* __restrict__ bq,
    const float* __restrict__ Wkv, const float* __restrict__ bkv,
    const float* __restrict__ Wqp, const float* __restrict__ bqp,
    const float* __restrict__ Wkvp, const float* __restrict__ bkvp,
    float* __restrict__ q, float* __restrict__ kk, float* __restrict__ vv,
    float* __restrict__ qpts, float* __restrict__ kpts, float* __restrict__ vpts)
{
    const int node0 = blockIdx.x * NPB;
    const int tid = threadIdx.x;
    __shared__ float sx[NPB][DD];
    __shared__ float sqp[NPB][96];
    __shared__ float skvp[NPB][144];

    for (int i = tid; i < NPB * DD; i += 256)
        sx[i >> 7][i & 127] = hV[(size_t)node0 * DD + i];
    __syncthreads();

    for (int c = tid; c < 512; c += 256) {
        float acc[NPB];
        #pragma unroll
        for (int r = 0; r < NPB; ++r) acc[r] = bq[c];
        for (int i = 0; i < DD; ++i) {
            float w = Wq[i * 512 + c];
            #pragma unroll
            for (int r = 0; r < NPB; ++r) acc[r] = fmaf(sx[r][i], w, acc[r]);
        }
        #pragma unroll
        for (int r = 0; r < NPB; ++r) q[(size_t)(node0 + r) * 512 + c] = acc[r];
    }
    for (int c = tid; c < 1024; c += 256) {
        float acc[NPB];
        #pragma unroll
        for (int r = 0; r < NPB; ++r) acc[r] = bkv[c];
        for (int i = 0; i < DD; ++i) {
            float w = Wkv[i * 1024 + c];
            #pragma unroll
            for (int r = 0; r < NPB; ++r) acc[r] = fmaf(sx[r][i], w, acc[r]);
        }
        int h = c >> 8, wcol = c & 255;
        #pragma unroll
        for (int r = 0; r < NPB; ++r) {
            if (wcol < DD) kk[(size_t)(node0 + r) * 512 + h * DD + wcol] = acc[r];
            else           vv[(size_t)(node0 + r) * 512 + h * DD + wcol - DD] = acc[r];
        }
    }
    if (tid < 96) {
        float acc[NPB];
        #pragma unroll
        for (int r = 0; r < NPB; ++r) acc[r] = bqp[tid];
        for (int i = 0; i < DD; ++i) {
            float w = Wqp[i * 96 + tid];
            #pragma unroll
            for (int r = 0; r < NPB; ++r) acc[r] = fmaf(sx[r][i], w, acc[r]);
        }
        #pragma unroll
        for (int r = 0; r < NPB; ++r) sqp[r][tid] = acc[r];
    }
    if (tid >= 112) {
        int c = tid - 112;
        float acc[NPB];
        #pragma unroll
        for (int r = 0; r < NPB; ++r) acc[r] = bkvp[c];
        for (int i = 0; i < DD; ++i) {
            float w = Wkvp[i * 144 + c];
            #pragma unroll
            for (int r = 0; r < NPB; ++r) acc[r] = fmaf(sx[r][i], w, acc[r]);
        }
        #pragma unroll
        for (int r = 0; r < NPB; ++r) skvp[r][c] = acc[r];
    }
    __syncthreads();

    for (int idx = tid; idx < NPB * 96; idx += 256) {
        int r = idx / 96, u = idx % 96;
        int j = u / 3, d = u % 3;
        int node = node0 + r;
        float acc = tvec[node * 3 + d];
        #pragma unroll
        for (int y = 0; y < 3; ++y)
            acc = fmaf(R[node * 9 + d * 3 + y], sqp[r][y * 32 + j], acc);
        qpts[(size_t)node * 96 + j * 3 + d] = acc;
    }
    for (int idx = tid; idx < NPB * 144; idx += 256) {
        int r = idx / 144, u = idx % 144;
        int jj = u / 3, d = u % 3;
        int node = node0 + r;
        float acc = tvec[node * 3 + d];
        #pragma unroll
        for (int y = 0; y < 3; ++y)
            acc = fmaf(R[node * 9 + d * 3 + y], skvp[r][y * 48 + jj], acc);
        int hh = jj / 12, pp = jj % 12;
        if (pp < PQ_) kpts[(size_t)node * 96 + (hh * PQ_ + pp) * 3 + d] = acc;
        else          vpts[(size_t)node * 48 + (hh * PV_ + (pp - PQ_)) * 3 + d] = acc;
    }
}

// ---- attn core: produces cat[1088] per node ----
__global__ __launch_bounds__(256) void attn_kernel(
    const float* __restrict__ hE, const int* __restrict__ Eidx,
    const float* __restrict__ R, const float* __restrict__ tvec,
    const float* __restrict__ mask_att,
    const float* __restrict__ Wb, const float* __restrict__ bb,
    const float* __restrict__ head_w,
    const float* __restrict__ q, const float* __restrict__ kk, const float* __restrict__ vv,
    const float* __restrict__ qpts, const float* __restrict__ kpts, const float* __restrict__ vpts,
    float* __restrict__ catg)
{
    const int node = blockIdx.x;
    const int b = node >> 11;
    const int tid = threadIdx.x;
    const int lane = tid & 63;
    const int wv = tid >> 6;

    __shared__ float s_hE[KK * DD];     // 15360 B
    __shared__ float s_cat[1088];
    __shared__ float s_qp[96];
    __shared__ float s_p[HH][32];
    __shared__ int   s_j[32];
    __shared__ float s_mask[32];
    __shared__ float s_opt[48];

    {
        const float4* src = (const float4*)(hE + (size_t)node * (KK * DD));
        float4* dst = (float4*)s_hE;
        for (int i = tid; i < (KK * DD) / 4; i += 256) dst[i] = src[i];
    }
    if (tid < 96) s_qp[tid] = qpts[(size_t)node * 96 + tid];
    if (tid < KK) {
        s_j[tid] = Eidx[(size_t)node * KK + tid];
        s_mask[tid] = 100000.0f * (mask_att[(size_t)node * KK + tid] - 1.0f);
    }
    __syncthreads();

    const int h = wv;
    const float q0  = q[(size_t)node * 512 + h * DD + lane];
    const float q1  = q[(size_t)node * 512 + h * DD + 64 + lane];
    const float wb0 = Wb[lane * HH + h];
    const float wb1 = Wb[(lane + 64) * HH + h];
    const float cpt = -0.5f * PT_SCALE * log1pf(expf(head_w[h]));
    const float bbh = INV3 * bb[h];
    const float qpl = (lane < 24) ? s_qp[h * 24 + lane] : 0.f;

    // ---- logits ----
    for (int kx = 0; kx < KK; ++kx) {
        size_t jb = (size_t)(b * NN + s_j[kx]);
        const float* kr = kk + jb * 512 + h * DD;
        float k0 = kr[lane], k1 = kr[lane + 64];
        float he0 = s_hE[kx * DD + lane], he1 = s_hE[kx * DD + 64 + lane];
        float ptc = 0.f;
        if (lane < 24) {
            float d = qpl - kpts[jb * 96 + h * 24 + lane];
            ptc = d * d;
        }
        float val = INV3C * (q0 * k0 + q1 * k1)
                  + INV3  * (he0 * wb0 + he1 * wb1)
                  + cpt * ptc;
        #pragma unroll
        for (int off = 32; off; off >>= 1) val += __shfl_down(val, off);
        if (lane == 0) s_p[h][kx] = val + bbh + s_mask[kx];
    }
    __syncthreads();

    // ---- softmax ----
    {
        float v = (lane < KK) ? s_p[h][lane] : -INFINITY;
        float m = v;
        #pragma unroll
        for (int off = 16; off; off >>= 1) m = fmaxf(m, __shfl_down(m, off));
        m = __shfl(m, 0);
        float e = (lane < KK) ? expf(v - m) : 0.f;
        float s = e;
        #pragma unroll
        for (int off = 16; off; off >>= 1) s += __shfl_down(s, off);
        s = __shfl(s, 0);
        if (lane < KK) s_p[h][lane] = e / s;
    }
    __syncthreads();

    // ---- o and o_pair ----
    {
        const int oh = tid >> 6;
        const int oc0 = (tid & 63) * 2;
        float a0 = 0.f, a1 = 0.f;
        for (int kx = 0; kx < KK; ++kx) {
            size_t jb = (size_t)(b * NN + s_j[kx]);
            const float2 v2 = *(const float2*)(vv + jb * 512 + oh * DD + oc0);
            float p = s_p[oh][kx];
            a0 = fmaf(p, v2.x, a0);
            a1 = fmaf(p, v2.y, a1);
        }
        s_cat[oh * DD + oc0]     = a0;
        s_cat[oh * DD + oc0 + 1] = a1;
        float b0 = 0.f, b1 = 0.f;
        for (int kx = 0; kx < KK; ++kx) {
            const float2 e2 = *(const float2*)(s_hE + kx * DD + oc0);
            float p = s_p[oh][kx];
            b0 = fmaf(p, e2.x, b0);
            b1 = fmaf(p, e2.y, b1);
        }
        s_cat[576 + oh * DD + oc0]     = b0;
        s_cat[576 + oh * DD + oc0 + 1] = b1;
    }
    // ---- o_pt ----
    if (tid < 48) {
        int jj = tid / 3, d = tid % 3;
        int oh = jj >> 2;
        float acc = 0.f;
        for (int kx = 0; kx < KK; ++kx) {
            size_t jb = (size_t)(b * NN + s_j[kx]);
            acc = fmaf(s_p[oh][kx], vpts[jb * 48 + jj * 3 + d], acc);
        }
        s_opt[tid] = acc;
    }
    __syncthreads();
    if (tid < 16) {
        int jj = tid;
        float g0 = s_opt[jj * 3 + 0] - tvec[node * 3 + 0];
        float g1 = s_opt[jj * 3 + 1] - tvec[node * 3 + 1];
        float g2 = s_opt[jj * 3 + 2] - tvec[node * 3 + 2];
        float l0 = R[node * 9 + 0] * g0 + R[node * 9 + 3] * g1 + R[node * 9 + 6] * g2;
        float l1 = R[node * 9 + 1] * g0 + R[node * 9 + 4] * g1 + R[node * 9 + 7] * g2;
        float l2 = R[node * 9 + 2] * g0 + R[node * 9 + 5] * g1 + R[node * 9 + 8] * g2;
        s_cat[512 + 0 * 16 + jj] = l0;
        s_cat[512 + 1 * 16 + jj] = l1;
        s_cat[512 + 2 * 16 + jj] = l2;
        s_cat[560 + jj] = sqrtf(l0 * l0 + l1 * l1 + l2 * l2 + 1e-8f);
    }
    __syncthreads();

    // ---- write cat ----
    {
        const float4* src = (const float4*)s_cat;
        float4* dst = (float4*)(catg + (size_t)node * 1088);
        for (int i = tid; i < 1088 / 4; i += 256) dst[i] = src[i];
    }
}

// ---- tail: cat @ Wout + residual + LN0 + MLP + LN1, 8 nodes/block ----
__global__ __launch_bounds__(256) void tail_kernel(
    const float* __restrict__ hV, const float* __restrict__ maskV,
    const float* __restrict__ catg,
    const float* __restrict__ Wout, const float* __restrict__ bout,
    const float* __restrict__ ln0w, const float* __restrict__ ln0b,
    const float* __restrict__ ln1w, const float* __restrict__ ln1b,
    const float* __restrict__ Wm1, const float* __restrict__ bm1,
    const float* __restrict__ Wm2, const float* __restrict__ bm2,
    float* __restrict__ out)
{
    const int node0 = blockIdx.x * NPC;
    const int tid = threadIdx.x;

    __shared__ float s_cat[NPC][1088];    // 34816 B; aliased by s_m1 later
    __shared__ float s_red[2][NPC][DD];   // 8192 B
    __shared__ float s_hv[NPC][DD];
    __shared__ float s_x[NPC][DD];
    __shared__ float s_stat[NPC][2];

    {
        const float4* src = (const float4*)(catg + (size_t)node0 * 1088);
        float4* dst = (float4*)&s_cat[0][0];
        for (int i = tid; i < NPC * 1088 / 4; i += 256) dst[i] = src[i];
    }
    __syncthreads();

    const int c = tid & 127, grp = tid >> 7;

    // ---- Wout GEMV, 8 nodes batched ----
    {
        float acc[NPC];
        #pragma unroll
        for (int r = 0; r < NPC; ++r) acc[r] = 0.f;
        for (int i4 = grp * 136; i4 < grp * 136 + 136; ++i4) {
            const int i = i4 * 4;
            float w0 = Wout[(size_t)(i + 0) * DD + c];
            float w1 = Wout[(size_t)(i + 1) * DD + c];
            float w2 = Wout[(size_t)(i + 2) * DD + c];
            float w3 = Wout[(size_t)(i + 3) * DD + c];
            #pragma unroll
            for (int r = 0; r < NPC; ++r) {
                float4 x = *(const float4*)&s_cat[r][i];
                acc[r] = fmaf(x.x, w0, acc[r]);
                acc[r] = fmaf(x.y, w1, acc[r]);
                acc[r] = fmaf(x.z, w2, acc[r]);
                acc[r] = fmaf(x.w, w3, acc[r]);
            }
        }
        #pragma unroll
        for (int r = 0; r < NPC; ++r) s_red[grp][r][c] = acc[r];
    }
    __syncthreads();
    for (int idx = tid; idx < NPC * DD; idx += 256) {
        int r = idx >> 7, cc = idx & 127;
        s_x[r][cc] = s_red[0][r][cc] + s_red[1][r][cc] + bout[cc]
                   + hV[(size_t)(node0 + r) * DD + cc];
    }
    __syncthreads();
    // ---- LN0: 8 groups of 32 lanes, one node each ----
    {
        int r = tid >> 5, l = tid & 31;
        float4 xv = *(const float4*)&s_x[r][l * 4];
        float ssum = xv.x + xv.y + xv.z + xv.w;
        float ssq = xv.x * xv.x + xv.y * xv.y + xv.z * xv.z + xv.w * xv.w;
        #pragma unroll
        for (int off = 16; off; off >>= 1) { ssum += __shfl_down(ssum, off); ssq += __shfl_down(ssq, off); }
        if (l == 0) {
            float mu = ssum / 128.f;
            s_stat[r][0] = mu;
            s_stat[r][1] = rsqrtf(ssq / 128.f - mu * mu + 1e-5f);
        }
    }
    __syncthreads();
    for (int idx = tid; idx < NPC * DD; idx += 256) {
        int r = idx >> 7, cc = idx & 127;
        s_hv[r][cc] = (s_x[r][cc] - s_stat[r][0]) * s_stat[r][1] * ln0w[cc] + ln0b[cc];
    }
    __syncthreads();

    // ---- MLP1: 128 -> 512, thread owns cols tid and tid+256 ----
    float* s_m1 = &s_cat[0][0];           // alias: [r*512 + c512]
    {
        float acc0[NPC], acc1[NPC];
        #pragma unroll
        for (int r = 0; r < NPC; ++r) { acc0[r] = 0.f; acc1[r] = 0.f; }
        for (int i4 = 0; i4 < 32; ++i4) {
            const int i = i4 * 4;
            float w00 = Wm1[(i + 0) * 512 + tid], w10 = Wm1[(i + 0) * 512 + tid + 256];
            float w01 = Wm1[(i + 1) * 512 + tid], w11 = Wm1[(i + 1) * 512 + tid + 256];
            float w02 = Wm1[(i + 2) * 512 + tid], w12 = Wm1[(i + 2) * 512 + tid + 256];
            float w03 = Wm1[(i + 3) * 512 + tid], w13 = Wm1[(i + 3) * 512 + tid + 256];
            #pragma unroll
            for (int r = 0; r < NPC; ++r) {
                float4 x = *(const float4*)&s_hv[r][i];
                acc0[r] = fmaf(x.x, w00, acc0[r]); acc1[r] = fmaf(x.x, w10, acc1[r]);
                acc0[r] = fmaf(x.y, w01, acc0[r]); acc1[r] = fmaf(x.y, w11, acc1[r]);
                acc0[r] = fmaf(x.z, w02, acc0[r]); acc1[r] = fmaf(x.z, w12, acc1[r]);
                acc0[r] = fmaf(x.w, w03, acc0[r]); acc1[r] = fmaf(x.w, w13, acc1[r]);
            }
        }
        float b0 = bm1[tid], b1 = bm1[tid + 256];
        #pragma unroll
        for (int r = 0; r < NPC; ++r) {
            s_m1[r * 512 + tid]       = fmaxf(acc0[r] + b0, 0.f);
            s_m1[r * 512 + tid + 256] = fmaxf(acc1[r] + b1, 0.f);
        }
    }
    __syncthreads();
    // ---- MLP2: 512 -> 128 ----
    {
        float acc[NPC];
        #pragma unroll
        for (int r = 0; r < NPC; ++r) acc[r] = 0.f;
        for (int i4 = grp * 64; i4 < grp * 64 + 64; ++i4) {
            const int i = i4 * 4;
            float w0 = Wm2[(i + 0) * DD + c];
            float w1 = Wm2[(i + 1) * DD + c];
            float w2 = Wm2[(i + 2) * DD + c];
            float w3 = Wm2[(i + 3) * DD + c];
            #pragma unroll
            for (int r = 0; r < NPC; ++r) {
                float4 x = *(const float4*)&s_m1[r * 512 + i];
                acc[r] = fmaf(x.x, w0, acc[r]);
                acc[r] = fmaf(x.y, w1, acc[r]);
                acc[r] = fmaf(x.z, w2, acc[r]);
                acc[r] = fmaf(x.w, w3, acc[r]);
            }
        }
        #pragma unroll
        for (int r = 0; r < NPC; ++r) s_red[grp][r][c] = acc[r];
    }
    __syncthreads();
    for (int idx = tid; idx < NPC * DD; idx += 256) {
        int r = idx >> 7, cc = idx & 127;
        s_x[r][cc] = s_red[0][r][cc] + s_red[1][r][cc] + bm2[cc] + s_hv[r][cc];
    }
    __syncthreads();
    // ---- LN1 ----
    {
        int r = tid >> 5, l = tid & 31;
        float4 xv = *(const float4*)&s_x[r][l * 4];
        float ssum = xv.x + xv.y + xv.z + xv.w;
        float ssq = xv.x * xv.x + xv.y * xv.y + xv.z * xv.z + xv.w * xv.w;
        #pragma unroll
        for (int off = 16; off; off >>= 1) { ssum += __shfl_down(ssum, off); ssq += __shfl_down(ssq, off); }
        if (l == 0) {
            float mu = ssum / 128.f;
            s_stat[r][0] = mu;
            s_stat[r][1] = rsqrtf(ssq / 128.f - mu * mu + 1e-5f);
        }
    }
    __syncthreads();
    for (int idx = tid; idx < NPC * DD; idx += 256) {
        int r = idx >> 7, cc = idx & 127;
        float o = (s_x[r][cc] - s_stat[r][0]) * s_stat[r][1] * ln1w[cc] + ln1b[cc];
        out[(size_t)(node0 + r) * DD + cc] = o * maskV[node0 + r];
    }
}

extern "C" void kernel_launch(void* const* d_in, const int* in_sizes, int n_in,
                              void* d_out, int out_size, void* d_ws, size_t ws_size,
                              hipStream_t stream)
{
    const float* hV      = (const float*)d_in[0];
    const float* hE      = (const float*)d_in[1];
    const int*   Eidx    = (const int*)  d_in[2];
    const float* R       = (const float*)d_in[3];
    const float* tvec    = (const float*)d_in[4];
    const float* mask_at = (const float*)d_in[5];
    const float* maskV   = (const float*)d_in[6];
    const float* Wq      = (const float*)d_in[7];
    const float* bq      = (const float*)d_in[8];
    const float* Wkv     = (const float*)d_in[9];
    const float* bkv     = (const float*)d_in[10];
    const float* Wqp     = (const float*)d_in[11];
    const float* bqp     = (const float*)d_in[12];
    const float* Wkvp    = (const float*)d_in[13];
    const float* bkvp    = (const float*)d_in[14];
    const float* Wb      = (const float*)d_in[15];
    const float* bb      = (const float*)d_in[16];
    const float* hw      = (const float*)d_in[17];
    const float* Wout    = (const float*)d_in[18];
    const float* bout    = (const float*)d_in[19];
    const float* ln0w    = (const float*)d_in[20];
    const float* ln0b    = (const float*)d_in[21];
    const float* ln1w    = (const float*)d_in[22];
    const float* ln1b    = (const float*)d_in[23];
    const float* Wm1     = (const float*)d_in[24];
    const float* bm1     = (const float*)d_in[25];
    const float* Wm2     = (const float*)d_in[26];
    const float* bm2     = (const float*)d_in[27];

    const size_t nodes = (size_t)BB * NN;
    float* ws  = (float*)d_ws;
    float* q   = ws;
    float* kk  = q   + nodes * 512;
    float* vv  = kk  + nodes * 512;
    float* qp  = vv  + nodes * 512;
    float* kp  = qp  + nodes * 96;
    float* vp  = kp  + nodes * 96;
    float* cat = vp  + nodes * 48;

    proj_kernel<<<(int)(nodes / NPB), 256, 0, stream>>>(
        hV, R, tvec, Wq, bq, Wkv, bkv, Wqp, bqp, Wkvp, bkvp,
        q, kk, vv, qp, kp, vp);

    attn_kernel<<<(int)nodes, 256, 0, stream>>>(
        hE, Eidx, R, tvec, mask_at,
        Wb, bb, hw,
        q, kk, vv, qp, kp, vp, cat);

    tail_kernel<<<(int)(nodes / NPC), 256, 0, stream>>>(
        hV, maskV, cat,
        Wout, bout, ln0w, ln0b, ln1w, ln1b,
        Wm1, bm1, Wm2, bm2, (float*)d_out);
}

// Round 5
// 209.750 us; speedup vs baseline: 1.7762x; 1.1760x over previous
//
#include <hip/hip_runtime.h>
#include <math.h>

#define BB 2
#define NN 2048
#define KK 30
#define DD 128
#define HH 4
#define PQ_ 8
#define PV_ 4
#define NPB 8
#define NPC 8

#define INV3C    0.05103103630798288f   // sqrt(1/(3*128))
#define INV3     0.5773502691896258f    // sqrt(1/3)
#define PT_SCALE 0.09622504486493764f   // sqrt(1/108)

__device__ __forceinline__ void fma4(float4& a, float s, const float4& w) {
    a.x = fmaf(s, w.x, a.x);
    a.y = fmaf(s, w.y, a.y);
    a.z = fmaf(s, w.z, a.z);
    a.w = fmaf(s, w.w, a.w);
}

// Projections restructured: 444 col-quads x 8 nodes per thread-task.
// Per K-chunk of 4: 4 float4 weight loads + 8 float4 LDS broadcasts -> 128 FMA.
__global__ __launch_bounds__(256) void proj_kernel(
    const float* __restrict__ hV, const float* __restrict__ R, const float* __restrict__ tvec,
    const float* __restrict__ Wq, const float* __restrict__ bq,
    const float* __restrict__ Wkv, const float* __restrict__ bkv,
    const float* __restrict__ Wqp, const float* __restrict__ bqp,
    const float* __restrict__ Wkvp, const float* __restrict__ bkvp,
    float* __restrict__ q, float* __restrict__ kk, float* __restrict__ vv,
    float* __restrict__ qpts, float* __restrict__ kpts, float* __restrict__ vpts)
{
    const int node0 = blockIdx.x * NPB;
    const int tid = threadIdx.x;
    __shared__ float4 sx4[NPB][32];     // x for 8 nodes
    __shared__ float4 sqp4[NPB][24];    // qp pre-rigid (96 cols)
    __shared__ float4 skvp4[NPB][36];   // kvp pre-rigid (144 cols)

    {
        const float4* src = (const float4*)(hV + (size_t)node0 * DD);
        sx4[tid >> 5][tid & 31] = src[tid];
    }
    __syncthreads();

    for (int Q = tid; Q < 444; Q += 256) {
        const float* W; const float* bias; int ncols, col, dest;
        if (Q < 128)      { W = Wq;   bias = bq;   ncols = 512;  col = Q * 4;         dest = 0; }
        else if (Q < 384) { W = Wkv;  bias = bkv;  ncols = 1024; col = (Q - 128) * 4; dest = 1; }
        else if (Q < 408) { W = Wqp;  bias = bqp;  ncols = 96;   col = (Q - 384) * 4; dest = 2; }
        else              { W = Wkvp; bias = bkvp; ncols = 144;  col = (Q - 408) * 4; dest = 3; }

        float4 acc[NPB];
        #pragma unroll
        for (int r = 0; r < NPB; ++r) acc[r] = make_float4(0.f, 0.f, 0.f, 0.f);

        for (int i = 0; i < DD; i += 4) {
            float4 w0 = *(const float4*)&W[(size_t)(i + 0) * ncols + col];
            float4 w1 = *(const float4*)&W[(size_t)(i + 1) * ncols + col];
            float4 w2 = *(const float4*)&W[(size_t)(i + 2) * ncols + col];
            float4 w3 = *(const float4*)&W[(size_t)(i + 3) * ncols + col];
            #pragma unroll
            for (int r = 0; r < NPB; ++r) {
                float4 x = sx4[r][i >> 2];
                fma4(acc[r], x.x, w0);
                fma4(acc[r], x.y, w1);
                fma4(acc[r], x.z, w2);
                fma4(acc[r], x.w, w3);
            }
        }

        float4 bv = *(const float4*)&bias[col];
        if (dest == 0) {
            #pragma unroll
            for (int r = 0; r < NPB; ++r) {
                float4 o = make_float4(acc[r].x + bv.x, acc[r].y + bv.y,
                                       acc[r].z + bv.z, acc[r].w + bv.w);
                *(float4*)&q[(size_t)(node0 + r) * 512 + col] = o;
            }
        } else if (dest == 1) {
            int h = col >> 8, wcol = col & 255;
            float* base = (wcol < 128) ? kk : vv;
            int off = h * DD + (wcol & 127);
            #pragma unroll
            for (int r = 0; r < NPB; ++r) {
                float4 o = make_float4(acc[r].x + bv.x, acc[r].y + bv.y,
                                       acc[r].z + bv.z, acc[r].w + bv.w);
                *(float4*)&base[(size_t)(node0 + r) * 512 + off] = o;
            }
        } else if (dest == 2) {
            #pragma unroll
            for (int r = 0; r < NPB; ++r) {
                float4 o = make_float4(acc[r].x + bv.x, acc[r].y + bv.y,
                                       acc[r].z + bv.z, acc[r].w + bv.w);
                sqp4[r][col >> 2] = o;
            }
        } else {
            #pragma unroll
            for (int r = 0; r < NPB; ++r) {
                float4 o = make_float4(acc[r].x + bv.x, acc[r].y + bv.y,
                                       acc[r].z + bv.z, acc[r].w + bv.w);
                skvp4[r][col >> 2] = o;
            }
        }
    }
    __syncthreads();

    const float* sqp_s  = (const float*)&sqp4[0][0];    // [r*96 + c]
    const float* skvp_s = (const float*)&skvp4[0][0];   // [r*144 + c]

    // rigid transform q_pts: out[x] = sum_y R[x,y]*p[y] + t[x]
    for (int idx = tid; idx < NPB * 96; idx += 256) {
        int r = idx / 96, u = idx % 96;
        int j = u / 3, d = u % 3;
        int node = node0 + r;
        float acc = tvec[node * 3 + d];
        #pragma unroll
        for (int y = 0; y < 3; ++y)
            acc = fmaf(R[node * 9 + d * 3 + y], sqp_s[r * 96 + y * 32 + j], acc);
        qpts[(size_t)node * 96 + j * 3 + d] = acc;
    }
    // rigid transform kv_pts, split into k_pts / v_pts
    for (int idx = tid; idx < NPB * 144; idx += 256) {
        int r = idx / 144, u = idx % 144;
        int jj = u / 3, d = u % 3;
        int node = node0 + r;
        float acc = tvec[node * 3 + d];
        #pragma unroll
        for (int y = 0; y < 3; ++y)
            acc = fmaf(R[node * 9 + d * 3 + y], skvp_s[r * 144 + y * 48 + jj], acc);
        int hh = jj / 12, pp = jj % 12;
        if (pp < PQ_) kpts[(size_t)node * 96 + (hh * PQ_ + pp) * 3 + d] = acc;
        else          vpts[(size_t)node * 48 + (hh * PV_ + (pp - PQ_)) * 3 + d] = acc;
    }
}

// ---- attn core: produces cat[1088] per node ----
__global__ __launch_bounds__(256) void attn_kernel(
    const float* __restrict__ hE, const int* __restrict__ Eidx,
    const float* __restrict__ R, const float* __restrict__ tvec,
    const float* __restrict__ mask_att,
    const float* __restrict__ Wb, const float* __restrict__ bb,
    const float* __restrict__ head_w,
    const float* __restrict__ q, const float* __restrict__ kk, const float* __restrict__ vv,
    const float* __restrict__ qpts, const float* __restrict__ kpts, const float* __restrict__ vpts,
    float* __restrict__ catg)
{
    const int node = blockIdx.x;
    const int b = node >> 11;
    const int tid = threadIdx.x;
    const int lane = tid & 63;
    const int wv = tid >> 6;

    __shared__ float s_hE[KK * DD];     // 15360 B
    __shared__ float s_cat[1088];
    __shared__ float s_qp[96];
    __shared__ float s_p[HH][32];
    __shared__ int   s_j[32];
    __shared__ float s_mask[32];
    __shared__ float s_opt[48];

    {
        const float4* src = (const float4*)(hE + (size_t)node * (KK * DD));
        float4* dst = (float4*)s_hE;
        for (int i = tid; i < (KK * DD) / 4; i += 256) dst[i] = src[i];
    }
    if (tid < 96) s_qp[tid] = qpts[(size_t)node * 96 + tid];
    if (tid < KK) {
        s_j[tid] = Eidx[(size_t)node * KK + tid];
        s_mask[tid] = 100000.0f * (mask_att[(size_t)node * KK + tid] - 1.0f);
    }
    __syncthreads();

    const int h = wv;
    const float q0  = q[(size_t)node * 512 + h * DD + lane];
    const float q1  = q[(size_t)node * 512 + h * DD + 64 + lane];
    const float wb0 = Wb[lane * HH + h];
    const float wb1 = Wb[(lane + 64) * HH + h];
    const float cpt = -0.5f * PT_SCALE * log1pf(expf(head_w[h]));
    const float bbh = INV3 * bb[h];
    const float qpl = (lane < 24) ? s_qp[h * 24 + lane] : 0.f;

    // ---- logits ----
    for (int kx = 0; kx < KK; ++kx) {
        size_t jb = (size_t)(b * NN + s_j[kx]);
        const float* kr = kk + jb * 512 + h * DD;
        float k0 = kr[lane], k1 = kr[lane + 64];
        float he0 = s_hE[kx * DD + lane], he1 = s_hE[kx * DD + 64 + lane];
        float ptc = 0.f;
        if (lane < 24) {
            float d = qpl - kpts[jb * 96 + h * 24 + lane];
            ptc = d * d;
        }
        float val = INV3C * (q0 * k0 + q1 * k1)
                  + INV3  * (he0 * wb0 + he1 * wb1)
                  + cpt * ptc;
        #pragma unroll
        for (int off = 32; off; off >>= 1) val += __shfl_down(val, off);
        if (lane == 0) s_p[h][kx] = val + bbh + s_mask[kx];
    }
    __syncthreads();

    // ---- softmax ----
    {
        float v = (lane < KK) ? s_p[h][lane] : -INFINITY;
        float m = v;
        #pragma unroll
        for (int off = 16; off; off >>= 1) m = fmaxf(m, __shfl_down(m, off));
        m = __shfl(m, 0);
        float e = (lane < KK) ? expf(v - m) : 0.f;
        float s = e;
        #pragma unroll
        for (int off = 16; off; off >>= 1) s += __shfl_down(s, off);
        s = __shfl(s, 0);
        if (lane < KK) s_p[h][lane] = e / s;
    }
    __syncthreads();

    // ---- o and o_pair ----
    {
        const int oh = tid >> 6;
        const int oc0 = (tid & 63) * 2;
        float a0 = 0.f, a1 = 0.f;
        for (int kx = 0; kx < KK; ++kx) {
            size_t jb = (size_t)(b * NN + s_j[kx]);
            const float2 v2 = *(const float2*)(vv + jb * 512 + oh * DD + oc0);
            float p = s_p[oh][kx];
            a0 = fmaf(p, v2.x, a0);
            a1 = fmaf(p, v2.y, a1);
        }
        s_cat[oh * DD + oc0]     = a0;
        s_cat[oh * DD + oc0 + 1] = a1;
        float b0 = 0.f, b1 = 0.f;
        for (int kx = 0; kx < KK; ++kx) {
            const float2 e2 = *(const float2*)(s_hE + kx * DD + oc0);
            float p = s_p[oh][kx];
            b0 = fmaf(p, e2.x, b0);
            b1 = fmaf(p, e2.y, b1);
        }
        s_cat[576 + oh * DD + oc0]     = b0;
        s_cat[576 + oh * DD + oc0 + 1] = b1;
    }
    // ---- o_pt ----
    if (tid < 48) {
        int jj = tid / 3, d = tid % 3;
        int oh = jj >> 2;
        float acc = 0.f;
        for (int kx = 0; kx < KK; ++kx) {
            size_t jb = (size_t)(b * NN + s_j[kx]);
            acc = fmaf(s_p[oh][kx], vpts[jb * 48 + jj * 3 + d], acc);
        }
        s_opt[tid] = acc;
    }
    __syncthreads();
    if (tid < 16) {
        int jj = tid;
        float g0 = s_opt[jj * 3 + 0] - tvec[node * 3 + 0];
        float g1 = s_opt[jj * 3 + 1] - tvec[node * 3 + 1];
        float g2 = s_opt[jj * 3 + 2] - tvec[node * 3 + 2];
        float l0 = R[node * 9 + 0] * g0 + R[node * 9 + 3] * g1 + R[node * 9 + 6] * g2;
        float l1 = R[node * 9 + 1] * g0 + R[node * 9 + 4] * g1 + R[node * 9 + 7] * g2;
        float l2 = R[node * 9 + 2] * g0 + R[node * 9 + 5] * g1 + R[node * 9 + 8] * g2;
        s_cat[512 + 0 * 16 + jj] = l0;
        s_cat[512 + 1 * 16 + jj] = l1;
        s_cat[512 + 2 * 16 + jj] = l2;
        s_cat[560 + jj] = sqrtf(l0 * l0 + l1 * l1 + l2 * l2 + 1e-8f);
    }
    __syncthreads();

    // ---- write cat ----
    {
        const float4* src = (const float4*)s_cat;
        float4* dst = (float4*)(catg + (size_t)node * 1088);
        for (int i = tid; i < 1088 / 4; i += 256) dst[i] = src[i];
    }
}

// ---- tail: cat @ Wout + residual + LN0 + MLP + LN1, 8 nodes/block ----
__global__ __launch_bounds__(256) void tail_kernel(
    const float* __restrict__ hV, const float* __restrict__ maskV,
    const float* __restrict__ catg,
    const float* __restrict__ Wout, const float* __restrict__ bout,
    const float* __restrict__ ln0w, const float* __restrict__ ln0b,
    const float* __restrict__ ln1w, const float* __restrict__ ln1b,
    const float* __restrict__ Wm1, const float* __restrict__ bm1,
    const float* __restrict__ Wm2, const float* __restrict__ bm2,
    float* __restrict__ out)
{
    const int node0 = blockIdx.x * NPC;
    const int tid = threadIdx.x;

    __shared__ float s_cat[NPC][1088];    // 34816 B; aliased by s_m1 later
    __shared__ float s_red[2][NPC][DD];   // 8192 B
    __shared__ float s_hv[NPC][DD];
    __shared__ float s_x[NPC][DD];
    __shared__ float s_stat[NPC][2];

    {
        const float4* src = (const float4*)(catg + (size_t)node0 * 1088);
        float4* dst = (float4*)&s_cat[0][0];
        for (int i = tid; i < NPC * 1088 / 4; i += 256) dst[i] = src[i];
    }
    __syncthreads();

    const int c = tid & 127, grp = tid >> 7;

    // ---- Wout GEMV, 8 nodes batched ----
    {
        float acc[NPC];
        #pragma unroll
        for (int r = 0; r < NPC; ++r) acc[r] = 0.f;
        for (int i4 = grp * 136; i4 < grp * 136 + 136; ++i4) {
            const int i = i4 * 4;
            float w0 = Wout[(size_t)(i + 0) * DD + c];
            float w1 = Wout[(size_t)(i + 1) * DD + c];
            float w2 = Wout[(size_t)(i + 2) * DD + c];
            float w3 = Wout[(size_t)(i + 3) * DD + c];
            #pragma unroll
            for (int r = 0; r < NPC; ++r) {
                float4 x = *(const float4*)&s_cat[r][i];
                acc[r] = fmaf(x.x, w0, acc[r]);
                acc[r] = fmaf(x.y, w1, acc[r]);
                acc[r] = fmaf(x.z, w2, acc[r]);
                acc[r] = fmaf(x.w, w3, acc[r]);
            }
        }
        #pragma unroll
        for (int r = 0; r < NPC; ++r) s_red[grp][r][c] = acc[r];
    }
    __syncthreads();
    for (int idx = tid; idx < NPC * DD; idx += 256) {
        int r = idx >> 7, cc = idx & 127;
        s_x[r][cc] = s_red[0][r][cc] + s_red[1][r][cc] + bout[cc]
                   + hV[(size_t)(node0 + r) * DD + cc];
    }
    __syncthreads();
    // ---- LN0: 8 groups of 32 lanes, one node each ----
    {
        int r = tid >> 5, l = tid & 31;
        float4 xv = *(const float4*)&s_x[r][l * 4];
        float ssum = xv.x + xv.y + xv.z + xv.w;
        float ssq = xv.x * xv.x + xv.y * xv.y + xv.z * xv.z + xv.w * xv.w;
        #pragma unroll
        for (int off = 16; off; off >>= 1) { ssum += __shfl_down(ssum, off); ssq += __shfl_down(ssq, off); }
        if (l == 0) {
            float mu = ssum / 128.f;
            s_stat[r][0] = mu;
            s_stat[r][1] = rsqrtf(ssq / 128.f - mu * mu + 1e-5f);
        }
    }
    __syncthreads();
    for (int idx = tid; idx < NPC * DD; idx += 256) {
        int r = idx >> 7, cc = idx & 127;
        s_hv[r][cc] = (s_x[r][cc] - s_stat[r][0]) * s_stat[r][1] * ln0w[cc] + ln0b[cc];
    }
    __syncthreads();

    // ---- MLP1: 128 -> 512, thread owns cols tid and tid+256 ----
    float* s_m1 = &s_cat[0][0];           // alias: [r*512 + c512]
    {
        float acc0[NPC], acc1[NPC];
        #pragma unroll
        for (int r = 0; r < NPC; ++r) { acc0[r] = 0.f; acc1[r] = 0.f; }
        for (int i4 = 0; i4 < 32; ++i4) {
            const int i = i4 * 4;
            float w00 = Wm1[(i + 0) * 512 + tid], w10 = Wm1[(i + 0) * 512 + tid + 256];
            float w01 = Wm1[(i + 1) * 512 + tid], w11 = Wm1[(i + 1) * 512 + tid + 256];
            float w02 = Wm1[(i + 2) * 512 + tid], w12 = Wm1[(i + 2) * 512 + tid + 256];
            float w03 = Wm1[(i + 3) * 512 + tid], w13 = Wm1[(i + 3) * 512 + tid + 256];
            #pragma unroll
            for (int r = 0; r < NPC; ++r) {
                float4 x = *(const float4*)&s_hv[r][i];
                acc0[r] = fmaf(x.x, w00, acc0[r]); acc1[r] = fmaf(x.x, w10, acc1[r]);
                acc0[r] = fmaf(x.y, w01, acc0[r]); acc1[r] = fmaf(x.y, w11, acc1[r]);
                acc0[r] = fmaf(x.z, w02, acc0[r]); acc1[r] = fmaf(x.z, w12, acc1[r]);
                acc0[r] = fmaf(x.w, w03, acc0[r]); acc1[r] = fmaf(x.w, w13, acc1[r]);
            }
        }
        float b0 = bm1[tid], b1 = bm1[tid + 256];
        #pragma unroll
        for (int r = 0; r < NPC; ++r) {
            s_m1[r * 512 + tid]       = fmaxf(acc0[r] + b0, 0.f);
            s_m1[r * 512 + tid + 256] = fmaxf(acc1[r] + b1, 0.f);
        }
    }
    __syncthreads();
    // ---- MLP2: 512 -> 128 ----
    {
        float acc[NPC];
        #pragma unroll
        for (int r = 0; r < NPC; ++r) acc[r] = 0.f;
        for (int i4 = grp * 64; i4 < grp * 64 + 64; ++i4) {
            const int i = i4 * 4;
            float w0 = Wm2[(i + 0) * DD + c];
            float w1 = Wm2[(i + 1) * DD + c];
            float w2 = Wm2[(i + 2) * DD + c];
            float w3 = Wm2[(i + 3) * DD + c];
            #pragma unroll
            for (int r = 0; r < NPC; ++r) {
                float4 x = *(const float4*)&s_m1[r * 512 + i];
                acc[r] = fmaf(x.x, w0, acc[r]);
                acc[r] = fmaf(x.y, w1, acc[r]);
                acc[r] = fmaf(x.z, w2, acc[r]);
                acc[r] = fmaf(x.w, w3, acc[r]);
            }
        }
        #pragma unroll
        for (int r = 0; r < NPC; ++r) s_red[grp][r][c] = acc[r];
    }
    __syncthreads();
    for (int idx = tid; idx < NPC * DD; idx += 256) {
        int r = idx >> 7, cc = idx & 127;
        s_x[r][cc] = s_red[0][r][cc] + s_red[1][r][cc] + bm2[cc] + s_hv[r][cc];
    }
    __syncthreads();
    // ---- LN1 ----
    {
        int r = tid >> 5, l = tid & 31;
        float4 xv = *(const float4*)&s_x[r][l * 4];
        float ssum = xv.x + xv.y + xv.z + xv.w;
        float ssq = xv.x * xv.x + xv.y * xv.y + xv.z * xv.z + xv.w * xv.w;
        #pragma unroll
        for (int off = 16; off; off >>= 1) { ssum += __shfl_down(ssum, off); ssq += __shfl_down(ssq, off); }
        if (l == 0) {
            float mu = ssum / 128.f;
            s_stat[r][0] = mu;
            s_stat[r][1] = rsqrtf(ssq / 128.f - mu * mu + 1e-5f);
        }
    }
    __syncthreads();
    for (int idx = tid; idx < NPC * DD; idx += 256) {
        int r = idx >> 7, cc = idx & 127;
        float o = (s_x[r][cc] - s_stat[r][0]) * s_stat[r][1] * ln1w[cc] + ln1b[cc];
        out[(size_t)(node0 + r) * DD + cc] = o * maskV[node0 + r];
    }
}

extern "C" void kernel_launch(void* const* d_in, const int* in_sizes, int n_in,
                              void* d_out, int out_size, void* d_ws, size_t ws_size,
                              hipStream_t stream)
{
    const float* hV      = (const float*)d_in[0];
    const float* hE      = (const float*)d_in[1];
    const int*   Eidx    = (const int*)  d_in[2];
    const float* R       = (const float*)d_in[3];
    const float* tvec    = (const float*)d_in[4];
    const float* mask_at = (const float*)d_in[5];
    const float* maskV   = (const float*)d_in[6];
    const float* Wq      = (const float*)d_in[7];
    const float* bq      = (const float*)d_in[8];
    const float* Wkv     = (const float*)d_in[9];
    const float* bkv     = (const float*)d_in[10];
    const float* Wqp     = (const float*)d_in[11];
    const float* bqp     = (const float*)d_in[12];
    const float* Wkvp    = (const float*)d_in[13];
    const float* bkvp    = (const float*)d_in[14];
    const float* Wb      = (const float*)d_in[15];
    const float* bb      = (const float*)d_in[16];
    const float* hw      = (const float*)d_in[17];
    const float* Wout    = (const float*)d_in[18];
    const float* bout    = (const float*)d_in[19];
    const float* ln0w    = (const float*)d_in[20];
    const float* ln0b    = (const float*)d_in[21];
    const float* ln1w    = (const float*)d_in[22];
    const float* ln1b    = (const float*)d_in[23];
    const float* Wm1     = (const float*)d_in[24];
    const float* bm1     = (const float*)d_in[25];
    const float* Wm2     = (const float*)d_in[26];
    const float* bm2     = (const float*)d_in[27];

    const size_t nodes = (size_t)BB * NN;
    float* ws  = (float*)d_ws;
    float* q   = ws;
    float* kk  = q   + nodes * 512;
    float* vv  = kk  + nodes * 512;
    float* qp  = vv  + nodes * 512;
    float* kp  = qp  + nodes * 96;
    float* vp  = kp  + nodes * 96;
    float* cat = vp  + nodes * 48;

    proj_kernel<<<(int)(nodes / NPB), 256, 0, stream>>>(
        hV, R, tvec, Wq, bq, Wkv, bkv, Wqp, bqp, Wkvp, bkvp,
        q, kk, vv, qp, kp, vp);

    attn_kernel<<<(int)nodes, 256, 0, stream>>>(
        hE, Eidx, R, tvec, mask_at,
        Wb, bb, hw,
        q, kk, vv, qp, kp, vp, cat);

    tail_kernel<<<(int)(nodes / NPC), 256, 0, stream>>>(
        hV, maskV, cat,
        Wout, bout, ln0w, ln0b, ln1w, ln1b,
        Wm1, bm1, Wm2, bm2, (float*)d_out);
}

// Round 6
// 169.041 us; speedup vs baseline: 2.2040x; 1.2408x over previous
//
#include <hip/hip_runtime.h>
#include <math.h>

#define BB 2
#define NN 2048
#define KK 30
#define DD 128
#define HH 4
#define PQ_ 8
#define PV_ 4
#define NPB 8
#define NPC 8

#define INV3C    0.05103103630798288f   // sqrt(1/(3*128))
#define INV3     0.5773502691896258f    // sqrt(1/3)
#define PT_SCALE 0.09622504486493764f   // sqrt(1/108)

__device__ __forceinline__ void fma4(float4& a, float s, const float4& w) {
    a.x = fmaf(s, w.x, a.x);
    a.y = fmaf(s, w.y, a.y);
    a.z = fmaf(s, w.z, a.z);
    a.w = fmaf(s, w.w, a.w);
}

// Projections: 444 col-quad tasks split across 2 blocks per node-group
// (column split => same total weight traffic, 2x blocks for latency hiding).
// Inner K-loop uses explicit 2-stage weight prefetch.
__global__ __launch_bounds__(256, 4) void proj_kernel(
    const float* __restrict__ hV, const float* __restrict__ R, const float* __restrict__ tvec,
    const float* __restrict__ Wq, const float* __restrict__ bq,
    const float* __restrict__ Wkv, const float* __restrict__ bkv,
    const float* __restrict__ Wqp, const float* __restrict__ bqp,
    const float* __restrict__ Wkvp, const float* __restrict__ bkvp,
    float* __restrict__ q, float* __restrict__ kk, float* __restrict__ vv,
    float* __restrict__ qpts, float* __restrict__ kpts, float* __restrict__ vpts)
{
    const int node0 = (blockIdx.x >> 1) * NPB;
    const int half  = blockIdx.x & 1;
    const int tid = threadIdx.x;
    __shared__ float4 sx4[NPB][32];     // x for 8 nodes
    __shared__ float4 sqp4[NPB][24];    // qp pre-rigid (96 cols)   [half 1 only]
    __shared__ float4 skvp4[NPB][36];   // kvp pre-rigid (144 cols) [half 1 only]

    {
        const float4* src = (const float4*)(hV + (size_t)node0 * DD);
        sx4[tid >> 5][tid & 31] = src[tid];
    }
    __syncthreads();

    if (tid < 222) {
        const int Q = half * 222 + tid;
        const float* W; const float* bias; int ncols, col, dest;
        if (Q < 128)      { W = Wq;   bias = bq;   ncols = 512;  col = Q * 4;         dest = 0; }
        else if (Q < 384) { W = Wkv;  bias = bkv;  ncols = 1024; col = (Q - 128) * 4; dest = 1; }
        else if (Q < 408) { W = Wqp;  bias = bqp;  ncols = 96;   col = (Q - 384) * 4; dest = 2; }
        else              { W = Wkvp; bias = bkvp; ncols = 144;  col = (Q - 408) * 4; dest = 3; }

        float4 acc[NPB];
        #pragma unroll
        for (int r = 0; r < NPB; ++r) acc[r] = make_float4(0.f, 0.f, 0.f, 0.f);

        // 2-stage software pipeline on weight loads
        float4 w0 = *(const float4*)&W[(size_t)0 * ncols + col];
        float4 w1 = *(const float4*)&W[(size_t)1 * ncols + col];
        float4 w2 = *(const float4*)&W[(size_t)2 * ncols + col];
        float4 w3 = *(const float4*)&W[(size_t)3 * ncols + col];
        for (int i = 0; i < DD; i += 4) {
            float4 n0, n1, n2, n3;
            if (i + 4 < DD) {
                n0 = *(const float4*)&W[(size_t)(i + 4) * ncols + col];
                n1 = *(const float4*)&W[(size_t)(i + 5) * ncols + col];
                n2 = *(const float4*)&W[(size_t)(i + 6) * ncols + col];
                n3 = *(const float4*)&W[(size_t)(i + 7) * ncols + col];
            }
            #pragma unroll
            for (int r = 0; r < NPB; ++r) {
                float4 x = sx4[r][i >> 2];
                fma4(acc[r], x.x, w0);
                fma4(acc[r], x.y, w1);
                fma4(acc[r], x.z, w2);
                fma4(acc[r], x.w, w3);
            }
            w0 = n0; w1 = n1; w2 = n2; w3 = n3;
        }

        float4 bv = *(const float4*)&bias[col];
        if (dest == 0) {
            #pragma unroll
            for (int r = 0; r < NPB; ++r) {
                float4 o = make_float4(acc[r].x + bv.x, acc[r].y + bv.y,
                                       acc[r].z + bv.z, acc[r].w + bv.w);
                *(float4*)&q[(size_t)(node0 + r) * 512 + col] = o;
            }
        } else if (dest == 1) {
            int h = col >> 8, wcol = col & 255;
            float* base = (wcol < 128) ? kk : vv;
            int off = h * DD + (wcol & 127);
            #pragma unroll
            for (int r = 0; r < NPB; ++r) {
                float4 o = make_float4(acc[r].x + bv.x, acc[r].y + bv.y,
                                       acc[r].z + bv.z, acc[r].w + bv.w);
                *(float4*)&base[(size_t)(node0 + r) * 512 + off] = o;
            }
        } else if (dest == 2) {
            #pragma unroll
            for (int r = 0; r < NPB; ++r) {
                float4 o = make_float4(acc[r].x + bv.x, acc[r].y + bv.y,
                                       acc[r].z + bv.z, acc[r].w + bv.w);
                sqp4[r][col >> 2] = o;
            }
        } else {
            #pragma unroll
            for (int r = 0; r < NPB; ++r) {
                float4 o = make_float4(acc[r].x + bv.x, acc[r].y + bv.y,
                                       acc[r].z + bv.z, acc[r].w + bv.w);
                skvp4[r][col >> 2] = o;
            }
        }
    }
    __syncthreads();

    if (half == 1) {
        const float* sqp_s  = (const float*)&sqp4[0][0];    // [r*96 + c]
        const float* skvp_s = (const float*)&skvp4[0][0];   // [r*144 + c]

        // rigid transform q_pts: out[x] = sum_y R[x,y]*p[y] + t[x]
        for (int idx = tid; idx < NPB * 96; idx += 256) {
            int r = idx / 96, u = idx % 96;
            int j = u / 3, d = u % 3;
            int node = node0 + r;
            float acc = tvec[node * 3 + d];
            #pragma unroll
            for (int y = 0; y < 3; ++y)
                acc = fmaf(R[node * 9 + d * 3 + y], sqp_s[r * 96 + y * 32 + j], acc);
            qpts[(size_t)node * 96 + j * 3 + d] = acc;
        }
        // rigid transform kv_pts, split into k_pts / v_pts
        for (int idx = tid; idx < NPB * 144; idx += 256) {
            int r = idx / 144, u = idx % 144;
            int jj = u / 3, d = u % 3;
            int node = node0 + r;
            float acc = tvec[node * 3 + d];
            #pragma unroll
            for (int y = 0; y < 3; ++y)
                acc = fmaf(R[node * 9 + d * 3 + y], skvp_s[r * 144 + y * 48 + jj], acc);
            int hh = jj / 12, pp = jj % 12;
            if (pp < PQ_) kpts[(size_t)node * 96 + (hh * PQ_ + pp) * 3 + d] = acc;
            else          vpts[(size_t)node * 48 + (hh * PV_ + (pp - PQ_)) * 3 + d] = acc;
        }
    }
}

// ---- attn core: produces cat[1088] per node. No hE LDS tile (L2 catches
// the o_pair re-read) -> ~6KB LDS -> 8 blocks/CU occupancy. ----
__global__ __launch_bounds__(256, 8) void attn_kernel(
    const float* __restrict__ hE, const int* __restrict__ Eidx,
    const float* __restrict__ R, const float* __restrict__ tvec,
    const float* __restrict__ mask_att,
    const float* __restrict__ Wb, const float* __restrict__ bb,
    const float* __restrict__ head_w,
    const float* __restrict__ q, const float* __restrict__ kk, const float* __restrict__ vv,
    const float* __restrict__ qpts, const float* __restrict__ kpts, const float* __restrict__ vpts,
    float* __restrict__ catg)
{
    const int node = blockIdx.x;
    const int b = node >> 11;
    const int tid = threadIdx.x;
    const int lane = tid & 63;
    const int wv = tid >> 6;

    __shared__ float s_cat[1088];
    __shared__ float s_qp[96];
    __shared__ float s_p[HH][32];
    __shared__ int   s_j[32];
    __shared__ float s_mask[32];
    __shared__ float s_opt[48];

    if (tid < 96) s_qp[tid] = qpts[(size_t)node * 96 + tid];
    if (tid < KK) {
        s_j[tid] = Eidx[(size_t)node * KK + tid];
        s_mask[tid] = 100000.0f * (mask_att[(size_t)node * KK + tid] - 1.0f);
    }
    __syncthreads();

    const int h = wv;
    const int l32 = lane & 31;
    const int g = lane >> 5;
    const float* hE_node = hE + (size_t)node * (KK * DD);

    // per-lane hoisted values (4 c-elements per lane within 32-lane group)
    const float q0  = q[(size_t)node * 512 + h * DD + l32];
    const float q1  = q[(size_t)node * 512 + h * DD + l32 + 32];
    const float q2  = q[(size_t)node * 512 + h * DD + l32 + 64];
    const float q3  = q[(size_t)node * 512 + h * DD + l32 + 96];
    const float wb0 = Wb[(l32 +  0) * HH + h];
    const float wb1 = Wb[(l32 + 32) * HH + h];
    const float wb2 = Wb[(l32 + 64) * HH + h];
    const float wb3 = Wb[(l32 + 96) * HH + h];
    const float cpt = -0.5f * PT_SCALE * log1pf(expf(head_w[h]));
    const float bbh = INV3 * bb[h];
    const float qpl = (l32 < 24) ? s_qp[h * 24 + l32] : 0.f;

    // ---- logits: 2 k's per iteration (one per 32-lane group) ----
    for (int kx2 = 0; kx2 < KK / 2; ++kx2) {
        const int k = kx2 * 2 + g;
        size_t jb = (size_t)(b * NN + s_j[k]);
        const float* kr = kk + jb * 512 + h * DD;
        float s = q0 * kr[l32] + q1 * kr[l32 + 32]
                + q2 * kr[l32 + 64] + q3 * kr[l32 + 96];
        const float* her = hE_node + k * DD;
        float t = wb0 * her[l32] + wb1 * her[l32 + 32]
                + wb2 * her[l32 + 64] + wb3 * her[l32 + 96];
        float ptc = 0.f;
        if (l32 < 24) {
            float d = qpl - kpts[jb * 96 + h * 24 + l32];
            ptc = d * d;
        }
        float val = INV3C * s + INV3 * t + cpt * ptc;
        #pragma unroll
        for (int off = 16; off; off >>= 1) val += __shfl_down(val, off, 32);
        if (l32 == 0) s_p[h][k] = val + bbh + s_mask[k];
    }
    __syncthreads();

    // ---- softmax over k (lanes 0..29) ----
    {
        float v = (lane < KK) ? s_p[h][lane] : -INFINITY;
        float m = v;
        #pragma unroll
        for (int off = 16; off; off >>= 1) m = fmaxf(m, __shfl_down(m, off));
        m = __shfl(m, 0);
        float e = (lane < KK) ? expf(v - m) : 0.f;
        float s = e;
        #pragma unroll
        for (int off = 16; off; off >>= 1) s += __shfl_down(s, off);
        s = __shfl(s, 0);
        if (lane < KK) s_p[h][lane] = e / s;
    }
    __syncthreads();

    // ---- o (gathered v) and o_pair (hE, L2-resident re-read) ----
    {
        const int oh = tid >> 6;
        const int oc0 = (tid & 63) * 2;
        float a0 = 0.f, a1 = 0.f;
        for (int kx = 0; kx < KK; ++kx) {
            size_t jb = (size_t)(b * NN + s_j[kx]);
            const float2 v2 = *(const float2*)(vv + jb * 512 + oh * DD + oc0);
            float p = s_p[oh][kx];
            a0 = fmaf(p, v2.x, a0);
            a1 = fmaf(p, v2.y, a1);
        }
        s_cat[oh * DD + oc0]     = a0;
        s_cat[oh * DD + oc0 + 1] = a1;
        float b0 = 0.f, b1 = 0.f;
        const float* her = hE_node + oc0;
        for (int kx = 0; kx < KK; ++kx) {
            const float2 e2 = *(const float2*)(her + kx * DD);
            float p = s_p[oh][kx];
            b0 = fmaf(p, e2.x, b0);
            b1 = fmaf(p, e2.y, b1);
        }
        s_cat[576 + oh * DD + oc0]     = b0;
        s_cat[576 + oh * DD + oc0 + 1] = b1;
    }
    // ---- o_pt ----
    if (tid < 48) {
        int jj = tid / 3, d = tid % 3;
        int oh = jj >> 2;
        float acc = 0.f;
        for (int kx = 0; kx < KK; ++kx) {
            size_t jb = (size_t)(b * NN + s_j[kx]);
            acc = fmaf(s_p[oh][kx], vpts[jb * 48 + jj * 3 + d], acc);
        }
        s_opt[tid] = acc;
    }
    __syncthreads();
    if (tid < 16) {
        int jj = tid;
        float g0 = s_opt[jj * 3 + 0] - tvec[node * 3 + 0];
        float g1 = s_opt[jj * 3 + 1] - tvec[node * 3 + 1];
        float g2 = s_opt[jj * 3 + 2] - tvec[node * 3 + 2];
        float l0 = R[node * 9 + 0] * g0 + R[node * 9 + 3] * g1 + R[node * 9 + 6] * g2;
        float l1 = R[node * 9 + 1] * g0 + R[node * 9 + 4] * g1 + R[node * 9 + 7] * g2;
        float l2 = R[node * 9 + 2] * g0 + R[node * 9 + 5] * g1 + R[node * 9 + 8] * g2;
        s_cat[512 + 0 * 16 + jj] = l0;
        s_cat[512 + 1 * 16 + jj] = l1;
        s_cat[512 + 2 * 16 + jj] = l2;
        s_cat[560 + jj] = sqrtf(l0 * l0 + l1 * l1 + l2 * l2 + 1e-8f);
    }
    __syncthreads();

    // ---- write cat ----
    {
        const float4* src = (const float4*)s_cat;
        float4* dst = (float4*)(catg + (size_t)node * 1088);
        for (int i = tid; i < 1088 / 4; i += 256) dst[i] = src[i];
    }
}

// ---- tail: cat @ Wout + residual + LN0 + MLP + LN1, 8 nodes/block ----
__global__ __launch_bounds__(256) void tail_kernel(
    const float* __restrict__ hV, const float* __restrict__ maskV,
    const float* __restrict__ catg,
    const float* __restrict__ Wout, const float* __restrict__ bout,
    const float* __restrict__ ln0w, const float* __restrict__ ln0b,
    const float* __restrict__ ln1w, const float* __restrict__ ln1b,
    const float* __restrict__ Wm1, const float* __restrict__ bm1,
    const float* __restrict__ Wm2, const float* __restrict__ bm2,
    float* __restrict__ out)
{
    const int node0 = blockIdx.x * NPC;
    const int tid = threadIdx.x;

    __shared__ float s_cat[NPC][1088];    // 34816 B; aliased by s_m1 later
    __shared__ float s_red[2][NPC][DD];   // 8192 B
    __shared__ float s_hv[NPC][DD];
    __shared__ float s_x[NPC][DD];
    __shared__ float s_stat[NPC][2];

    {
        const float4* src = (const float4*)(catg + (size_t)node0 * 1088);
        float4* dst = (float4*)&s_cat[0][0];
        for (int i = tid; i < NPC * 1088 / 4; i += 256) dst[i] = src[i];
    }
    __syncthreads();

    const int c = tid & 127, grp = tid >> 7;

    // ---- Wout GEMV, 8 nodes batched ----
    {
        float acc[NPC];
        #pragma unroll
        for (int r = 0; r < NPC; ++r) acc[r] = 0.f;
        for (int i4 = grp * 136; i4 < grp * 136 + 136; ++i4) {
            const int i = i4 * 4;
            float w0 = Wout[(size_t)(i + 0) * DD + c];
            float w1 = Wout[(size_t)(i + 1) * DD + c];
            float w2 = Wout[(size_t)(i + 2) * DD + c];
            float w3 = Wout[(size_t)(i + 3) * DD + c];
            #pragma unroll
            for (int r = 0; r < NPC; ++r) {
                float4 x = *(const float4*)&s_cat[r][i];
                acc[r] = fmaf(x.x, w0, acc[r]);
                acc[r] = fmaf(x.y, w1, acc[r]);
                acc[r] = fmaf(x.z, w2, acc[r]);
                acc[r] = fmaf(x.w, w3, acc[r]);
            }
        }
        #pragma unroll
        for (int r = 0; r < NPC; ++r) s_red[grp][r][c] = acc[r];
    }
    __syncthreads();
    for (int idx = tid; idx < NPC * DD; idx += 256) {
        int r = idx >> 7, cc = idx & 127;
        s_x[r][cc] = s_red[0][r][cc] + s_red[1][r][cc] + bout[cc]
                   + hV[(size_t)(node0 + r) * DD + cc];
    }
    __syncthreads();
    // ---- LN0: 8 groups of 32 lanes, one node each ----
    {
        int r = tid >> 5, l = tid & 31;
        float4 xv = *(const float4*)&s_x[r][l * 4];
        float ssum = xv.x + xv.y + xv.z + xv.w;
        float ssq = xv.x * xv.x + xv.y * xv.y + xv.z * xv.z + xv.w * xv.w;
        #pragma unroll
        for (int off = 16; off; off >>= 1) { ssum += __shfl_down(ssum, off); ssq += __shfl_down(ssq, off); }
        if (l == 0) {
            float mu = ssum / 128.f;
            s_stat[r][0] = mu;
            s_stat[r][1] = rsqrtf(ssq / 128.f - mu * mu + 1e-5f);
        }
    }
    __syncthreads();
    for (int idx = tid; idx < NPC * DD; idx += 256) {
        int r = idx >> 7, cc = idx & 127;
        s_hv[r][cc] = (s_x[r][cc] - s_stat[r][0]) * s_stat[r][1] * ln0w[cc] + ln0b[cc];
    }
    __syncthreads();

    // ---- MLP1: 128 -> 512, thread owns cols tid and tid+256 ----
    float* s_m1 = &s_cat[0][0];           // alias: [r*512 + c512]
    {
        float acc0[NPC], acc1[NPC];
        #pragma unroll
        for (int r = 0; r < NPC; ++r) { acc0[r] = 0.f; acc1[r] = 0.f; }
        for (int i4 = 0; i4 < 32; ++i4) {
            const int i = i4 * 4;
            float w00 = Wm1[(i + 0) * 512 + tid], w10 = Wm1[(i + 0) * 512 + tid + 256];
            float w01 = Wm1[(i + 1) * 512 + tid], w11 = Wm1[(i + 1) * 512 + tid + 256];
            float w02 = Wm1[(i + 2) * 512 + tid], w12 = Wm1[(i + 2) * 512 + tid + 256];
            float w03 = Wm1[(i + 3) * 512 + tid], w13 = Wm1[(i + 3) * 512 + tid + 256];
            #pragma unroll
            for (int r = 0; r < NPC; ++r) {
                float4 x = *(const float4*)&s_hv[r][i];
                acc0[r] = fmaf(x.x, w00, acc0[r]); acc1[r] = fmaf(x.x, w10, acc1[r]);
                acc0[r] = fmaf(x.y, w01, acc0[r]); acc1[r] = fmaf(x.y, w11, acc1[r]);
                acc0[r] = fmaf(x.z, w02, acc0[r]); acc1[r] = fmaf(x.z, w12, acc1[r]);
                acc0[r] = fmaf(x.w, w03, acc0[r]); acc1[r] = fmaf(x.w, w13, acc1[r]);
            }
        }
        float b0 = bm1[tid], b1 = bm1[tid + 256];
        #pragma unroll
        for (int r = 0; r < NPC; ++r) {
            s_m1[r * 512 + tid]       = fmaxf(acc0[r] + b0, 0.f);
            s_m1[r * 512 + tid + 256] = fmaxf(acc1[r] + b1, 0.f);
        }
    }
    __syncthreads();
    // ---- MLP2: 512 -> 128 ----
    {
        float acc[NPC];
        #pragma unroll
        for (int r = 0; r < NPC; ++r) acc[r] = 0.f;
        for (int i4 = grp * 64; i4 < grp * 64 + 64; ++i4) {
            const int i = i4 * 4;
            float w0 = Wm2[(i + 0) * DD + c];
            float w1 = Wm2[(i + 1) * DD + c];
            float w2 = Wm2[(i + 2) * DD + c];
            float w3 = Wm2[(i + 3) * DD + c];
            #pragma unroll
            for (int r = 0; r < NPC; ++r) {
                float4 x = *(const float4*)&s_m1[r * 512 + i];
                acc[r] = fmaf(x.x, w0, acc[r]);
                acc[r] = fmaf(x.y, w1, acc[r]);
                acc[r] = fmaf(x.z, w2, acc[r]);
                acc[r] = fmaf(x.w, w3, acc[r]);
            }
        }
        #pragma unroll
        for (int r = 0; r < NPC; ++r) s_red[grp][r][c] = acc[r];
    }
    __syncthreads();
    for (int idx = tid; idx < NPC * DD; idx += 256) {
        int r = idx >> 7, cc = idx & 127;
        s_x[r][cc] = s_red[0][r][cc] + s_red[1][r][cc] + bm2[cc] + s_hv[r][cc];
    }
    __syncthreads();
    // ---- LN1 ----
    {
        int r = tid >> 5, l = tid & 31;
        float4 xv = *(const float4*)&s_x[r][l * 4];
        float ssum = xv.x + xv.y + xv.z + xv.w;
        float ssq = xv.x * xv.x + xv.y * xv.y + xv.z * xv.z + xv.w * xv.w;
        #pragma unroll
        for (int off = 16; off; off >>= 1) { ssum += __shfl_down(ssum, off); ssq += __shfl_down(ssq, off); }
        if (l == 0) {
            float mu = ssum / 128.f;
            s_stat[r][0] = mu;
            s_stat[r][1] = rsqrtf(ssq / 128.f - mu * mu + 1e-5f);
        }
    }
    __syncthreads();
    for (int idx = tid; idx < NPC * DD; idx += 256) {
        int r = idx >> 7, cc = idx & 127;
        float o = (s_x[r][cc] - s_stat[r][0]) * s_stat[r][1] * ln1w[cc] + ln1b[cc];
        out[(size_t)(node0 + r) * DD + cc] = o * maskV[node0 + r];
    }
}

extern "C" void kernel_launch(void* const* d_in, const int* in_sizes, int n_in,
                              void* d_out, int out_size, void* d_ws, size_t ws_size,
                              hipStream_t stream)
{
    const float* hV      = (const float*)d_in[0];
    const float* hE      = (const float*)d_in[1];
    const int*   Eidx    = (const int*)  d_in[2];
    const float* R       = (const float*)d_in[3];
    const float* tvec    = (const float*)d_in[4];
    const float* mask_at = (const float*)d_in[5];
    const float* maskV   = (const float*)d_in[6];
    const float* Wq      = (const float*)d_in[7];
    const float* bq      = (const float*)d_in[8];
    const float* Wkv     = (const float*)d_in[9];
    const float* bkv     = (const float*)d_in[10];
    const float* Wqp     = (const float*)d_in[11];
    const float* bqp     = (const float*)d_in[12];
    const float* Wkvp    = (const float*)d_in[13];
    const float* bkvp    = (const float*)d_in[14];
    const float* Wb      = (const float*)d_in[15];
    const float* bb      = (const float*)d_in[16];
    const float* hw      = (const float*)d_in[17];
    const float* Wout    = (const float*)d_in[18];
    const float* bout    = (const float*)d_in[19];
    const float* ln0w    = (const float*)d_in[20];
    const float* ln0b    = (const float*)d_in[21];
    const float* ln1w    = (const float*)d_in[22];
    const float* ln1b    = (const float*)d_in[23];
    const float* Wm1     = (const float*)d_in[24];
    const float* bm1     = (const float*)d_in[25];
    const float* Wm2     = (const float*)d_in[26];
    const float* bm2     = (const float*)d_in[27];

    const size_t nodes = (size_t)BB * NN;
    float* ws  = (float*)d_ws;
    float* q   = ws;
    float* kk  = q   + nodes * 512;
    float* vv  = kk  + nodes * 512;
    float* qp  = vv  + nodes * 512;
    float* kp  = qp  + nodes * 96;
    float* vp  = kp  + nodes * 96;
    float* cat = vp  + nodes * 48;

    proj_kernel<<<(int)(nodes / NPB) * 2, 256, 0, stream>>>(
        hV, R, tvec, Wq, bq, Wkv, bkv, Wqp, bqp, Wkvp, bkvp,
        q, kk, vv, qp, kp, vp);

    attn_kernel<<<(int)nodes, 256, 0, stream>>>(
        hE, Eidx, R, tvec, mask_at,
        Wb, bb, hw,
        q, kk, vv, qp, kp, vp, cat);

    tail_kernel<<<(int)(nodes / NPC), 256, 0, stream>>>(
        hV, maskV, cat,
        Wout, bout, ln0w, ln0b, ln1w, ln1b,
        Wm1, bm1, Wm2, bm2, (float*)d_out);
}

// Round 7
// 138.982 us; speedup vs baseline: 2.6807x; 1.2163x over previous
//
#include <hip/hip_runtime.h>
#include <math.h>

#define BB 2
#define NN 2048
#define KK 30
#define DD 128
#define HH 4
#define PQ_ 8
#define PV_ 4
#define NPB 8
#define TM 16      // nodes per tail block

#define INV3C    0.05103103630798288f   // sqrt(1/(3*128))
#define INV3     0.5773502691896258f    // sqrt(1/3)
#define PT_SCALE 0.09622504486493764f   // sqrt(1/108)

typedef __attribute__((ext_vector_type(8))) short short8;
typedef __attribute__((ext_vector_type(4))) float f32x4;
typedef unsigned short ushort_t;

__device__ __forceinline__ ushort_t f2bf(float f) {
    unsigned u = __float_as_uint(f);
    unsigned r = u + 0x7FFFu + ((u >> 16) & 1u);   // RNE
    return (ushort_t)(r >> 16);
}

__device__ __forceinline__ void fma4(float4& a, float s, const float4& w) {
    a.x = fmaf(s, w.x, a.x);
    a.y = fmaf(s, w.y, a.y);
    a.z = fmaf(s, w.z, a.z);
    a.w = fmaf(s, w.w, a.w);
}

// ---- weight prep: bf16 + transpose (WT[n][k]) for MFMA B-fragments ----
__global__ __launch_bounds__(256) void prep_kernel(
    const float* __restrict__ Wout, const float* __restrict__ Wm1,
    const float* __restrict__ Wm2,
    ushort_t* __restrict__ WoutT, ushort_t* __restrict__ Wm1T,
    ushort_t* __restrict__ Wm2T)
{
    const int stride = gridDim.x * blockDim.x;
    const int t0 = blockIdx.x * blockDim.x + threadIdx.x;
    for (int idx = t0; idx < 128 * 1088; idx += stride) {
        int n = idx / 1088, k = idx - n * 1088;
        WoutT[idx] = f2bf(Wout[(size_t)k * 128 + n]);
    }
    for (int idx = t0; idx < 512 * 128; idx += stride) {
        int n = idx >> 7, k = idx & 127;
        Wm1T[idx] = f2bf(Wm1[(size_t)k * 512 + n]);
    }
    for (int idx = t0; idx < 128 * 512; idx += stride) {
        int n = idx >> 9, k = idx & 511;
        Wm2T[idx] = f2bf(Wm2[(size_t)k * 128 + n]);
    }
}

// Projections: 444 col-quad tasks split across 2 blocks per node-group.
__global__ __launch_bounds__(256, 4) void proj_kernel(
    const float* __restrict__ hV, const float* __restrict__ R, const float* __restrict__ tvec,
    const float* __restrict__ Wq, const float* __restrict__ bq,
    const float* __restrict__ Wkv, const float* __restrict__ bkv,
    const float* __restrict__ Wqp, const float* __restrict__ bqp,
    const float* __restrict__ Wkvp, const float* __restrict__ bkvp,
    float* __restrict__ q, float* __restrict__ kk, float* __restrict__ vv,
    float* __restrict__ qpts, float* __restrict__ kpts, float* __restrict__ vpts)
{
    const int node0 = (blockIdx.x >> 1) * NPB;
    const int half  = blockIdx.x & 1;
    const int tid = threadIdx.x;
    __shared__ float4 sx4[NPB][32];
    __shared__ float4 sqp4[NPB][24];
    __shared__ float4 skvp4[NPB][36];

    {
        const float4* src = (const float4*)(hV + (size_t)node0 * DD);
        sx4[tid >> 5][tid & 31] = src[tid];
    }
    __syncthreads();

    if (tid < 222) {
        const int Q = half * 222 + tid;
        const float* W; const float* bias; int ncols, col, dest;
        if (Q < 128)      { W = Wq;   bias = bq;   ncols = 512;  col = Q * 4;         dest = 0; }
        else if (Q < 384) { W = Wkv;  bias = bkv;  ncols = 1024; col = (Q - 128) * 4; dest = 1; }
        else if (Q < 408) { W = Wqp;  bias = bqp;  ncols = 96;   col = (Q - 384) * 4; dest = 2; }
        else              { W = Wkvp; bias = bkvp; ncols = 144;  col = (Q - 408) * 4; dest = 3; }

        float4 acc[NPB];
        #pragma unroll
        for (int r = 0; r < NPB; ++r) acc[r] = make_float4(0.f, 0.f, 0.f, 0.f);

        float4 w0 = *(const float4*)&W[(size_t)0 * ncols + col];
        float4 w1 = *(const float4*)&W[(size_t)1 * ncols + col];
        float4 w2 = *(const float4*)&W[(size_t)2 * ncols + col];
        float4 w3 = *(const float4*)&W[(size_t)3 * ncols + col];
        for (int i = 0; i < DD; i += 4) {
            float4 n0, n1, n2, n3;
            if (i + 4 < DD) {
                n0 = *(const float4*)&W[(size_t)(i + 4) * ncols + col];
                n1 = *(const float4*)&W[(size_t)(i + 5) * ncols + col];
                n2 = *(const float4*)&W[(size_t)(i + 6) * ncols + col];
                n3 = *(const float4*)&W[(size_t)(i + 7) * ncols + col];
            }
            #pragma unroll
            for (int r = 0; r < NPB; ++r) {
                float4 x = sx4[r][i >> 2];
                fma4(acc[r], x.x, w0);
                fma4(acc[r], x.y, w1);
                fma4(acc[r], x.z, w2);
                fma4(acc[r], x.w, w3);
            }
            w0 = n0; w1 = n1; w2 = n2; w3 = n3;
        }

        float4 bv = *(const float4*)&bias[col];
        if (dest == 0) {
            #pragma unroll
            for (int r = 0; r < NPB; ++r) {
                float4 o = make_float4(acc[r].x + bv.x, acc[r].y + bv.y,
                                       acc[r].z + bv.z, acc[r].w + bv.w);
                *(float4*)&q[(size_t)(node0 + r) * 512 + col] = o;
            }
        } else if (dest == 1) {
            int h = col >> 8, wcol = col & 255;
            float* base = (wcol < 128) ? kk : vv;
            int off = h * DD + (wcol & 127);
            #pragma unroll
            for (int r = 0; r < NPB; ++r) {
                float4 o = make_float4(acc[r].x + bv.x, acc[r].y + bv.y,
                                       acc[r].z + bv.z, acc[r].w + bv.w);
                *(float4*)&base[(size_t)(node0 + r) * 512 + off] = o;
            }
        } else if (dest == 2) {
            #pragma unroll
            for (int r = 0; r < NPB; ++r) {
                float4 o = make_float4(acc[r].x + bv.x, acc[r].y + bv.y,
                                       acc[r].z + bv.z, acc[r].w + bv.w);
                sqp4[r][col >> 2] = o;
            }
        } else {
            #pragma unroll
            for (int r = 0; r < NPB; ++r) {
                float4 o = make_float4(acc[r].x + bv.x, acc[r].y + bv.y,
                                       acc[r].z + bv.z, acc[r].w + bv.w);
                skvp4[r][col >> 2] = o;
            }
        }
    }
    __syncthreads();

    if (half == 1) {
        const float* sqp_s  = (const float*)&sqp4[0][0];    // [r*96 + c]
        const float* skvp_s = (const float*)&skvp4[0][0];   // [r*144 + c]

        for (int idx = tid; idx < NPB * 96; idx += 256) {
            int r = idx / 96, u = idx % 96;
            int j = u / 3, d = u % 3;
            int node = node0 + r;
            float acc = tvec[node * 3 + d];
            #pragma unroll
            for (int y = 0; y < 3; ++y)
                acc = fmaf(R[node * 9 + d * 3 + y], sqp_s[r * 96 + y * 32 + j], acc);
            qpts[(size_t)node * 96 + j * 3 + d] = acc;
        }
        for (int idx = tid; idx < NPB * 144; idx += 256) {
            int r = idx / 144, u = idx % 144;
            int jj = u / 3, d = u % 3;
            int node = node0 + r;
            float acc = tvec[node * 3 + d];
            #pragma unroll
            for (int y = 0; y < 3; ++y)
                acc = fmaf(R[node * 9 + d * 3 + y], skvp_s[r * 144 + y * 48 + jj], acc);
            int hh = jj / 12, pp = jj % 12;
            if (pp < PQ_) kpts[(size_t)node * 96 + (hh * PQ_ + pp) * 3 + d] = acc;
            else          vpts[(size_t)node * 48 + (hh * PV_ + (pp - PQ_)) * 3 + d] = acc;
        }
    }
}

// ---- attn core: produces cat[1088] per node, written as bf16 ----
__global__ __launch_bounds__(256, 8) void attn_kernel(
    const float* __restrict__ hE, const int* __restrict__ Eidx,
    const float* __restrict__ R, const float* __restrict__ tvec,
    const float* __restrict__ mask_att,
    const float* __restrict__ Wb, const float* __restrict__ bb,
    const float* __restrict__ head_w,
    const float* __restrict__ q, const float* __restrict__ kk, const float* __restrict__ vv,
    const float* __restrict__ qpts, const float* __restrict__ kpts, const float* __restrict__ vpts,
    ushort_t* __restrict__ catb)
{
    const int node = blockIdx.x;
    const int b = node >> 11;
    const int tid = threadIdx.x;
    const int lane = tid & 63;
    const int wv = tid >> 6;

    __shared__ float s_cat[1088];
    __shared__ float s_qp[96];
    __shared__ float s_p[HH][32];
    __shared__ int   s_j[32];
    __shared__ float s_mask[32];
    __shared__ float s_opt[48];

    if (tid < 96) s_qp[tid] = qpts[(size_t)node * 96 + tid];
    if (tid < KK) {
        s_j[tid] = Eidx[(size_t)node * KK + tid];
        s_mask[tid] = 100000.0f * (mask_att[(size_t)node * KK + tid] - 1.0f);
    }
    __syncthreads();

    const int h = wv;
    const int l32 = lane & 31;
    const int g = lane >> 5;
    const float* hE_node = hE + (size_t)node * (KK * DD);

    const float q0  = q[(size_t)node * 512 + h * DD + l32];
    const float q1  = q[(size_t)node * 512 + h * DD + l32 + 32];
    const float q2  = q[(size_t)node * 512 + h * DD + l32 + 64];
    const float q3  = q[(size_t)node * 512 + h * DD + l32 + 96];
    const float wb0 = Wb[(l32 +  0) * HH + h];
    const float wb1 = Wb[(l32 + 32) * HH + h];
    const float wb2 = Wb[(l32 + 64) * HH + h];
    const float wb3 = Wb[(l32 + 96) * HH + h];
    const float cpt = -0.5f * PT_SCALE * log1pf(expf(head_w[h]));
    const float bbh = INV3 * bb[h];
    const float qpl = (l32 < 24) ? s_qp[h * 24 + l32] : 0.f;

    for (int kx2 = 0; kx2 < KK / 2; ++kx2) {
        const int k = kx2 * 2 + g;
        size_t jb = (size_t)(b * NN + s_j[k]);
        const float* kr = kk + jb * 512 + h * DD;
        float s = q0 * kr[l32] + q1 * kr[l32 + 32]
                + q2 * kr[l32 + 64] + q3 * kr[l32 + 96];
        const float* her = hE_node + k * DD;
        float t = wb0 * her[l32] + wb1 * her[l32 + 32]
                + wb2 * her[l32 + 64] + wb3 * her[l32 + 96];
        float ptc = 0.f;
        if (l32 < 24) {
            float d = qpl - kpts[jb * 96 + h * 24 + l32];
            ptc = d * d;
        }
        float val = INV3C * s + INV3 * t + cpt * ptc;
        #pragma unroll
        for (int off = 16; off; off >>= 1) val += __shfl_down(val, off, 32);
        if (l32 == 0) s_p[h][k] = val + bbh + s_mask[k];
    }
    __syncthreads();

    {
        float v = (lane < KK) ? s_p[h][lane] : -INFINITY;
        float m = v;
        #pragma unroll
        for (int off = 16; off; off >>= 1) m = fmaxf(m, __shfl_down(m, off));
        m = __shfl(m, 0);
        float e = (lane < KK) ? expf(v - m) : 0.f;
        float s = e;
        #pragma unroll
        for (int off = 16; off; off >>= 1) s += __shfl_down(s, off);
        s = __shfl(s, 0);
        if (lane < KK) s_p[h][lane] = e / s;
    }
    __syncthreads();

    {
        const int oh = tid >> 6;
        const int oc0 = (tid & 63) * 2;
        float a0 = 0.f, a1 = 0.f;
        for (int kx = 0; kx < KK; ++kx) {
            size_t jb = (size_t)(b * NN + s_j[kx]);
            const float2 v2 = *(const float2*)(vv + jb * 512 + oh * DD + oc0);
            float p = s_p[oh][kx];
            a0 = fmaf(p, v2.x, a0);
            a1 = fmaf(p, v2.y, a1);
        }
        s_cat[oh * DD + oc0]     = a0;
        s_cat[oh * DD + oc0 + 1] = a1;
        float b0 = 0.f, b1 = 0.f;
        const float* her = hE_node + oc0;
        for (int kx = 0; kx < KK; ++kx) {
            const float2 e2 = *(const float2*)(her + kx * DD);
            float p = s_p[oh][kx];
            b0 = fmaf(p, e2.x, b0);
            b1 = fmaf(p, e2.y, b1);
        }
        s_cat[576 + oh * DD + oc0]     = b0;
        s_cat[576 + oh * DD + oc0 + 1] = b1;
    }
    if (tid < 48) {
        int jj = tid / 3, d = tid % 3;
        int oh = jj >> 2;
        float acc = 0.f;
        for (int kx = 0; kx < KK; ++kx) {
            size_t jb = (size_t)(b * NN + s_j[kx]);
            acc = fmaf(s_p[oh][kx], vpts[jb * 48 + jj * 3 + d], acc);
        }
        s_opt[tid] = acc;
    }
    __syncthreads();
    if (tid < 16) {
        int jj = tid;
        float g0 = s_opt[jj * 3 + 0] - tvec[node * 3 + 0];
        float g1 = s_opt[jj * 3 + 1] - tvec[node * 3 + 1];
        float g2 = s_opt[jj * 3 + 2] - tvec[node * 3 + 2];
        float l0 = R[node * 9 + 0] * g0 + R[node * 9 + 3] * g1 + R[node * 9 + 6] * g2;
        float l1 = R[node * 9 + 1] * g0 + R[node * 9 + 4] * g1 + R[node * 9 + 7] * g2;
        float l2 = R[node * 9 + 2] * g0 + R[node * 9 + 5] * g1 + R[node * 9 + 8] * g2;
        s_cat[512 + 0 * 16 + jj] = l0;
        s_cat[512 + 1 * 16 + jj] = l1;
        s_cat[512 + 2 * 16 + jj] = l2;
        s_cat[560 + jj] = sqrtf(l0 * l0 + l1 * l1 + l2 * l2 + 1e-8f);
    }
    __syncthreads();

    // ---- write cat as bf16 ----
    for (int i = tid; i < 1088; i += 256)
        catb[(size_t)node * 1088 + i] = f2bf(s_cat[i]);
}

// ---- tail: MFMA GEMMs. 16 nodes/block, 512 threads (8 waves), grid 256.
// mfma_f32_16x16x32_bf16: A row=lane&15, k=(lane>>4)*8+j (8 contig bf16);
// B col=lane&15, same k; C col=lane&15, row=(lane>>4)*4+reg. ----
__global__ __launch_bounds__(512) void tail_kernel(
    const float* __restrict__ hV, const float* __restrict__ maskV,
    const ushort_t* __restrict__ catb,
    const ushort_t* __restrict__ WoutT, const float* __restrict__ bout,
    const float* __restrict__ ln0w, const float* __restrict__ ln0b,
    const float* __restrict__ ln1w, const float* __restrict__ ln1b,
    const ushort_t* __restrict__ Wm1T, const float* __restrict__ bm1,
    const ushort_t* __restrict__ Wm2T, const float* __restrict__ bm2,
    float* __restrict__ out)
{
    const int node0 = blockIdx.x * TM;
    const int tid = threadIdx.x;
    const int w  = tid >> 6;    // wave 0..7
    const int l  = tid & 63;
    const int lr = l & 15;      // row/col lane index
    const int lk = l >> 4;      // k-group 0..3

    __shared__ float    s_x[TM][DD];        // 8 KB (GEMM out / LN in)
    __shared__ float    s_hv[TM][DD];       // 8 KB (post-LN0, fp32 residual)
    __shared__ ushort_t s_hvb[TM][136];     // 4.25 KB (padded bf16 A for MLP1)
    __shared__ ushort_t s_m1[TM][520];      // 16.25 KB (padded bf16 A for MLP2)
    __shared__ float    s_rs[TM][16];
    __shared__ float    s_rq[TM][16];
    __shared__ float    s_stat[TM][2];

    // ---- GEMM1: s = cat[16x1088] @ Wout[1088x128]; wave w -> cols w*16..+16
    {
        f32x4 acc = {0.f, 0.f, 0.f, 0.f};
        const ushort_t* Ab = catb + (size_t)(node0 + lr) * 1088 + lk * 8;
        const ushort_t* Bb = WoutT + (size_t)(w * 16 + lr) * 1088 + lk * 8;
        #pragma unroll 2
        for (int ks = 0; ks < 34; ++ks) {
            short8 a = *(const short8*)(Ab + ks * 32);
            short8 bfr = *(const short8*)(Bb + ks * 32);
            acc = __builtin_amdgcn_mfma_f32_16x16x32_bf16(a, bfr, acc, 0, 0, 0);
        }
        #pragma unroll
        for (int i = 0; i < 4; ++i)
            s_x[lk * 4 + i][w * 16 + lr] = acc[i];
    }
    __syncthreads();

    // ---- bias + residual + LN0 stats ----
    if (tid < 256) {
        int r = tid >> 4, sg = tid & 15;
        float ss = 0.f, sq = 0.f;
        #pragma unroll
        for (int j = 0; j < 8; ++j) {
            int cc = sg * 8 + j;
            float x = s_x[r][cc] + bout[cc] + hV[(size_t)(node0 + r) * DD + cc];
            s_x[r][cc] = x;
            ss += x; sq += x * x;
        }
        s_rs[r][sg] = ss; s_rq[r][sg] = sq;
    }
    __syncthreads();
    if (tid < TM) {
        float ss = 0.f, sq = 0.f;
        #pragma unroll
        for (int sg = 0; sg < 16; ++sg) { ss += s_rs[tid][sg]; sq += s_rq[tid][sg]; }
        float mu = ss / 128.f;
        s_stat[tid][0] = mu;
        s_stat[tid][1] = rsqrtf(sq / 128.f - mu * mu + 1e-5f);
    }
    __syncthreads();
    {
        int idx = tid * 4;
        int r = idx >> 7, cc = idx & 127;
        float mu = s_stat[r][0], rstd = s_stat[r][1];
        #pragma unroll
        for (int j = 0; j < 4; ++j) {
            float hvv = (s_x[r][cc + j] - mu) * rstd * ln0w[cc + j] + ln0b[cc + j];
            s_hv[r][cc + j] = hvv;
            s_hvb[r][cc + j] = f2bf(hvv);
        }
    }
    __syncthreads();

    // ---- GEMM2: m1 = hv[16x128] @ Wm1[128x512], ReLU; wave w -> cols w*64..+64
    {
        const ushort_t* Ab = &s_hvb[lr][lk * 8];
        #pragma unroll
        for (int t = 0; t < 4; ++t) {
            int n0 = w * 64 + t * 16;
            f32x4 acc = {0.f, 0.f, 0.f, 0.f};
            const ushort_t* Bb = Wm1T + (size_t)(n0 + lr) * 128 + lk * 8;
            #pragma unroll
            for (int ks = 0; ks < 4; ++ks) {
                short8 a = *(const short8*)(Ab + ks * 32);
                short8 bfr = *(const short8*)(Bb + ks * 32);
                acc = __builtin_amdgcn_mfma_f32_16x16x32_bf16(a, bfr, acc, 0, 0, 0);
            }
            int n = n0 + lr;
            float bm = bm1[n];
            #pragma unroll
            for (int i = 0; i < 4; ++i)
                s_m1[lk * 4 + i][n] = f2bf(fmaxf(acc[i] + bm, 0.f));
        }
    }
    __syncthreads();

    // ---- GEMM3: m = m1[16x512] @ Wm2[512x128]; wave w -> cols w*16..+16
    {
        f32x4 acc = {0.f, 0.f, 0.f, 0.f};
        const ushort_t* Ab = &s_m1[lr][lk * 8];
        const ushort_t* Bb = Wm2T + (size_t)(w * 16 + lr) * 512 + lk * 8;
        #pragma unroll 4
        for (int ks = 0; ks < 16; ++ks) {
            short8 a = *(const short8*)(Ab + ks * 32);
            short8 bfr = *(const short8*)(Bb + ks * 32);
            acc = __builtin_amdgcn_mfma_f32_16x16x32_bf16(a, bfr, acc, 0, 0, 0);
        }
        #pragma unroll
        for (int i = 0; i < 4; ++i)
            s_x[lk * 4 + i][w * 16 + lr] = acc[i];
    }
    __syncthreads();

    // ---- bm2 + residual + LN1 ----
    if (tid < 256) {
        int r = tid >> 4, sg = tid & 15;
        float ss = 0.f, sq = 0.f;
        #pragma unroll
        for (int j = 0; j < 8; ++j) {
            int cc = sg * 8 + j;
            float x = s_x[r][cc] + bm2[cc] + s_hv[r][cc];
            s_x[r][cc] = x;
            ss += x; sq += x * x;
        }
        s_rs[r][sg] = ss; s_rq[r][sg] = sq;
    }
    __syncthreads();
    if (tid < TM) {
        float ss = 0.f, sq = 0.f;
        #pragma unroll
        for (int sg = 0; sg < 16; ++sg) { ss += s_rs[tid][sg]; sq += s_rq[tid][sg]; }
        float mu = ss / 128.f;
        s_stat[tid][0] = mu;
        s_stat[tid][1] = rsqrtf(sq / 128.f - mu * mu + 1e-5f);
    }
    __syncthreads();
    {
        int idx = tid * 4;
        int r = idx >> 7, cc = idx & 127;
        float mu = s_stat[r][0], rstd = s_stat[r][1];
        float mk = maskV[node0 + r];
        float4 o;
        o.x = ((s_x[r][cc + 0] - mu) * rstd * ln1w[cc + 0] + ln1b[cc + 0]) * mk;
        o.y = ((s_x[r][cc + 1] - mu) * rstd * ln1w[cc + 1] + ln1b[cc + 1]) * mk;
        o.z = ((s_x[r][cc + 2] - mu) * rstd * ln1w[cc + 2] + ln1b[cc + 2]) * mk;
        o.w = ((s_x[r][cc + 3] - mu) * rstd * ln1w[cc + 3] + ln1b[cc + 3]) * mk;
        *(float4*)&out[(size_t)(node0 + r) * DD + cc] = o;
    }
}

extern "C" void kernel_launch(void* const* d_in, const int* in_sizes, int n_in,
                              void* d_out, int out_size, void* d_ws, size_t ws_size,
                              hipStream_t stream)
{
    const float* hV      = (const float*)d_in[0];
    const float* hE      = (const float*)d_in[1];
    const int*   Eidx    = (const int*)  d_in[2];
    const float* R       = (const float*)d_in[3];
    const float* tvec    = (const float*)d_in[4];
    const float* mask_at = (const float*)d_in[5];
    const float* maskV   = (const float*)d_in[6];
    const float* Wq      = (const float*)d_in[7];
    const float* bq      = (const float*)d_in[8];
    const float* Wkv     = (const float*)d_in[9];
    const float* bkv     = (const float*)d_in[10];
    const float* Wqp     = (const float*)d_in[11];
    const float* bqp     = (const float*)d_in[12];
    const float* Wkvp    = (const float*)d_in[13];
    const float* bkvp    = (const float*)d_in[14];
    const float* Wb      = (const float*)d_in[15];
    const float* bb      = (const float*)d_in[16];
    const float* hw      = (const float*)d_in[17];
    const float* Wout    = (const float*)d_in[18];
    const float* bout    = (const float*)d_in[19];
    const float* ln0w    = (const float*)d_in[20];
    const float* ln0b    = (const float*)d_in[21];
    const float* ln1w    = (const float*)d_in[22];
    const float* ln1b    = (const float*)d_in[23];
    const float* Wm1     = (const float*)d_in[24];
    const float* bm1     = (const float*)d_in[25];
    const float* Wm2     = (const float*)d_in[26];
    const float* bm2     = (const float*)d_in[27];

    const size_t nodes = (size_t)BB * NN;
    float* ws  = (float*)d_ws;
    float* q   = ws;
    float* kk  = q   + nodes * 512;
    float* vv  = kk  + nodes * 512;
    float* qp  = vv  + nodes * 512;
    float* kp  = qp  + nodes * 96;
    float* vp  = kp  + nodes * 96;
    ushort_t* catb  = (ushort_t*)(vp + nodes * 48);
    ushort_t* WoutT = catb  + nodes * 1088;
    ushort_t* Wm1T  = WoutT + 128 * 1088;
    ushort_t* Wm2T  = Wm1T  + 512 * 128;

    prep_kernel<<<256, 256, 0, stream>>>(Wout, Wm1, Wm2, WoutT, Wm1T, Wm2T);

    proj_kernel<<<(int)(nodes / NPB) * 2, 256, 0, stream>>>(
        hV, R, tvec, Wq, bq, Wkv, bkv, Wqp, bqp, Wkvp, bkvp,
        q, kk, vv, qp, kp, vp);

    attn_kernel<<<(int)nodes, 256, 0, stream>>>(
        hE, Eidx, R, tvec, mask_at,
        Wb, bb, hw,
        q, kk, vv, qp, kp, vp, catb);

    tail_kernel<<<(int)(nodes / TM), 512, 0, stream>>>(
        hV, maskV, catb,
        WoutT, bout, ln0w, ln0b, ln1w, ln1b,
        Wm1T, bm1, Wm2T, bm2, (float*)d_out);
}

// Round 8
// 119.044 us; speedup vs baseline: 3.1296x; 1.1675x over previous
//
#include <hip/hip_runtime.h>
#include <math.h>

#define BB 2
#define NN 2048
#define KK 30
#define DD 128
#define HH 4
#define PQ_ 8
#define PV_ 4
#define NPB 8
#define TM 16      // nodes per tail block

#define INV3C    0.05103103630798288f   // sqrt(1/(3*128))
#define INV3     0.5773502691896258f    // sqrt(1/3)
#define PT_SCALE 0.09622504486493764f   // sqrt(1/108)

typedef __attribute__((ext_vector_type(8))) short short8;
typedef __attribute__((ext_vector_type(4))) float f32x4;
typedef __attribute__((ext_vector_type(4))) unsigned short us4;
typedef unsigned short ushort_t;

__device__ __forceinline__ ushort_t f2bf(float f) {
    unsigned u = __float_as_uint(f);
    unsigned r = u + 0x7FFFu + ((u >> 16) & 1u);   // RNE
    return (ushort_t)(r >> 16);
}
__device__ __forceinline__ float bf2f(ushort_t u) {
    return __uint_as_float(((unsigned)u) << 16);
}

__device__ __forceinline__ void fma4(float4& a, float s, const float4& w) {
    a.x = fmaf(s, w.x, a.x);
    a.y = fmaf(s, w.y, a.y);
    a.z = fmaf(s, w.z, a.z);
    a.w = fmaf(s, w.w, a.w);
}

// ---- weight prep: bf16 + transpose (WT[n][k]) for MFMA B-fragments ----
__global__ __launch_bounds__(256) void prep_kernel(
    const float* __restrict__ Wout, const float* __restrict__ Wm1,
    const float* __restrict__ Wm2,
    ushort_t* __restrict__ WoutT, ushort_t* __restrict__ Wm1T,
    ushort_t* __restrict__ Wm2T)
{
    const int stride = gridDim.x * blockDim.x;
    const int t0 = blockIdx.x * blockDim.x + threadIdx.x;
    for (int idx = t0; idx < 128 * 1088; idx += stride) {
        int n = idx / 1088, k = idx - n * 1088;
        WoutT[idx] = f2bf(Wout[(size_t)k * 128 + n]);
    }
    for (int idx = t0; idx < 512 * 128; idx += stride) {
        int n = idx >> 7, k = idx & 127;
        Wm1T[idx] = f2bf(Wm1[(size_t)k * 512 + n]);
    }
    for (int idx = t0; idx < 128 * 512; idx += stride) {
        int n = idx >> 9, k = idx & 511;
        Wm2T[idx] = f2bf(Wm2[(size_t)k * 128 + n]);
    }
}

// Projections: 444 col-quad tasks split across 2 blocks per node-group.
// k_/v_ outputs packed to bf16 (halves gather traffic in attn).
__global__ __launch_bounds__(256, 4) void proj_kernel(
    const float* __restrict__ hV, const float* __restrict__ R, const float* __restrict__ tvec,
    const float* __restrict__ Wq, const float* __restrict__ bq,
    const float* __restrict__ Wkv, const float* __restrict__ bkv,
    const float* __restrict__ Wqp, const float* __restrict__ bqp,
    const float* __restrict__ Wkvp, const float* __restrict__ bkvp,
    float* __restrict__ q, ushort_t* __restrict__ kb, ushort_t* __restrict__ vb,
    float* __restrict__ qpts, float* __restrict__ kpts, float* __restrict__ vpts)
{
    const int node0 = (blockIdx.x >> 1) * NPB;
    const int half  = blockIdx.x & 1;
    const int tid = threadIdx.x;
    __shared__ float4 sx4[NPB][32];
    __shared__ float4 sqp4[NPB][24];
    __shared__ float4 skvp4[NPB][36];

    {
        const float4* src = (const float4*)(hV + (size_t)node0 * DD);
        sx4[tid >> 5][tid & 31] = src[tid];
    }
    __syncthreads();

    if (tid < 222) {
        const int Q = half * 222 + tid;
        const float* W; const float* bias; int ncols, col, dest;
        if (Q < 128)      { W = Wq;   bias = bq;   ncols = 512;  col = Q * 4;         dest = 0; }
        else if (Q < 384) { W = Wkv;  bias = bkv;  ncols = 1024; col = (Q - 128) * 4; dest = 1; }
        else if (Q < 408) { W = Wqp;  bias = bqp;  ncols = 96;   col = (Q - 384) * 4; dest = 2; }
        else              { W = Wkvp; bias = bkvp; ncols = 144;  col = (Q - 408) * 4; dest = 3; }

        float4 acc[NPB];
        #pragma unroll
        for (int r = 0; r < NPB; ++r) acc[r] = make_float4(0.f, 0.f, 0.f, 0.f);

        float4 w0 = *(const float4*)&W[(size_t)0 * ncols + col];
        float4 w1 = *(const float4*)&W[(size_t)1 * ncols + col];
        float4 w2 = *(const float4*)&W[(size_t)2 * ncols + col];
        float4 w3 = *(const float4*)&W[(size_t)3 * ncols + col];
        for (int i = 0; i < DD; i += 4) {
            float4 n0, n1, n2, n3;
            if (i + 4 < DD) {
                n0 = *(const float4*)&W[(size_t)(i + 4) * ncols + col];
                n1 = *(const float4*)&W[(size_t)(i + 5) * ncols + col];
                n2 = *(const float4*)&W[(size_t)(i + 6) * ncols + col];
                n3 = *(const float4*)&W[(size_t)(i + 7) * ncols + col];
            }
            #pragma unroll
            for (int r = 0; r < NPB; ++r) {
                float4 x = sx4[r][i >> 2];
                fma4(acc[r], x.x, w0);
                fma4(acc[r], x.y, w1);
                fma4(acc[r], x.z, w2);
                fma4(acc[r], x.w, w3);
            }
            w0 = n0; w1 = n1; w2 = n2; w3 = n3;
        }

        float4 bv = *(const float4*)&bias[col];
        if (dest == 0) {
            #pragma unroll
            for (int r = 0; r < NPB; ++r) {
                float4 o = make_float4(acc[r].x + bv.x, acc[r].y + bv.y,
                                       acc[r].z + bv.z, acc[r].w + bv.w);
                *(float4*)&q[(size_t)(node0 + r) * 512 + col] = o;
            }
        } else if (dest == 1) {
            int h = col >> 8, wcol = col & 255;
            ushort_t* base = (wcol < 128) ? kb : vb;
            int off = h * DD + (wcol & 127);
            #pragma unroll
            for (int r = 0; r < NPB; ++r) {
                us4 o;
                o.x = f2bf(acc[r].x + bv.x);
                o.y = f2bf(acc[r].y + bv.y);
                o.z = f2bf(acc[r].z + bv.z);
                o.w = f2bf(acc[r].w + bv.w);
                *(us4*)&base[(size_t)(node0 + r) * 512 + off] = o;
            }
        } else if (dest == 2) {
            #pragma unroll
            for (int r = 0; r < NPB; ++r) {
                float4 o = make_float4(acc[r].x + bv.x, acc[r].y + bv.y,
                                       acc[r].z + bv.z, acc[r].w + bv.w);
                sqp4[r][col >> 2] = o;
            }
        } else {
            #pragma unroll
            for (int r = 0; r < NPB; ++r) {
                float4 o = make_float4(acc[r].x + bv.x, acc[r].y + bv.y,
                                       acc[r].z + bv.z, acc[r].w + bv.w);
                skvp4[r][col >> 2] = o;
            }
        }
    }
    __syncthreads();

    if (half == 1) {
        const float* sqp_s  = (const float*)&sqp4[0][0];    // [r*96 + c]
        const float* skvp_s = (const float*)&skvp4[0][0];   // [r*144 + c]

        for (int idx = tid; idx < NPB * 96; idx += 256) {
            int r = idx / 96, u = idx % 96;
            int j = u / 3, d = u % 3;
            int node = node0 + r;
            float acc = tvec[node * 3 + d];
            #pragma unroll
            for (int y = 0; y < 3; ++y)
                acc = fmaf(R[node * 9 + d * 3 + y], sqp_s[r * 96 + y * 32 + j], acc);
            qpts[(size_t)node * 96 + j * 3 + d] = acc;
        }
        for (int idx = tid; idx < NPB * 144; idx += 256) {
            int r = idx / 144, u = idx % 144;
            int jj = u / 3, d = u % 3;
            int node = node0 + r;
            float acc = tvec[node * 3 + d];
            #pragma unroll
            for (int y = 0; y < 3; ++y)
                acc = fmaf(R[node * 9 + d * 3 + y], skvp_s[r * 144 + y * 48 + jj], acc);
            int hh = jj / 12, pp = jj % 12;
            if (pp < PQ_) kpts[(size_t)node * 96 + (hh * PQ_ + pp) * 3 + d] = acc;
            else          vpts[(size_t)node * 48 + (hh * PV_ + (pp - PQ_)) * 3 + d] = acc;
        }
    }
}

// ---- attn core. hE read from HBM exactly ONCE: logits loop consumes it in
// fp32 and stages bf16 into LDS for the o_pair pass. k/v gathers are bf16. ----
__global__ __launch_bounds__(256, 8) void attn_kernel(
    const float* __restrict__ hE, const int* __restrict__ Eidx,
    const float* __restrict__ R, const float* __restrict__ tvec,
    const float* __restrict__ mask_att,
    const float* __restrict__ Wb, const float* __restrict__ bb,
    const float* __restrict__ head_w,
    const float* __restrict__ q, const ushort_t* __restrict__ kb,
    const ushort_t* __restrict__ vb,
    const float* __restrict__ qpts, const float* __restrict__ kpts, const float* __restrict__ vpts,
    ushort_t* __restrict__ catb)
{
    const int node = blockIdx.x;
    const int b = node >> 11;
    const int tid = threadIdx.x;
    const int lane = tid & 63;
    const int wv = tid >> 6;

    __shared__ ushort_t s_hEb[KK * DD];   // 7680 B, bf16-staged hE
    __shared__ float s_cat[1088];
    __shared__ float s_qp[96];
    __shared__ float s_p[HH][32];
    __shared__ int   s_j[32];
    __shared__ float s_mask[32];
    __shared__ float s_opt[48];

    if (tid < 96) s_qp[tid] = qpts[(size_t)node * 96 + tid];
    if (tid < KK) {
        s_j[tid] = Eidx[(size_t)node * KK + tid];
        s_mask[tid] = 100000.0f * (mask_att[(size_t)node * KK + tid] - 1.0f);
    }
    __syncthreads();

    const int h = wv;
    const int l32 = lane & 31;
    const int g = lane >> 5;
    const float* hE_node = hE + (size_t)node * (KK * DD);

    const float q0  = q[(size_t)node * 512 + h * DD + l32];
    const float q1  = q[(size_t)node * 512 + h * DD + l32 + 32];
    const float q2  = q[(size_t)node * 512 + h * DD + l32 + 64];
    const float q3  = q[(size_t)node * 512 + h * DD + l32 + 96];
    const float wb0 = Wb[(l32 +  0) * HH + h];
    const float wb1 = Wb[(l32 + 32) * HH + h];
    const float wb2 = Wb[(l32 + 64) * HH + h];
    const float wb3 = Wb[(l32 + 96) * HH + h];
    const float cpt = -0.5f * PT_SCALE * log1pf(expf(head_w[h]));
    const float bbh = INV3 * bb[h];
    const float qpl = (l32 < 24) ? s_qp[h * 24 + l32] : 0.f;

    // ---- logits: 2 k's per iteration; stage hE -> LDS bf16 (waves 0+1 only,
    // to write each element once) ----
    for (int kx2 = 0; kx2 < KK / 2; ++kx2) {
        const int k = kx2 * 2 + g;
        size_t jb = (size_t)(b * NN + s_j[k]);
        const ushort_t* kr = kb + jb * 512 + h * DD;
        float k0 = bf2f(kr[l32]),      k1 = bf2f(kr[l32 + 32]);
        float k2 = bf2f(kr[l32 + 64]), k3 = bf2f(kr[l32 + 96]);
        float s = q0 * k0 + q1 * k1 + q2 * k2 + q3 * k3;
        const float* her = hE_node + k * DD;
        float h0 = her[l32], h1 = her[l32 + 32], h2 = her[l32 + 64], h3 = her[l32 + 96];
        if (wv == 0) {
            s_hEb[k * DD + l32]      = f2bf(h0);
            s_hEb[k * DD + l32 + 32] = f2bf(h1);
            s_hEb[k * DD + l32 + 64] = f2bf(h2);
            s_hEb[k * DD + l32 + 96] = f2bf(h3);
        }
        float t = wb0 * h0 + wb1 * h1 + wb2 * h2 + wb3 * h3;
        float ptc = 0.f;
        if (l32 < 24) {
            float d = qpl - kpts[jb * 96 + h * 24 + l32];
            ptc = d * d;
        }
        float val = INV3C * s + INV3 * t + cpt * ptc;
        #pragma unroll
        for (int off = 16; off; off >>= 1) val += __shfl_down(val, off, 32);
        if (l32 == 0) s_p[h][k] = val + bbh + s_mask[k];
    }
    __syncthreads();

    // ---- softmax over k ----
    {
        float v = (lane < KK) ? s_p[h][lane] : -INFINITY;
        float m = v;
        #pragma unroll
        for (int off = 16; off; off >>= 1) m = fmaxf(m, __shfl_down(m, off));
        m = __shfl(m, 0);
        float e = (lane < KK) ? expf(v - m) : 0.f;
        float s = e;
        #pragma unroll
        for (int off = 16; off; off >>= 1) s += __shfl_down(s, off);
        s = __shfl(s, 0);
        if (lane < KK) s_p[h][lane] = e / s;
    }
    __syncthreads();

    // ---- o (bf16 gathered v) and o_pair (bf16 hE from LDS) ----
    {
        const int oh = tid >> 6;
        const int oc0 = (tid & 63) * 2;
        float a0 = 0.f, a1 = 0.f;
        for (int kx = 0; kx < KK; ++kx) {
            size_t jb = (size_t)(b * NN + s_j[kx]);
            unsigned pv = *(const unsigned*)&vb[jb * 512 + oh * DD + oc0];
            float p = s_p[oh][kx];
            a0 = fmaf(p, bf2f((ushort_t)(pv & 0xffff)), a0);
            a1 = fmaf(p, bf2f((ushort_t)(pv >> 16)), a1);
        }
        s_cat[oh * DD + oc0]     = a0;
        s_cat[oh * DD + oc0 + 1] = a1;
        float b0 = 0.f, b1 = 0.f;
        for (int kx = 0; kx < KK; ++kx) {
            unsigned pe = *(const unsigned*)&s_hEb[kx * DD + oc0];
            float p = s_p[oh][kx];
            b0 = fmaf(p, bf2f((ushort_t)(pe & 0xffff)), b0);
            b1 = fmaf(p, bf2f((ushort_t)(pe >> 16)), b1);
        }
        s_cat[576 + oh * DD + oc0]     = b0;
        s_cat[576 + oh * DD + oc0 + 1] = b1;
    }
    // ---- o_pt ----
    if (tid < 48) {
        int jj = tid / 3, d = tid % 3;
        int oh = jj >> 2;
        float acc = 0.f;
        for (int kx = 0; kx < KK; ++kx) {
            size_t jb = (size_t)(b * NN + s_j[kx]);
            acc = fmaf(s_p[oh][kx], vpts[jb * 48 + jj * 3 + d], acc);
        }
        s_opt[tid] = acc;
    }
    __syncthreads();
    if (tid < 16) {
        int jj = tid;
        float g0 = s_opt[jj * 3 + 0] - tvec[node * 3 + 0];
        float g1 = s_opt[jj * 3 + 1] - tvec[node * 3 + 1];
        float g2 = s_opt[jj * 3 + 2] - tvec[node * 3 + 2];
        float l0 = R[node * 9 + 0] * g0 + R[node * 9 + 3] * g1 + R[node * 9 + 6] * g2;
        float l1 = R[node * 9 + 1] * g0 + R[node * 9 + 4] * g1 + R[node * 9 + 7] * g2;
        float l2 = R[node * 9 + 2] * g0 + R[node * 9 + 5] * g1 + R[node * 9 + 8] * g2;
        s_cat[512 + 0 * 16 + jj] = l0;
        s_cat[512 + 1 * 16 + jj] = l1;
        s_cat[512 + 2 * 16 + jj] = l2;
        s_cat[560 + jj] = sqrtf(l0 * l0 + l1 * l1 + l2 * l2 + 1e-8f);
    }
    __syncthreads();

    // ---- write cat as bf16 ----
    for (int i = tid; i < 1088; i += 256)
        catb[(size_t)node * 1088 + i] = f2bf(s_cat[i]);
}

// ---- tail: MFMA GEMMs. 16 nodes/block, 512 threads (8 waves), grid 256. ----
__global__ __launch_bounds__(512) void tail_kernel(
    const float* __restrict__ hV, const float* __restrict__ maskV,
    const ushort_t* __restrict__ catb,
    const ushort_t* __restrict__ WoutT, const float* __restrict__ bout,
    const float* __restrict__ ln0w, const float* __restrict__ ln0b,
    const float* __restrict__ ln1w, const float* __restrict__ ln1b,
    const ushort_t* __restrict__ Wm1T, const float* __restrict__ bm1,
    const ushort_t* __restrict__ Wm2T, const float* __restrict__ bm2,
    float* __restrict__ out)
{
    const int node0 = blockIdx.x * TM;
    const int tid = threadIdx.x;
    const int w  = tid >> 6;    // wave 0..7
    const int l  = tid & 63;
    const int lr = l & 15;      // row/col lane index
    const int lk = l >> 4;      // k-group 0..3

    __shared__ float    s_x[TM][DD];
    __shared__ float    s_hv[TM][DD];
    __shared__ ushort_t s_hvb[TM][136];
    __shared__ ushort_t s_m1[TM][520];
    __shared__ float    s_rs[TM][16];
    __shared__ float    s_rq[TM][16];
    __shared__ float    s_stat[TM][2];

    // ---- GEMM1: s = cat[16x1088] @ Wout[1088x128]
    {
        f32x4 acc = {0.f, 0.f, 0.f, 0.f};
        const ushort_t* Ab = catb + (size_t)(node0 + lr) * 1088 + lk * 8;
        const ushort_t* Bb = WoutT + (size_t)(w * 16 + lr) * 1088 + lk * 8;
        #pragma unroll 2
        for (int ks = 0; ks < 34; ++ks) {
            short8 a = *(const short8*)(Ab + ks * 32);
            short8 bfr = *(const short8*)(Bb + ks * 32);
            acc = __builtin_amdgcn_mfma_f32_16x16x32_bf16(a, bfr, acc, 0, 0, 0);
        }
        #pragma unroll
        for (int i = 0; i < 4; ++i)
            s_x[lk * 4 + i][w * 16 + lr] = acc[i];
    }
    __syncthreads();

    // ---- bias + residual + LN0 ----
    if (tid < 256) {
        int r = tid >> 4, sg = tid & 15;
        float ss = 0.f, sq = 0.f;
        #pragma unroll
        for (int j = 0; j < 8; ++j) {
            int cc = sg * 8 + j;
            float x = s_x[r][cc] + bout[cc] + hV[(size_t)(node0 + r) * DD + cc];
            s_x[r][cc] = x;
            ss += x; sq += x * x;
        }
        s_rs[r][sg] = ss; s_rq[r][sg] = sq;
    }
    __syncthreads();
    if (tid < TM) {
        float ss = 0.f, sq = 0.f;
        #pragma unroll
        for (int sg = 0; sg < 16; ++sg) { ss += s_rs[tid][sg]; sq += s_rq[tid][sg]; }
        float mu = ss / 128.f;
        s_stat[tid][0] = mu;
        s_stat[tid][1] = rsqrtf(sq / 128.f - mu * mu + 1e-5f);
    }
    __syncthreads();
    {
        int idx = tid * 4;
        int r = idx >> 7, cc = idx & 127;
        float mu = s_stat[r][0], rstd = s_stat[r][1];
        #pragma unroll
        for (int j = 0; j < 4; ++j) {
            float hvv = (s_x[r][cc + j] - mu) * rstd * ln0w[cc + j] + ln0b[cc + j];
            s_hv[r][cc + j] = hvv;
            s_hvb[r][cc + j] = f2bf(hvv);
        }
    }
    __syncthreads();

    // ---- GEMM2: m1 = hv[16x128] @ Wm1[128x512], ReLU ----
    {
        const ushort_t* Ab = &s_hvb[lr][lk * 8];
        #pragma unroll
        for (int t = 0; t < 4; ++t) {
            int n0 = w * 64 + t * 16;
            f32x4 acc = {0.f, 0.f, 0.f, 0.f};
            const ushort_t* Bb = Wm1T + (size_t)(n0 + lr) * 128 + lk * 8;
            #pragma unroll
            for (int ks = 0; ks < 4; ++ks) {
                short8 a = *(const short8*)(Ab + ks * 32);
                short8 bfr = *(const short8*)(Bb + ks * 32);
                acc = __builtin_amdgcn_mfma_f32_16x16x32_bf16(a, bfr, acc, 0, 0, 0);
            }
            int n = n0 + lr;
            float bm = bm1[n];
            #pragma unroll
            for (int i = 0; i < 4; ++i)
                s_m1[lk * 4 + i][n] = f2bf(fmaxf(acc[i] + bm, 0.f));
        }
    }
    __syncthreads();

    // ---- GEMM3: m = m1[16x512] @ Wm2[512x128] ----
    {
        f32x4 acc = {0.f, 0.f, 0.f, 0.f};
        const ushort_t* Ab = &s_m1[lr][lk * 8];
        const ushort_t* Bb = Wm2T + (size_t)(w * 16 + lr) * 512 + lk * 8;
        #pragma unroll 4
        for (int ks = 0; ks < 16; ++ks) {
            short8 a = *(const short8*)(Ab + ks * 32);
            short8 bfr = *(const short8*)(Bb + ks * 32);
            acc = __builtin_amdgcn_mfma_f32_16x16x32_bf16(a, bfr, acc, 0, 0, 0);
        }
        #pragma unroll
        for (int i = 0; i < 4; ++i)
            s_x[lk * 4 + i][w * 16 + lr] = acc[i];
    }
    __syncthreads();

    // ---- bm2 + residual + LN1 ----
    if (tid < 256) {
        int r = tid >> 4, sg = tid & 15;
        float ss = 0.f, sq = 0.f;
        #pragma unroll
        for (int j = 0; j < 8; ++j) {
            int cc = sg * 8 + j;
            float x = s_x[r][cc] + bm2[cc] + s_hv[r][cc];
            s_x[r][cc] = x;
            ss += x; sq += x * x;
        }
        s_rs[r][sg] = ss; s_rq[r][sg] = sq;
    }
    __syncthreads();
    if (tid < TM) {
        float ss = 0.f, sq = 0.f;
        #pragma unroll
        for (int sg = 0; sg < 16; ++sg) { ss += s_rs[tid][sg]; sq += s_rq[tid][sg]; }
        float mu = ss / 128.f;
        s_stat[tid][0] = mu;
        s_stat[tid][1] = rsqrtf(sq / 128.f - mu * mu + 1e-5f);
    }
    __syncthreads();
    {
        int idx = tid * 4;
        int r = idx >> 7, cc = idx & 127;
        float mu = s_stat[r][0], rstd = s_stat[r][1];
        float mk = maskV[node0 + r];
        float4 o;
        o.x = ((s_x[r][cc + 0] - mu) * rstd * ln1w[cc + 0] + ln1b[cc + 0]) * mk;
        o.y = ((s_x[r][cc + 1] - mu) * rstd * ln1w[cc + 1] + ln1b[cc + 1]) * mk;
        o.z = ((s_x[r][cc + 2] - mu) * rstd * ln1w[cc + 2] + ln1b[cc + 2]) * mk;
        o.w = ((s_x[r][cc + 3] - mu) * rstd * ln1w[cc + 3] + ln1b[cc + 3]) * mk;
        *(float4*)&out[(size_t)(node0 + r) * DD + cc] = o;
    }
}

extern "C" void kernel_launch(void* const* d_in, const int* in_sizes, int n_in,
                              void* d_out, int out_size, void* d_ws, size_t ws_size,
                              hipStream_t stream)
{
    const float* hV      = (const float*)d_in[0];
    const float* hE      = (const float*)d_in[1];
    const int*   Eidx    = (const int*)  d_in[2];
    const float* R       = (const float*)d_in[3];
    const float* tvec    = (const float*)d_in[4];
    const float* mask_at = (const float*)d_in[5];
    const float* maskV   = (const float*)d_in[6];
    const float* Wq      = (const float*)d_in[7];
    const float* bq      = (const float*)d_in[8];
    const float* Wkv     = (const float*)d_in[9];
    const float* bkv     = (const float*)d_in[10];
    const float* Wqp     = (const float*)d_in[11];
    const float* bqp     = (const float*)d_in[12];
    const float* Wkvp    = (const float*)d_in[13];
    const float* bkvp    = (const float*)d_in[14];
    const float* Wb      = (const float*)d_in[15];
    const float* bb      = (const float*)d_in[16];
    const float* hw      = (const float*)d_in[17];
    const float* Wout    = (const float*)d_in[18];
    const float* bout    = (const float*)d_in[19];
    const float* ln0w    = (const float*)d_in[20];
    const float* ln0b    = (const float*)d_in[21];
    const float* ln1w    = (const float*)d_in[22];
    const float* ln1b    = (const float*)d_in[23];
    const float* Wm1     = (const float*)d_in[24];
    const float* bm1     = (const float*)d_in[25];
    const float* Wm2     = (const float*)d_in[26];
    const float* bm2     = (const float*)d_in[27];

    const size_t nodes = (size_t)BB * NN;
    float* ws  = (float*)d_ws;
    float* q   = ws;                       // nodes*512 f32
    float* qp  = q  + nodes * 512;         // nodes*96  f32
    float* kp  = qp + nodes * 96;          // nodes*96  f32
    float* vp  = kp + nodes * 96;          // nodes*48  f32
    ushort_t* kb    = (ushort_t*)(vp + nodes * 48);   // nodes*512 bf16
    ushort_t* vb    = kb + nodes * 512;               // nodes*512 bf16
    ushort_t* catb  = vb + nodes * 512;               // nodes*1088 bf16
    ushort_t* WoutT = catb  + nodes * 1088;
    ushort_t* Wm1T  = WoutT + 128 * 1088;
    ushort_t* Wm2T  = Wm1T  + 512 * 128;

    prep_kernel<<<256, 256, 0, stream>>>(Wout, Wm1, Wm2, WoutT, Wm1T, Wm2T);

    proj_kernel<<<(int)(nodes / NPB) * 2, 256, 0, stream>>>(
        hV, R, tvec, Wq, bq, Wkv, bkv, Wqp, bqp, Wkvp, bkvp,
        q, kb, vb, qp, kp, vp);

    attn_kernel<<<(int)nodes, 256, 0, stream>>>(
        hE, Eidx, R, tvec, mask_at,
        Wb, bb, hw,
        q, kb, vb, qp, kp, vp, catb);

    tail_kernel<<<(int)(nodes / TM), 512, 0, stream>>>(
        hV, maskV, catb,
        WoutT, bout, ln0w, ln0b, ln1w, ln1b,
        Wm1T, bm1, Wm2T, bm2, (float*)d_out);
}

// Round 9
// 117.386 us; speedup vs baseline: 3.1739x; 1.0141x over previous
//
#include <hip/hip_runtime.h>
#include <math.h>

#define BB 2
#define NN 2048
#define KK 30
#define DD 128
#define HH 4
#define PQ_ 8
#define PV_ 4
#define TM 16      // nodes per MFMA block (proj + tail)

#define INV3C    0.05103103630798288f   // sqrt(1/(3*128))
#define INV3     0.5773502691896258f    // sqrt(1/3)
#define PT_SCALE 0.09622504486493764f   // sqrt(1/108)

typedef __attribute__((ext_vector_type(8))) short short8;
typedef __attribute__((ext_vector_type(4))) float f32x4;
typedef unsigned short ushort_t;

__device__ __forceinline__ ushort_t f2bf(float f) {
    unsigned u = __float_as_uint(f);
    unsigned r = u + 0x7FFFu + ((u >> 16) & 1u);   // RNE
    return (ushort_t)(r >> 16);
}
__device__ __forceinline__ float bf2f(ushort_t u) {
    return __uint_as_float(((unsigned)u) << 16);
}
__device__ __forceinline__ float bflo(unsigned u) {
    return __uint_as_float(u << 16);
}
__device__ __forceinline__ float bfhi(unsigned u) {
    return __uint_as_float(u & 0xffff0000u);
}

// ---- weight prep: bf16 transposed weights for all MFMA GEMMs ----
__global__ __launch_bounds__(256) void prep_kernel(
    const float* __restrict__ Wout, const float* __restrict__ Wm1,
    const float* __restrict__ Wm2,
    const float* __restrict__ Wq, const float* __restrict__ Wkv,
    const float* __restrict__ Wqp, const float* __restrict__ Wkvp,
    ushort_t* __restrict__ WoutT, ushort_t* __restrict__ Wm1T,
    ushort_t* __restrict__ Wm2T, ushort_t* __restrict__ WprojT)
{
    const int stride = gridDim.x * blockDim.x;
    const int t0 = blockIdx.x * blockDim.x + threadIdx.x;
    for (int idx = t0; idx < 128 * 1088; idx += stride) {
        int n = idx / 1088, k = idx - n * 1088;
        WoutT[idx] = f2bf(Wout[(size_t)k * 128 + n]);
    }
    for (int idx = t0; idx < 512 * 128; idx += stride) {
        int n = idx >> 7, k = idx & 127;
        Wm1T[idx] = f2bf(Wm1[(size_t)k * 512 + n]);
    }
    for (int idx = t0; idx < 128 * 512; idx += stride) {
        int n = idx >> 9, k = idx & 511;
        Wm2T[idx] = f2bf(Wm2[(size_t)k * 128 + n]);
    }
    // fused proj weight: n<512 q | 512..1536 kv | 1536..1632 qp | 1632..1776 kvp | pad
    for (int idx = t0; idx < 1792 * 128; idx += stride) {
        int n = idx >> 7, k = idx & 127;
        float v;
        if (n < 512)       v = Wq[(size_t)k * 512 + n];
        else if (n < 1536) v = Wkv[(size_t)k * 1024 + (n - 512)];
        else if (n < 1632) v = Wqp[k * 96 + (n - 1536)];
        else if (n < 1776) v = Wkvp[k * 144 + (n - 1632)];
        else               v = 0.f;
        WprojT[idx] = f2bf(v);
    }
}

// ---- proj: MFMA GEMM X[16x128]bf16 @ WprojT. 2 blocks per 16-node group
// (tile split), epilogue scatters bf16 q/k/v + stages qp/kvp for rigid. ----
__global__ __launch_bounds__(512) void proj_kernel(
    const float* __restrict__ hV, const float* __restrict__ R, const float* __restrict__ tvec,
    const ushort_t* __restrict__ WT,
    const float* __restrict__ bq, const float* __restrict__ bkv,
    const float* __restrict__ bqp, const float* __restrict__ bkvp,
    ushort_t* __restrict__ qb, ushort_t* __restrict__ kb, ushort_t* __restrict__ vb,
    float* __restrict__ qpts, float* __restrict__ kpts, float* __restrict__ vpts)
{
    const int node0 = (blockIdx.x >> 1) * TM;
    const int half  = blockIdx.x & 1;
    const int tid = threadIdx.x;
    const int w = tid >> 6, l = tid & 63, lr = l & 15, lk = l >> 4;

    __shared__ ushort_t s_A[TM][128];    // 4 KB bf16 A tile
    __shared__ float s_qp[TM][96];       // 6 KB
    __shared__ float s_kvp[TM][144];     // 9 KB

    {
        int i = tid * 4; int r = i >> 7, c = i & 127;
        float4 x = *(const float4*)&hV[(size_t)(node0 + r) * DD + c];
        s_A[r][c + 0] = f2bf(x.x); s_A[r][c + 1] = f2bf(x.y);
        s_A[r][c + 2] = f2bf(x.z); s_A[r][c + 3] = f2bf(x.w);
    }
    __syncthreads();

    const ushort_t* Ab = &s_A[lr][lk * 8];
    // 112 tiles of 16 cols; half h owns tiles [h*56, h*56+56); 7 per wave
    for (int t = 0; t < 7; ++t) {
        const int tile = half * 56 + w * 7 + t;
        const int n = tile * 16 + lr;
        f32x4 acc = {0.f, 0.f, 0.f, 0.f};
        const ushort_t* Bb = WT + (size_t)n * 128 + lk * 8;
        #pragma unroll
        for (int ks = 0; ks < 4; ++ks) {
            short8 a = *(const short8*)(Ab + ks * 32);
            short8 bfr = *(const short8*)(Bb + ks * 32);
            acc = __builtin_amdgcn_mfma_f32_16x16x32_bf16(a, bfr, acc, 0, 0, 0);
        }
        // C: col = n (lane&15), rows = node0 + lk*4 + i
        if (n < 512) {
            float bias = bq[n];
            #pragma unroll
            for (int i = 0; i < 4; ++i)
                qb[(size_t)(node0 + lk * 4 + i) * 512 + n] = f2bf(acc[i] + bias);
        } else if (n < 1536) {
            int n2 = n - 512;
            float bias = bkv[n2];
            int hh = n2 >> 8, wcol = n2 & 255;
            ushort_t* base = (wcol < 128) ? kb : vb;
            int off = hh * DD + (wcol & 127);
            #pragma unroll
            for (int i = 0; i < 4; ++i)
                base[(size_t)(node0 + lk * 4 + i) * 512 + off] = f2bf(acc[i] + bias);
        } else if (n < 1632) {
            int c = n - 1536;
            float bias = bqp[c];
            #pragma unroll
            for (int i = 0; i < 4; ++i) s_qp[lk * 4 + i][c] = acc[i] + bias;
        } else if (n < 1776) {
            int c = n - 1632;
            float bias = bkvp[c];
            #pragma unroll
            for (int i = 0; i < 4; ++i) s_kvp[lk * 4 + i][c] = acc[i] + bias;
        }
    }
    __syncthreads();

    if (half == 1) {
        // rigid transform q_pts: out[x] = sum_y R[x,y]*p[y] + t[x]
        for (int idx = tid; idx < TM * 96; idx += 512) {
            int r = idx / 96, u = idx % 96;
            int j = u / 3, d = u % 3;
            int node = node0 + r;
            float acc = tvec[node * 3 + d];
            #pragma unroll
            for (int y = 0; y < 3; ++y)
                acc = fmaf(R[node * 9 + d * 3 + y], s_qp[r][y * 32 + j], acc);
            qpts[(size_t)node * 96 + j * 3 + d] = acc;
        }
        for (int idx = tid; idx < TM * 144; idx += 512) {
            int r = idx / 144, u = idx % 144;
            int jj = u / 3, d = u % 3;
            int node = node0 + r;
            float acc = tvec[node * 3 + d];
            #pragma unroll
            for (int y = 0; y < 3; ++y)
                acc = fmaf(R[node * 9 + d * 3 + y], s_kvp[r][y * 48 + jj], acc);
            int hh = jj / 12, pp = jj % 12;
            if (pp < PQ_) kpts[(size_t)node * 96 + (hh * PQ_ + pp) * 3 + d] = acc;
            else          vpts[(size_t)node * 48 + (hh * PV_ + (pp - PQ_)) * 3 + d] = acc;
        }
    }
}

// ---- attn core: bf16 q/k/v, hE single HBM pass, 6-deep prefetch ILP ----
__global__ __launch_bounds__(256, 8) void attn_kernel(
    const float* __restrict__ hE, const int* __restrict__ Eidx,
    const float* __restrict__ R, const float* __restrict__ tvec,
    const float* __restrict__ mask_att,
    const float* __restrict__ Wb, const float* __restrict__ bb,
    const float* __restrict__ head_w,
    const ushort_t* __restrict__ qb, const ushort_t* __restrict__ kb,
    const ushort_t* __restrict__ vb,
    const float* __restrict__ qpts, const float* __restrict__ kpts, const float* __restrict__ vpts,
    ushort_t* __restrict__ catb)
{
    const int node = blockIdx.x;
    const int b = node >> 11;
    const int tid = threadIdx.x;
    const int lane = tid & 63;
    const int wv = tid >> 6;

    __shared__ ushort_t s_hEb[KK * DD];   // 7680 B
    __shared__ float s_cat[1088];
    __shared__ float s_qp[96];
    __shared__ float s_p[HH][32];
    __shared__ int   s_j[32];
    __shared__ float s_mask[32];
    __shared__ float s_opt[48];

    if (tid < 96) s_qp[tid] = qpts[(size_t)node * 96 + tid];
    if (tid < KK) {
        s_j[tid] = Eidx[(size_t)node * KK + tid];
        s_mask[tid] = 100000.0f * (mask_att[(size_t)node * KK + tid] - 1.0f);
    }
    __syncthreads();

    const int h = wv;
    const int l32 = lane & 31;
    const int g = lane >> 5;
    const float* hE_node = hE + (size_t)node * (KK * DD);

    // q pairs: elems {2*l32, 2*l32+1} and {64+2*l32, 65+2*l32}
    const unsigned qu0 = *(const unsigned*)&qb[(size_t)node * 512 + h * DD + 2 * l32];
    const unsigned qu1 = *(const unsigned*)&qb[(size_t)node * 512 + h * DD + 64 + 2 * l32];
    const float q0 = bflo(qu0), q1 = bfhi(qu0), q2 = bflo(qu1), q3 = bfhi(qu1);
    const float wb0 = Wb[(l32 +  0) * HH + h];
    const float wb1 = Wb[(l32 + 32) * HH + h];
    const float wb2 = Wb[(l32 + 64) * HH + h];
    const float wb3 = Wb[(l32 + 96) * HH + h];
    const float cpt = -0.5f * PT_SCALE * log1pf(expf(head_w[h]));
    const float bbh = INV3 * bb[h];
    const float qpl = (l32 < 24) ? s_qp[h * 24 + l32] : 0.f;

    // ---- logits: 2 k's per iteration; stage hE -> LDS bf16 (wave 0) ----
    for (int kx2 = 0; kx2 < KK / 2; ++kx2) {
        const int k = kx2 * 2 + g;
        size_t jb = (size_t)(b * NN + s_j[k]);
        const ushort_t* kr = kb + jb * 512 + h * DD;
        unsigned ku0 = *(const unsigned*)&kr[2 * l32];
        unsigned ku1 = *(const unsigned*)&kr[64 + 2 * l32];
        float s = q0 * bflo(ku0) + q1 * bfhi(ku0) + q2 * bflo(ku1) + q3 * bfhi(ku1);
        const float* her = hE_node + k * DD;
        float h0 = her[l32], h1 = her[l32 + 32], h2 = her[l32 + 64], h3 = her[l32 + 96];
        if (wv == 0) {
            s_hEb[k * DD + l32]      = f2bf(h0);
            s_hEb[k * DD + l32 + 32] = f2bf(h1);
            s_hEb[k * DD + l32 + 64] = f2bf(h2);
            s_hEb[k * DD + l32 + 96] = f2bf(h3);
        }
        float t = wb0 * h0 + wb1 * h1 + wb2 * h2 + wb3 * h3;
        float ptc = 0.f;
        if (l32 < 24) {
            float d = qpl - kpts[jb * 96 + h * 24 + l32];
            ptc = d * d;
        }
        float val = INV3C * s + INV3 * t + cpt * ptc;
        #pragma unroll
        for (int off = 16; off; off >>= 1) val += __shfl_down(val, off, 32);
        if (l32 == 0) s_p[h][k] = val + bbh + s_mask[k];
    }
    __syncthreads();

    // ---- softmax over k ----
    {
        float v = (lane < KK) ? s_p[h][lane] : -INFINITY;
        float m = v;
        #pragma unroll
        for (int off = 16; off; off >>= 1) m = fmaxf(m, __shfl_down(m, off));
        m = __shfl(m, 0);
        float e = (lane < KK) ? expf(v - m) : 0.f;
        float s = e;
        #pragma unroll
        for (int off = 16; off; off >>= 1) s += __shfl_down(s, off);
        s = __shfl(s, 0);
        if (lane < KK) s_p[h][lane] = e / s;
    }
    __syncthreads();

    // ---- o (bf16 gathered v) + o_pair (LDS hE), 6-deep rolling prefetch ----
    {
        const int oh = tid >> 6;
        const int oc0 = (tid & 63) * 2;
        const ushort_t* vrow = vb + oh * DD + oc0;
        float a0 = 0.f, a1 = 0.f, b0 = 0.f, b1 = 0.f;
        unsigned buf[6];
        #pragma unroll
        for (int j = 0; j < 6; ++j)
            buf[j] = *(const unsigned*)(vrow + (size_t)(b * NN + s_j[j]) * 512);
        #pragma unroll
        for (int base = 0; base < KK; base += 6) {
            unsigned nbuf[6];
            if (base + 6 < KK) {
                #pragma unroll
                for (int j = 0; j < 6; ++j)
                    nbuf[j] = *(const unsigned*)(vrow + (size_t)(b * NN + s_j[base + 6 + j]) * 512);
            }
            #pragma unroll
            for (int j = 0; j < 6; ++j) {
                const int kx = base + j;
                float p = s_p[oh][kx];
                a0 = fmaf(p, bflo(buf[j]), a0);
                a1 = fmaf(p, bfhi(buf[j]), a1);
                unsigned pe = *(const unsigned*)&s_hEb[kx * DD + oc0];
                b0 = fmaf(p, bflo(pe), b0);
                b1 = fmaf(p, bfhi(pe), b1);
            }
            #pragma unroll
            for (int j = 0; j < 6; ++j) buf[j] = nbuf[j];
        }
        s_cat[oh * DD + oc0]           = a0;
        s_cat[oh * DD + oc0 + 1]       = a1;
        s_cat[576 + oh * DD + oc0]     = b0;
        s_cat[576 + oh * DD + oc0 + 1] = b1;
    }
    // ---- o_pt: 48 items, 6-deep prefetch ----
    if (tid < 48) {
        const int oh = (tid / 3) >> 2;
        float acc = 0.f;
        float fb[6];
        #pragma unroll
        for (int j = 0; j < 6; ++j)
            fb[j] = vpts[(size_t)(b * NN + s_j[j]) * 48 + tid];
        #pragma unroll
        for (int base = 0; base < KK; base += 6) {
            float nb[6];
            if (base + 6 < KK) {
                #pragma unroll
                for (int j = 0; j < 6; ++j)
                    nb[j] = vpts[(size_t)(b * NN + s_j[base + 6 + j]) * 48 + tid];
            }
            #pragma unroll
            for (int j = 0; j < 6; ++j)
                acc = fmaf(s_p[oh][base + j], fb[j], acc);
            #pragma unroll
            for (int j = 0; j < 6; ++j) fb[j] = nb[j];
        }
        s_opt[tid] = acc;
    }
    __syncthreads();
    if (tid < 16) {
        int jj = tid;
        float g0 = s_opt[jj * 3 + 0] - tvec[node * 3 + 0];
        float g1 = s_opt[jj * 3 + 1] - tvec[node * 3 + 1];
        float g2 = s_opt[jj * 3 + 2] - tvec[node * 3 + 2];
        float l0 = R[node * 9 + 0] * g0 + R[node * 9 + 3] * g1 + R[node * 9 + 6] * g2;
        float l1 = R[node * 9 + 1] * g0 + R[node * 9 + 4] * g1 + R[node * 9 + 7] * g2;
        float l2 = R[node * 9 + 2] * g0 + R[node * 9 + 5] * g1 + R[node * 9 + 8] * g2;
        s_cat[512 + 0 * 16 + jj] = l0;
        s_cat[512 + 1 * 16 + jj] = l1;
        s_cat[512 + 2 * 16 + jj] = l2;
        s_cat[560 + jj] = sqrtf(l0 * l0 + l1 * l1 + l2 * l2 + 1e-8f);
    }
    __syncthreads();

    for (int i = tid; i < 1088; i += 256)
        catb[(size_t)node * 1088 + i] = f2bf(s_cat[i]);
}

// ---- tail: MFMA GEMMs. 16 nodes/block, 512 threads (8 waves), grid 256. ----
__global__ __launch_bounds__(512) void tail_kernel(
    const float* __restrict__ hV, const float* __restrict__ maskV,
    const ushort_t* __restrict__ catb,
    const ushort_t* __restrict__ WoutT, const float* __restrict__ bout,
    const float* __restrict__ ln0w, const float* __restrict__ ln0b,
    const float* __restrict__ ln1w, const float* __restrict__ ln1b,
    const ushort_t* __restrict__ Wm1T, const float* __restrict__ bm1,
    const ushort_t* __restrict__ Wm2T, const float* __restrict__ bm2,
    float* __restrict__ out)
{
    const int node0 = blockIdx.x * TM;
    const int tid = threadIdx.x;
    const int w  = tid >> 6;
    const int l  = tid & 63;
    const int lr = l & 15;
    const int lk = l >> 4;

    __shared__ float    s_x[TM][DD];
    __shared__ float    s_hv[TM][DD];
    __shared__ ushort_t s_hvb[TM][136];
    __shared__ ushort_t s_m1[TM][520];
    __shared__ float    s_rs[TM][16];
    __shared__ float    s_rq[TM][16];
    __shared__ float    s_stat[TM][2];

    // ---- GEMM1: s = cat[16x1088] @ Wout[1088x128]
    {
        f32x4 acc = {0.f, 0.f, 0.f, 0.f};
        const ushort_t* Ab = catb + (size_t)(node0 + lr) * 1088 + lk * 8;
        const ushort_t* Bb = WoutT + (size_t)(w * 16 + lr) * 1088 + lk * 8;
        #pragma unroll 2
        for (int ks = 0; ks < 34; ++ks) {
            short8 a = *(const short8*)(Ab + ks * 32);
            short8 bfr = *(const short8*)(Bb + ks * 32);
            acc = __builtin_amdgcn_mfma_f32_16x16x32_bf16(a, bfr, acc, 0, 0, 0);
        }
        #pragma unroll
        for (int i = 0; i < 4; ++i)
            s_x[lk * 4 + i][w * 16 + lr] = acc[i];
    }
    __syncthreads();

    // ---- bias + residual + LN0 ----
    if (tid < 256) {
        int r = tid >> 4, sg = tid & 15;
        float ss = 0.f, sq = 0.f;
        #pragma unroll
        for (int j = 0; j < 8; ++j) {
            int cc = sg * 8 + j;
            float x = s_x[r][cc] + bout[cc] + hV[(size_t)(node0 + r) * DD + cc];
            s_x[r][cc] = x;
            ss += x; sq += x * x;
        }
        s_rs[r][sg] = ss; s_rq[r][sg] = sq;
    }
    __syncthreads();
    if (tid < TM) {
        float ss = 0.f, sq = 0.f;
        #pragma unroll
        for (int sg = 0; sg < 16; ++sg) { ss += s_rs[tid][sg]; sq += s_rq[tid][sg]; }
        float mu = ss / 128.f;
        s_stat[tid][0] = mu;
        s_stat[tid][1] = rsqrtf(sq / 128.f - mu * mu + 1e-5f);
    }
    __syncthreads();
    {
        int idx = tid * 4;
        int r = idx >> 7, cc = idx & 127;
        float mu = s_stat[r][0], rstd = s_stat[r][1];
        #pragma unroll
        for (int j = 0; j < 4; ++j) {
            float hvv = (s_x[r][cc + j] - mu) * rstd * ln0w[cc + j] + ln0b[cc + j];
            s_hv[r][cc + j] = hvv;
            s_hvb[r][cc + j] = f2bf(hvv);
        }
    }
    __syncthreads();

    // ---- GEMM2: m1 = hv[16x128] @ Wm1[128x512], ReLU ----
    {
        const ushort_t* Ab = &s_hvb[lr][lk * 8];
        #pragma unroll
        for (int t = 0; t < 4; ++t) {
            int n0 = w * 64 + t * 16;
            f32x4 acc = {0.f, 0.f, 0.f, 0.f};
            const ushort_t* Bb = Wm1T + (size_t)(n0 + lr) * 128 + lk * 8;
            #pragma unroll
            for (int ks = 0; ks < 4; ++ks) {
                short8 a = *(const short8*)(Ab + ks * 32);
                short8 bfr = *(const short8*)(Bb + ks * 32);
                acc = __builtin_amdgcn_mfma_f32_16x16x32_bf16(a, bfr, acc, 0, 0, 0);
            }
            int n = n0 + lr;
            float bm = bm1[n];
            #pragma unroll
            for (int i = 0; i < 4; ++i)
                s_m1[lk * 4 + i][n] = f2bf(fmaxf(acc[i] + bm, 0.f));
        }
    }
    __syncthreads();

    // ---- GEMM3: m = m1[16x512] @ Wm2[512x128] ----
    {
        f32x4 acc = {0.f, 0.f, 0.f, 0.f};
        const ushort_t* Ab = &s_m1[lr][lk * 8];
        const ushort_t* Bb = Wm2T + (size_t)(w * 16 + lr) * 512 + lk * 8;
        #pragma unroll 4
        for (int ks = 0; ks < 16; ++ks) {
            short8 a = *(const short8*)(Ab + ks * 32);
            short8 bfr = *(const short8*)(Bb + ks * 32);
            acc = __builtin_amdgcn_mfma_f32_16x16x32_bf16(a, bfr, acc, 0, 0, 0);
        }
        #pragma unroll
        for (int i = 0; i < 4; ++i)
            s_x[lk * 4 + i][w * 16 + lr] = acc[i];
    }
    __syncthreads();

    // ---- bm2 + residual + LN1 ----
    if (tid < 256) {
        int r = tid >> 4, sg = tid & 15;
        float ss = 0.f, sq = 0.f;
        #pragma unroll
        for (int j = 0; j < 8; ++j) {
            int cc = sg * 8 + j;
            float x = s_x[r][cc] + bm2[cc] + s_hv[r][cc];
            s_x[r][cc] = x;
            ss += x; sq += x * x;
        }
        s_rs[r][sg] = ss; s_rq[r][sg] = sq;
    }
    __syncthreads();
    if (tid < TM) {
        float ss = 0.f, sq = 0.f;
        #pragma unroll
        for (int sg = 0; sg < 16; ++sg) { ss += s_rs[tid][sg]; sq += s_rq[tid][sg]; }
        float mu = ss / 128.f;
        s_stat[tid][0] = mu;
        s_stat[tid][1] = rsqrtf(sq / 128.f - mu * mu + 1e-5f);
    }
    __syncthreads();
    {
        int idx = tid * 4;
        int r = idx >> 7, cc = idx & 127;
        float mu = s_stat[r][0], rstd = s_stat[r][1];
        float mk = maskV[node0 + r];
        float4 o;
        o.x = ((s_x[r][cc + 0] - mu) * rstd * ln1w[cc + 0] + ln1b[cc + 0]) * mk;
        o.y = ((s_x[r][cc + 1] - mu) * rstd * ln1w[cc + 1] + ln1b[cc + 1]) * mk;
        o.z = ((s_x[r][cc + 2] - mu) * rstd * ln1w[cc + 2] + ln1b[cc + 2]) * mk;
        o.w = ((s_x[r][cc + 3] - mu) * rstd * ln1w[cc + 3] + ln1b[cc + 3]) * mk;
        *(float4*)&out[(size_t)(node0 + r) * DD + cc] = o;
    }
}

extern "C" void kernel_launch(void* const* d_in, const int* in_sizes, int n_in,
                              void* d_out, int out_size, void* d_ws, size_t ws_size,
                              hipStream_t stream)
{
    const float* hV      = (const float*)d_in[0];
    const float* hE      = (const float*)d_in[1];
    const int*   Eidx    = (const int*)  d_in[2];
    const float* R       = (const float*)d_in[3];
    const float* tvec    = (const float*)d_in[4];
    const float* mask_at = (const float*)d_in[5];
    const float* maskV   = (const float*)d_in[6];
    const float* Wq      = (const float*)d_in[7];
    const float* bq      = (const float*)d_in[8];
    const float* Wkv     = (const float*)d_in[9];
    const float* bkv     = (const float*)d_in[10];
    const float* Wqp     = (const float*)d_in[11];
    const float* bqp     = (const float*)d_in[12];
    const float* Wkvp    = (const float*)d_in[13];
    const float* bkvp    = (const float*)d_in[14];
    const float* Wb      = (const float*)d_in[15];
    const float* bb      = (const float*)d_in[16];
    const float* hw      = (const float*)d_in[17];
    const float* Wout    = (const float*)d_in[18];
    const float* bout    = (const float*)d_in[19];
    const float* ln0w    = (const float*)d_in[20];
    const float* ln0b    = (const float*)d_in[21];
    const float* ln1w    = (const float*)d_in[22];
    const float* ln1b    = (const float*)d_in[23];
    const float* Wm1     = (const float*)d_in[24];
    const float* bm1     = (const float*)d_in[25];
    const float* Wm2     = (const float*)d_in[26];
    const float* bm2     = (const float*)d_in[27];

    const size_t nodes = (size_t)BB * NN;
    ushort_t* qb     = (ushort_t*)d_ws;                 // nodes*512 bf16
    ushort_t* kb     = qb + nodes * 512;
    ushort_t* vb     = kb + nodes * 512;
    ushort_t* catb   = vb + nodes * 512;                // nodes*1088
    ushort_t* WoutT  = catb + nodes * 1088;
    ushort_t* Wm1T   = WoutT + 128 * 1088;
    ushort_t* Wm2T   = Wm1T + 512 * 128;
    ushort_t* WprojT = Wm2T + 128 * 512;                // 1792*128
    float* qpts = (float*)(WprojT + 1792 * 128);
    float* kpts = qpts + nodes * 96;
    float* vpts = kpts + nodes * 96;

    prep_kernel<<<256, 256, 0, stream>>>(Wout, Wm1, Wm2, Wq, Wkv, Wqp, Wkvp,
                                         WoutT, Wm1T, Wm2T, WprojT);

    proj_kernel<<<(int)(nodes / TM) * 2, 512, 0, stream>>>(
        hV, R, tvec, WprojT, bq, bkv, bqp, bkvp,
        qb, kb, vb, qpts, kpts, vpts);

    attn_kernel<<<(int)nodes, 256, 0, stream>>>(
        hE, Eidx, R, tvec, mask_at,
        Wb, bb, hw,
        qb, kb, vb, qpts, kpts, vpts, catb);

    tail_kernel<<<(int)(nodes / TM), 512, 0, stream>>>(
        hV, maskV, catb,
        WoutT, bout, ln0w, ln0b, ln1w, ln1b,
        Wm1T, bm1, Wm2T, bm2, (float*)d_out);
}

// Round 10
// 103.686 us; speedup vs baseline: 3.5932x; 1.1321x over previous
//
#include <hip/hip_runtime.h>
#include <math.h>

#define BB 2
#define NN 2048
#define KK 30
#define DD 128
#define HH 4
#define PQ_ 8
#define PV_ 4
#define TM 16      // nodes per MFMA block (proj + tail)

#define INV3C    0.05103103630798288f   // sqrt(1/(3*128))
#define INV3     0.5773502691896258f    // sqrt(1/3)
#define PT_SCALE 0.09622504486493764f   // sqrt(1/108)

typedef __attribute__((ext_vector_type(8))) short short8;
typedef __attribute__((ext_vector_type(4))) float f32x4;
typedef unsigned short ushort_t;

__device__ __forceinline__ ushort_t f2bf(float f) {
    unsigned u = __float_as_uint(f);
    unsigned r = u + 0x7FFFu + ((u >> 16) & 1u);   // RNE
    return (ushort_t)(r >> 16);
}
__device__ __forceinline__ float bf2f(ushort_t u) {
    return __uint_as_float(((unsigned)u) << 16);
}
__device__ __forceinline__ float bflo(unsigned u) {
    return __uint_as_float(u << 16);
}
__device__ __forceinline__ float bfhi(unsigned u) {
    return __uint_as_float(u & 0xffff0000u);
}

// ---- weight prep: bf16 transposed weights for all MFMA GEMMs ----
__global__ __launch_bounds__(256) void prep_kernel(
    const float* __restrict__ Wout, const float* __restrict__ Wm1,
    const float* __restrict__ Wm2,
    const float* __restrict__ Wq, const float* __restrict__ Wkv,
    const float* __restrict__ Wqp, const float* __restrict__ Wkvp,
    ushort_t* __restrict__ WoutT, ushort_t* __restrict__ Wm1T,
    ushort_t* __restrict__ Wm2T, ushort_t* __restrict__ WprojT)
{
    const int stride = gridDim.x * blockDim.x;
    const int t0 = blockIdx.x * blockDim.x + threadIdx.x;
    for (int idx = t0; idx < 128 * 1088; idx += stride) {
        int n = idx / 1088, k = idx - n * 1088;
        WoutT[idx] = f2bf(Wout[(size_t)k * 128 + n]);
    }
    for (int idx = t0; idx < 512 * 128; idx += stride) {
        int n = idx >> 7, k = idx & 127;
        Wm1T[idx] = f2bf(Wm1[(size_t)k * 512 + n]);
    }
    for (int idx = t0; idx < 128 * 512; idx += stride) {
        int n = idx >> 9, k = idx & 511;
        Wm2T[idx] = f2bf(Wm2[(size_t)k * 128 + n]);
    }
    // fused proj weight: n<512 q | 512..1536 kv | 1536..1632 qp | 1632..1776 kvp | pad
    for (int idx = t0; idx < 1792 * 128; idx += stride) {
        int n = idx >> 7, k = idx & 127;
        float v;
        if (n < 512)       v = Wq[(size_t)k * 512 + n];
        else if (n < 1536) v = Wkv[(size_t)k * 1024 + (n - 512)];
        else if (n < 1632) v = Wqp[k * 96 + (n - 1536)];
        else if (n < 1776) v = Wkvp[k * 144 + (n - 1632)];
        else               v = 0.f;
        WprojT[idx] = f2bf(v);
    }
}

// ---- proj: MFMA GEMM X[16x128]bf16 @ WprojT ----
__global__ __launch_bounds__(512) void proj_kernel(
    const float* __restrict__ hV, const float* __restrict__ R, const float* __restrict__ tvec,
    const ushort_t* __restrict__ WT,
    const float* __restrict__ bq, const float* __restrict__ bkv,
    const float* __restrict__ bqp, const float* __restrict__ bkvp,
    ushort_t* __restrict__ qb, ushort_t* __restrict__ kb, ushort_t* __restrict__ vb,
    float* __restrict__ qpts, float* __restrict__ kpts, float* __restrict__ vpts)
{
    const int node0 = (blockIdx.x >> 1) * TM;
    const int half  = blockIdx.x & 1;
    const int tid = threadIdx.x;
    const int w = tid >> 6, l = tid & 63, lr = l & 15, lk = l >> 4;

    __shared__ ushort_t s_A[TM][128];    // 4 KB bf16 A tile
    __shared__ float s_qp[TM][96];       // 6 KB
    __shared__ float s_kvp[TM][144];     // 9 KB

    {
        int i = tid * 4; int r = i >> 7, c = i & 127;
        float4 x = *(const float4*)&hV[(size_t)(node0 + r) * DD + c];
        s_A[r][c + 0] = f2bf(x.x); s_A[r][c + 1] = f2bf(x.y);
        s_A[r][c + 2] = f2bf(x.z); s_A[r][c + 3] = f2bf(x.w);
    }
    __syncthreads();

    const ushort_t* Ab = &s_A[lr][lk * 8];
    for (int t = 0; t < 7; ++t) {
        const int tile = half * 56 + w * 7 + t;
        const int n = tile * 16 + lr;
        f32x4 acc = {0.f, 0.f, 0.f, 0.f};
        const ushort_t* Bb = WT + (size_t)n * 128 + lk * 8;
        #pragma unroll
        for (int ks = 0; ks < 4; ++ks) {
            short8 a = *(const short8*)(Ab + ks * 32);
            short8 bfr = *(const short8*)(Bb + ks * 32);
            acc = __builtin_amdgcn_mfma_f32_16x16x32_bf16(a, bfr, acc, 0, 0, 0);
        }
        if (n < 512) {
            float bias = bq[n];
            #pragma unroll
            for (int i = 0; i < 4; ++i)
                qb[(size_t)(node0 + lk * 4 + i) * 512 + n] = f2bf(acc[i] + bias);
        } else if (n < 1536) {
            int n2 = n - 512;
            float bias = bkv[n2];
            int hh = n2 >> 8, wcol = n2 & 255;
            ushort_t* base = (wcol < 128) ? kb : vb;
            int off = hh * DD + (wcol & 127);
            #pragma unroll
            for (int i = 0; i < 4; ++i)
                base[(size_t)(node0 + lk * 4 + i) * 512 + off] = f2bf(acc[i] + bias);
        } else if (n < 1632) {
            int c = n - 1536;
            float bias = bqp[c];
            #pragma unroll
            for (int i = 0; i < 4; ++i) s_qp[lk * 4 + i][c] = acc[i] + bias;
        } else if (n < 1776) {
            int c = n - 1632;
            float bias = bkvp[c];
            #pragma unroll
            for (int i = 0; i < 4; ++i) s_kvp[lk * 4 + i][c] = acc[i] + bias;
        }
    }
    __syncthreads();

    if (half == 1) {
        for (int idx = tid; idx < TM * 96; idx += 512) {
            int r = idx / 96, u = idx % 96;
            int j = u / 3, d = u % 3;
            int node = node0 + r;
            float acc = tvec[node * 3 + d];
            #pragma unroll
            for (int y = 0; y < 3; ++y)
                acc = fmaf(R[node * 9 + d * 3 + y], s_qp[r][y * 32 + j], acc);
            qpts[(size_t)node * 96 + j * 3 + d] = acc;
        }
        for (int idx = tid; idx < TM * 144; idx += 512) {
            int r = idx / 144, u = idx % 144;
            int jj = u / 3, d = u % 3;
            int node = node0 + r;
            float acc = tvec[node * 3 + d];
            #pragma unroll
            for (int y = 0; y < 3; ++y)
                acc = fmaf(R[node * 9 + d * 3 + y], s_kvp[r][y * 48 + jj], acc);
            int hh = jj / 12, pp = jj % 12;
            if (pp < PQ_) kpts[(size_t)node * 96 + (hh * PQ_ + pp) * 3 + d] = acc;
            else          vpts[(size_t)node * 48 + (hh * PV_ + (pp - PQ_)) * 3 + d] = acc;
        }
    }
}

// ---- attn core: bf16 q/k/v, hE single HBM pass. launch_bounds(256,6)
// gives 85-VGPR budget; fully-unrolled gather loops let the compiler
// hoist loads for ILP without the spill-prone manual buffers. ----
__global__ __launch_bounds__(256, 6) void attn_kernel(
    const float* __restrict__ hE, const int* __restrict__ Eidx,
    const float* __restrict__ R, const float* __restrict__ tvec,
    const float* __restrict__ mask_att,
    const float* __restrict__ Wb, const float* __restrict__ bb,
    const float* __restrict__ head_w,
    const ushort_t* __restrict__ qb, const ushort_t* __restrict__ kb,
    const ushort_t* __restrict__ vb,
    const float* __restrict__ qpts, const float* __restrict__ kpts, const float* __restrict__ vpts,
    ushort_t* __restrict__ catb)
{
    const int node = blockIdx.x;
    const int b = node >> 11;
    const int tid = threadIdx.x;
    const int lane = tid & 63;
    const int wv = tid >> 6;

    __shared__ ushort_t s_hEb[KK * DD];   // 7680 B
    __shared__ float s_cat[1088];
    __shared__ float s_qp[96];
    __shared__ float s_p[HH][32];
    __shared__ int   s_j[32];
    __shared__ float s_mask[32];
    __shared__ float s_opt[48];

    if (tid < 96) s_qp[tid] = qpts[(size_t)node * 96 + tid];
    if (tid < KK) {
        s_j[tid] = Eidx[(size_t)node * KK + tid];
        s_mask[tid] = 100000.0f * (mask_att[(size_t)node * KK + tid] - 1.0f);
    }
    __syncthreads();

    const int h = wv;
    const int l32 = lane & 31;
    const int g = lane >> 5;
    const float* hE_node = hE + (size_t)node * (KK * DD);

    const unsigned qu0 = *(const unsigned*)&qb[(size_t)node * 512 + h * DD + 2 * l32];
    const unsigned qu1 = *(const unsigned*)&qb[(size_t)node * 512 + h * DD + 64 + 2 * l32];
    const float q0 = bflo(qu0), q1 = bfhi(qu0), q2 = bflo(qu1), q3 = bfhi(qu1);
    const float wb0 = Wb[(l32 +  0) * HH + h];
    const float wb1 = Wb[(l32 + 32) * HH + h];
    const float wb2 = Wb[(l32 + 64) * HH + h];
    const float wb3 = Wb[(l32 + 96) * HH + h];
    const float cpt = -0.5f * PT_SCALE * log1pf(expf(head_w[h]));
    const float bbh = INV3 * bb[h];
    const float qpl = (l32 < 24) ? s_qp[h * 24 + l32] : 0.f;

    // ---- logits: 2 k's per iteration; stage hE -> LDS bf16 (wave 0) ----
    #pragma unroll
    for (int kx2 = 0; kx2 < KK / 2; ++kx2) {
        const int k = kx2 * 2 + g;
        size_t jb = (size_t)(b * NN + s_j[k]);
        const ushort_t* kr = kb + jb * 512 + h * DD;
        unsigned ku0 = *(const unsigned*)&kr[2 * l32];
        unsigned ku1 = *(const unsigned*)&kr[64 + 2 * l32];
        float s = q0 * bflo(ku0) + q1 * bfhi(ku0) + q2 * bflo(ku1) + q3 * bfhi(ku1);
        const float* her = hE_node + k * DD;
        float h0 = her[l32], h1 = her[l32 + 32], h2 = her[l32 + 64], h3 = her[l32 + 96];
        if (wv == 0) {
            s_hEb[k * DD + l32]      = f2bf(h0);
            s_hEb[k * DD + l32 + 32] = f2bf(h1);
            s_hEb[k * DD + l32 + 64] = f2bf(h2);
            s_hEb[k * DD + l32 + 96] = f2bf(h3);
        }
        float t = wb0 * h0 + wb1 * h1 + wb2 * h2 + wb3 * h3;
        float ptc = 0.f;
        if (l32 < 24) {
            float d = qpl - kpts[jb * 96 + h * 24 + l32];
            ptc = d * d;
        }
        float val = INV3C * s + INV3 * t + cpt * ptc;
        #pragma unroll
        for (int off = 16; off; off >>= 1) val += __shfl_down(val, off, 32);
        if (l32 == 0) s_p[h][k] = val + bbh + s_mask[k];
    }
    __syncthreads();

    // ---- softmax over k ----
    {
        float v = (lane < KK) ? s_p[h][lane] : -INFINITY;
        float m = v;
        #pragma unroll
        for (int off = 16; off; off >>= 1) m = fmaxf(m, __shfl_down(m, off));
        m = __shfl(m, 0);
        float e = (lane < KK) ? expf(v - m) : 0.f;
        float s = e;
        #pragma unroll
        for (int off = 16; off; off >>= 1) s += __shfl_down(s, off);
        s = __shfl(s, 0);
        if (lane < KK) s_p[h][lane] = e / s;
    }
    __syncthreads();

    // ---- o (bf16 gathered v) + o_pair (LDS hE), fully unrolled ----
    {
        const int oh = tid >> 6;
        const int oc0 = (tid & 63) * 2;
        const ushort_t* vrow = vb + oh * DD + oc0;
        float a0 = 0.f, a1 = 0.f, b0 = 0.f, b1 = 0.f;
        #pragma unroll
        for (int kx = 0; kx < KK; ++kx) {
            unsigned pv = *(const unsigned*)(vrow + (size_t)(b * NN + s_j[kx]) * 512);
            unsigned pe = *(const unsigned*)&s_hEb[kx * DD + oc0];
            float p = s_p[oh][kx];
            a0 = fmaf(p, bflo(pv), a0);
            a1 = fmaf(p, bfhi(pv), a1);
            b0 = fmaf(p, bflo(pe), b0);
            b1 = fmaf(p, bfhi(pe), b1);
        }
        s_cat[oh * DD + oc0]           = a0;
        s_cat[oh * DD + oc0 + 1]       = a1;
        s_cat[576 + oh * DD + oc0]     = b0;
        s_cat[576 + oh * DD + oc0 + 1] = b1;
    }
    // ---- o_pt: 48 items, fully unrolled ----
    if (tid < 48) {
        const int oh = (tid / 3) >> 2;
        float acc = 0.f;
        #pragma unroll
        for (int kx = 0; kx < KK; ++kx)
            acc = fmaf(s_p[oh][kx], vpts[(size_t)(b * NN + s_j[kx]) * 48 + tid], acc);
        s_opt[tid] = acc;
    }
    __syncthreads();
    if (tid < 16) {
        int jj = tid;
        float g0 = s_opt[jj * 3 + 0] - tvec[node * 3 + 0];
        float g1 = s_opt[jj * 3 + 1] - tvec[node * 3 + 1];
        float g2 = s_opt[jj * 3 + 2] - tvec[node * 3 + 2];
        float l0 = R[node * 9 + 0] * g0 + R[node * 9 + 3] * g1 + R[node * 9 + 6] * g2;
        float l1 = R[node * 9 + 1] * g0 + R[node * 9 + 4] * g1 + R[node * 9 + 7] * g2;
        float l2 = R[node * 9 + 2] * g0 + R[node * 9 + 5] * g1 + R[node * 9 + 8] * g2;
        s_cat[512 + 0 * 16 + jj] = l0;
        s_cat[512 + 1 * 16 + jj] = l1;
        s_cat[512 + 2 * 16 + jj] = l2;
        s_cat[560 + jj] = sqrtf(l0 * l0 + l1 * l1 + l2 * l2 + 1e-8f);
    }
    __syncthreads();

    for (int i = tid; i < 1088; i += 256)
        catb[(size_t)node * 1088 + i] = f2bf(s_cat[i]);
}

// ---- tail: MFMA GEMMs. 16 nodes/block, 512 threads (8 waves), grid 256. ----
__global__ __launch_bounds__(512) void tail_kernel(
    const float* __restrict__ hV, const float* __restrict__ maskV,
    const ushort_t* __restrict__ catb,
    const ushort_t* __restrict__ WoutT, const float* __restrict__ bout,
    const float* __restrict__ ln0w, const float* __restrict__ ln0b,
    const float* __restrict__ ln1w, const float* __restrict__ ln1b,
    const ushort_t* __restrict__ Wm1T, const float* __restrict__ bm1,
    const ushort_t* __restrict__ Wm2T, const float* __restrict__ bm2,
    float* __restrict__ out)
{
    const int node0 = blockIdx.x * TM;
    const int tid = threadIdx.x;
    const int w  = tid >> 6;
    const int l  = tid & 63;
    const int lr = l & 15;
    const int lk = l >> 4;

    __shared__ float    s_x[TM][DD];
    __shared__ float    s_hv[TM][DD];
    __shared__ ushort_t s_hvb[TM][136];
    __shared__ ushort_t s_m1[TM][520];
    __shared__ float    s_rs[TM][16];
    __shared__ float    s_rq[TM][16];
    __shared__ float    s_stat[TM][2];

    // ---- GEMM1: s = cat[16x1088] @ Wout[1088x128]
    {
        f32x4 acc = {0.f, 0.f, 0.f, 0.f};
        const ushort_t* Ab = catb + (size_t)(node0 + lr) * 1088 + lk * 8;
        const ushort_t* Bb = WoutT + (size_t)(w * 16 + lr) * 1088 + lk * 8;
        #pragma unroll 2
        for (int ks = 0; ks < 34; ++ks) {
            short8 a = *(const short8*)(Ab + ks * 32);
            short8 bfr = *(const short8*)(Bb + ks * 32);
            acc = __builtin_amdgcn_mfma_f32_16x16x32_bf16(a, bfr, acc, 0, 0, 0);
        }
        #pragma unroll
        for (int i = 0; i < 4; ++i)
            s_x[lk * 4 + i][w * 16 + lr] = acc[i];
    }
    __syncthreads();

    // ---- bias + residual + LN0 ----
    if (tid < 256) {
        int r = tid >> 4, sg = tid & 15;
        float ss = 0.f, sq = 0.f;
        #pragma unroll
        for (int j = 0; j < 8; ++j) {
            int cc = sg * 8 + j;
            float x = s_x[r][cc] + bout[cc] + hV[(size_t)(node0 + r) * DD + cc];
            s_x[r][cc] = x;
            ss += x; sq += x * x;
        }
        s_rs[r][sg] = ss; s_rq[r][sg] = sq;
    }
    __syncthreads();
    if (tid < TM) {
        float ss = 0.f, sq = 0.f;
        #pragma unroll
        for (int sg = 0; sg < 16; ++sg) { ss += s_rs[tid][sg]; sq += s_rq[tid][sg]; }
        float mu = ss / 128.f;
        s_stat[tid][0] = mu;
        s_stat[tid][1] = rsqrtf(sq / 128.f - mu * mu + 1e-5f);
    }
    __syncthreads();
    {
        int idx = tid * 4;
        int r = idx >> 7, cc = idx & 127;
        float mu = s_stat[r][0], rstd = s_stat[r][1];
        #pragma unroll
        for (int j = 0; j < 4; ++j) {
            float hvv = (s_x[r][cc + j] - mu) * rstd * ln0w[cc + j] + ln0b[cc + j];
            s_hv[r][cc + j] = hvv;
            s_hvb[r][cc + j] = f2bf(hvv);
        }
    }
    __syncthreads();

    // ---- GEMM2: m1 = hv[16x128] @ Wm1[128x512], ReLU ----
    {
        const ushort_t* Ab = &s_hvb[lr][lk * 8];
        #pragma unroll
        for (int t = 0; t < 4; ++t) {
            int n0 = w * 64 + t * 16;
            f32x4 acc = {0.f, 0.f, 0.f, 0.f};
            const ushort_t* Bb = Wm1T + (size_t)(n0 + lr) * 128 + lk * 8;
            #pragma unroll
            for (int ks = 0; ks < 4; ++ks) {
                short8 a = *(const short8*)(Ab + ks * 32);
                short8 bfr = *(const short8*)(Bb + ks * 32);
                acc = __builtin_amdgcn_mfma_f32_16x16x32_bf16(a, bfr, acc, 0, 0, 0);
            }
            int n = n0 + lr;
            float bm = bm1[n];
            #pragma unroll
            for (int i = 0; i < 4; ++i)
                s_m1[lk * 4 + i][n] = f2bf(fmaxf(acc[i] + bm, 0.f));
        }
    }
    __syncthreads();

    // ---- GEMM3: m = m1[16x512] @ Wm2[512x128] ----
    {
        f32x4 acc = {0.f, 0.f, 0.f, 0.f};
        const ushort_t* Ab = &s_m1[lr][lk * 8];
        const ushort_t* Bb = Wm2T + (size_t)(w * 16 + lr) * 512 + lk * 8;
        #pragma unroll 4
        for (int ks = 0; ks < 16; ++ks) {
            short8 a = *(const short8*)(Ab + ks * 32);
            short8 bfr = *(const short8*)(Bb + ks * 32);
            acc = __builtin_amdgcn_mfma_f32_16x16x32_bf16(a, bfr, acc, 0, 0, 0);
        }
        #pragma unroll
        for (int i = 0; i < 4; ++i)
            s_x[lk * 4 + i][w * 16 + lr] = acc[i];
    }
    __syncthreads();

    // ---- bm2 + residual + LN1 ----
    if (tid < 256) {
        int r = tid >> 4, sg = tid & 15;
        float ss = 0.f, sq = 0.f;
        #pragma unroll
        for (int j = 0; j < 8; ++j) {
            int cc = sg * 8 + j;
            float x = s_x[r][cc] + bm2[cc] + s_hv[r][cc];
            s_x[r][cc] = x;
            ss += x; sq += x * x;
        }
        s_rs[r][sg] = ss; s_rq[r][sg] = sq;
    }
    __syncthreads();
    if (tid < TM) {
        float ss = 0.f, sq = 0.f;
        #pragma unroll
        for (int sg = 0; sg < 16; ++sg) { ss += s_rs[tid][sg]; sq += s_rq[tid][sg]; }
        float mu = ss / 128.f;
        s_stat[tid][0] = mu;
        s_stat[tid][1] = rsqrtf(sq / 128.f - mu * mu + 1e-5f);
    }
    __syncthreads();
    {
        int idx = tid * 4;
        int r = idx >> 7, cc = idx & 127;
        float mu = s_stat[r][0], rstd = s_stat[r][1];
        float mk = maskV[node0 + r];
        float4 o;
        o.x = ((s_x[r][cc + 0] - mu) * rstd * ln1w[cc + 0] + ln1b[cc + 0]) * mk;
        o.y = ((s_x[r][cc + 1] - mu) * rstd * ln1w[cc + 1] + ln1b[cc + 1]) * mk;
        o.z = ((s_x[r][cc + 2] - mu) * rstd * ln1w[cc + 2] + ln1b[cc + 2]) * mk;
        o.w = ((s_x[r][cc + 3] - mu) * rstd * ln1w[cc + 3] + ln1b[cc + 3]) * mk;
        *(float4*)&out[(size_t)(node0 + r) * DD + cc] = o;
    }
}

extern "C" void kernel_launch(void* const* d_in, const int* in_sizes, int n_in,
                              void* d_out, int out_size, void* d_ws, size_t ws_size,
                              hipStream_t stream)
{
    const float* hV      = (const float*)d_in[0];
    const float* hE      = (const float*)d_in[1];
    const int*   Eidx    = (const int*)  d_in[2];
    const float* R       = (const float*)d_in[3];
    const float* tvec    = (const float*)d_in[4];
    const float* mask_at = (const float*)d_in[5];
    const float* maskV   = (const float*)d_in[6];
    const float* Wq      = (const float*)d_in[7];
    const float* bq      = (const float*)d_in[8];
    const float* Wkv     = (const float*)d_in[9];
    const float* bkv     = (const float*)d_in[10];
    const float* Wqp     = (const float*)d_in[11];
    const float* bqp     = (const float*)d_in[12];
    const float* Wkvp    = (const float*)d_in[13];
    const float* bkvp    = (const float*)d_in[14];
    const float* Wb      = (const float*)d_in[15];
    const float* bb      = (const float*)d_in[16];
    const float* hw      = (const float*)d_in[17];
    const float* Wout    = (const float*)d_in[18];
    const float* bout    = (const float*)d_in[19];
    const float* ln0w    = (const float*)d_in[20];
    const float* ln0b    = (const float*)d_in[21];
    const float* ln1w    = (const float*)d_in[22];
    const float* ln1b    = (const float*)d_in[23];
    const float* Wm1     = (const float*)d_in[24];
    const float* bm1     = (const float*)d_in[25];
    const float* Wm2     = (const float*)d_in[26];
    const float* bm2     = (const float*)d_in[27];

    const size_t nodes = (size_t)BB * NN;
    ushort_t* qb     = (ushort_t*)d_ws;                 // nodes*512 bf16
    ushort_t* kb     = qb + nodes * 512;
    ushort_t* vb     = kb + nodes * 512;
    ushort_t* catb   = vb + nodes * 512;                // nodes*1088
    ushort_t* WoutT  = catb + nodes * 1088;
    ushort_t* Wm1T   = WoutT + 128 * 1088;
    ushort_t* Wm2T   = Wm1T + 512 * 128;
    ushort_t* WprojT = Wm2T + 128 * 512;                // 1792*128
    float* qpts = (float*)(WprojT + 1792 * 128);
    float* kpts = qpts + nodes * 96;
    float* vpts = kpts + nodes * 96;

    prep_kernel<<<256, 256, 0, stream>>>(Wout, Wm1, Wm2, Wq, Wkv, Wqp, Wkvp,
                                         WoutT, Wm1T, Wm2T, WprojT);

    proj_kernel<<<(int)(nodes / TM) * 2, 512, 0, stream>>>(
        hV, R, tvec, WprojT, bq, bkv, bqp, bkvp,
        qb, kb, vb, qpts, kpts, vpts);

    attn_kernel<<<(int)nodes, 256, 0, stream>>>(
        hE, Eidx, R, tvec, mask_at,
        Wb, bb, hw,
        qb, kb, vb, qpts, kpts, vpts, catb);

    tail_kernel<<<(int)(nodes / TM), 512, 0, stream>>>(
        hV, maskV, catb,
        WoutT, bout, ln0w, ln0b, ln1w, ln1b,
        Wm1T, bm1, Wm2T, bm2, (float*)d_out);
}